// Round 4
// baseline (14245.149 us; speedup 1.0000x reference)
//
#include <hip/hip_runtime.h>
#include <math.h>
#include <stdint.h>
#include <stddef.h>

typedef unsigned short u16;
typedef unsigned int   u32;
typedef __attribute__((ext_vector_type(8))) short short8;   // bf16x8 MFMA frag (guide §3)
typedef __attribute__((ext_vector_type(4))) float f32x4;

#define DI __device__ __forceinline__

// ---------------- problem constants ----------------
static constexpr int Vv = 32000, Ee = 512, Hh = 1024, Zz = 256;
static constexpr int Bb = 64, Ss = 256, Tt = 64;
static constexpr int G3 = 3 * Hh;            // 3072

// ---------------- workspace layout (bytes) ----------------
static constexpr size_t SZ_W3    = (size_t)G3 * G3 * 2;        // 18,874,368 (tripled Whh)
static constexpr size_t OFF_WHHE3 = 0;
static constexpr size_t OFF_WHHD3 = OFF_WHHE3 + SZ_W3;
static constexpr size_t OFF_WIHE3 = OFF_WHHD3 + SZ_W3;
static constexpr size_t SZ_WIHE3 = (size_t)G3 * (3 * Ee) * 2;  // 9,437,184
static constexpr size_t OFF_WVOC  = OFF_WIHE3 + SZ_WIHE3;
static constexpr size_t SZ_WVOC  = (size_t)Vv * Hh * 2;        // 65,536,000
static constexpr size_t OFF_XS    = OFF_WVOC + SZ_WVOC;        // x' split (dead after gx GEMM)
static constexpr size_t SZ_XS    = (size_t)Ss * Bb * (3 * Ee) * 2; // 50,331,648
static constexpr size_t OFF_GX    = OFF_XS + SZ_XS;
static constexpr size_t SZ_GX    = (size_t)Ss * Bb * G3 * 4;   // 201,326,592
// overlay inside XS region (only used after gx GEMM has consumed XS):
static constexpr size_t OFF_HA0  = OFF_XS;
static constexpr size_t OFF_HA1  = OFF_HA0 + (size_t)Bb * G3 * 2;   // 393,216 each
static constexpr size_t OFF_H    = OFF_HA1 + (size_t)Bb * G3 * 2;
static constexpr size_t OFF_H2F  = OFF_H   + (size_t)Bb * Hh * 4;
static constexpr size_t OFF_H2B  = OFF_H2F + (size_t)Tt * Bb * Hh * 4;
static constexpr size_t OFF_GXD  = OFF_H2B + (size_t)Tt * Bb * Hh * 2;
static constexpr size_t OFF_HENC = OFF_GXD + 12288;
static constexpr size_t OFF_ZB   = OFF_HENC + (size_t)Bb * Zz * 4;
static constexpr size_t OFF_RM   = OFF_ZB + (size_t)Bb * Zz * 4;
static constexpr size_t OFF_SE   = OFF_RM + 16384;
static constexpr size_t OFF_LSE  = OFF_SE + 16384;
static constexpr size_t OFF_BV   = OFF_LSE + 16384;
static constexpr size_t OFF_BI   = OFF_BV + 16384;
static constexpr size_t OFF_CC   = OFF_BI + 16384;
static constexpr size_t OFF_CAND = OFF_CC + 16384;             // 4096*32 ints
static constexpr size_t OFF_PART = OFF_CAND + (size_t)4096 * 32 * 4;  // 512*64*48 f32 = 6.3MB
static constexpr size_t OFF_CNT  = OFF_PART + (size_t)512 * 64 * 48 * 4;  // 64 cnt + root

// ---------------- small helpers ----------------
DI u16 f2bf(float f) {                       // f32 -> bf16 RNE
  u32 u = __float_as_uint(f);
  u32 r = (u + 0x7FFFu + ((u >> 16) & 1u)) >> 16;
  return (u16)r;
}
DI float bf2f(u16 h) { return __uint_as_float(((u32)h) << 16); }

DI f32x4 mfma16(short8 a, short8 b, f32x4 c) {
  return __builtin_amdgcn_mfma_f32_16x16x32_bf16(a, b, c, 0, 0, 0);
}
DI void llds16(const u16* g, u16* l) {       // async global->LDS, 16B/lane (guide §5)
  __builtin_amdgcn_global_load_lds(
      (const __attribute__((address_space(1))) u32*)g,
      (__attribute__((address_space(3))) u32*)l, 16, 0, 0);
}

// agent-scope (device-coherent) access: sc-bit ops, NO cache maintenance.
// hA/h/part/cnt/root are ONLY ever accessed through these -> no XCD L2 ever
// holds a stale copy (lesson of Round 2/3: fences are catastrophic, per-access
// coherence is cheap).
DI void ag_store(float* p, float v) {
  __hip_atomic_store(p, v, __ATOMIC_RELAXED, __HIP_MEMORY_SCOPE_AGENT);
}
DI float ag_load(const float* p) {
  return __hip_atomic_load((float*)p, __ATOMIC_RELAXED, __HIP_MEMORY_SCOPE_AGENT);
}
DI void ag_store_u32(u32* p, u32 v) {
  __hip_atomic_store(p, v, __ATOMIC_RELAXED, __HIP_MEMORY_SCOPE_AGENT);
}
DI u32 ag_load_u32(const u32* p) {
  return __hip_atomic_load((u32*)p, __ATOMIC_RELAXED, __HIP_MEMORY_SCOPE_AGENT);
}

// ---------------- utility kernels ----------------
__global__ void k_zero(u32* p, int n) {
  for (int i = blockIdx.x * 256 + threadIdx.x; i < n; i += gridDim.x * 256) p[i] = 0;
}

// W (rows x kin) f32 -> tripled bf16 [W_hi | W_hi | W_lo] (rows x 3kin)
__global__ void k_trip(const float* __restrict__ W, u16* __restrict__ W3, int rows, int kin) {
  int n = rows * kin;
  for (int i = blockIdx.x * 256 + threadIdx.x; i < n; i += gridDim.x * 256) {
    int rr = i / kin, k = i - rr * kin;
    float v = W[i];
    u16 hi = f2bf(v);
    u16 lo = f2bf(v - bf2f(hi));
    u16* o = W3 + (size_t)rr * (3 * kin);
    o[k] = hi; o[kin + k] = hi; o[2 * kin + k] = lo;
  }
}

__global__ void k_tobf(const float* __restrict__ W, u16* __restrict__ Wb, int n) {
  for (int i = blockIdx.x * 256 + threadIdx.x; i < n; i += gridDim.x * 256) Wb[i] = f2bf(W[i]);
}

// x' = gathered embeddings split as [x_hi | x_lo | x_hi]  (matches B' = [W_hi|W_hi|W_lo])
__global__ void k_xsplit(const int* __restrict__ inp, const float* __restrict__ emb,
                         u16* __restrict__ xs) {
  int n = Ss * Bb * Ee;
  for (int i = blockIdx.x * 256 + threadIdx.x; i < n; i += gridDim.x * 256) {
    int m = i >> 9, k = i & (Ee - 1);
    int tok = inp[m];
    float v = emb[(size_t)tok * Ee + k];
    u16 hi = f2bf(v);
    u16 lo = f2bf(v - bf2f(hi));
    u16* o = xs + (size_t)m * (3 * Ee);
    o[k] = hi; o[Ee + k] = lo; o[2 * Ee + k] = hi;
  }
}

// gxd[g] = emb_dec[EOS] . Wih_d[g] + bih_d[g]   (exact f32, once)
__global__ void k_gxd(const float* __restrict__ emb_dec, const float* __restrict__ Wih_d,
                      const float* __restrict__ bih_d, float* __restrict__ gxd) {
  int g = blockIdx.x * 256 + threadIdx.x;
  if (g >= G3) return;
  const float* er = emb_dec + 2 * Ee;        // EOS_ID = 2
  const float* wr = Wih_d + (size_t)g * Ee;
  float s = 0.f;
  for (int e = 0; e < Ee; e++) s += er[e] * wr[e];
  gxd[g] = s + bih_d[g];
}

// ---------------- generic GEMM: C[m][n] = sum_k A[m][k]*B[n][k] + bias[n] (f32 out) ----------------
__global__ __launch_bounds__(256, 2) void gemm_bt(
    const u16* __restrict__ A, const u16* __restrict__ Bw, const float* __restrict__ bias,
    float* __restrict__ C, int M, int N, int K) {
  __shared__ __align__(16) u16 As[128 * 32];
  __shared__ __align__(16) u16 Bs[128 * 32];
  int tid = threadIdx.x;
  int wave = tid >> 6, lane = tid & 63;
  int wr = wave >> 1, wc = wave & 1;
  int m0 = blockIdx.y * 128, n0 = blockIdx.x * 128;
  f32x4 acc[4][4];
#pragma unroll
  for (int i = 0; i < 4; i++)
#pragma unroll
    for (int j = 0; j < 4; j++) acc[i][j] = (f32x4){0.f, 0.f, 0.f, 0.f};

  int lrow = lane >> 2, lcol = (lane & 3) * 8;
  int r15 = lane & 15, kk = (lane >> 4) * 8;

  for (int k0 = 0; k0 < K; k0 += 32) {
    __syncthreads();
#pragma unroll
    for (int rch = 0; rch < 2; rch++) {
      int c = rch * 4 + wave;
      int row = c * 16 + lrow;
      llds16(A  + (size_t)(m0 + row) * K + k0 + lcol, &As[c * 512]);
      llds16(Bw + (size_t)(n0 + row) * K + k0 + lcol, &Bs[c * 512]);
    }
    __syncthreads();
    short8 af[4], bfv[4];
#pragma unroll
    for (int mi = 0; mi < 4; mi++)
      af[mi] = *(const short8*)&As[(wr * 64 + mi * 16 + r15) * 32 + kk];
#pragma unroll
    for (int ni = 0; ni < 4; ni++)
      bfv[ni] = *(const short8*)&Bs[(wc * 64 + ni * 16 + r15) * 32 + kk];
#pragma unroll
    for (int mi = 0; mi < 4; mi++)
#pragma unroll
      for (int ni = 0; ni < 4; ni++) acc[mi][ni] = mfma16(af[mi], bfv[ni], acc[mi][ni]);
  }
#pragma unroll
  for (int mi = 0; mi < 4; mi++)
#pragma unroll
    for (int ni = 0; ni < 4; ni++) {
      int col = n0 + wc * 64 + ni * 16 + r15;
      float bs = bias[col];
#pragma unroll
      for (int i = 0; i < 4; i++) {
        int row = m0 + wr * 64 + mi * 16 + (lane >> 4) * 4 + i;
        C[(size_t)row * N + col] = acc[mi][ni][i] + bs;
      }
    }
}

// ---------------- persistent GRU phase (cooperative, all steps in one launch) ----------------
// 512 blocks = 64 jt (16 hidden dims -> 48 gate rows) x 8 kq (384 of tripled K=3072).
// Per step: split-K partials (A: sc loads; W: plain loads -> L2-resident across steps),
// sc partial stores -> per-jt monotonic counter -> 8th arriver does gate epilogue ->
// bumps root; everyone polls root (64*(st+1)). No cache maintenance anywhere.
template <int DEC>
__global__ __launch_bounds__(256, 2) void k_persist(
    const u16* __restrict__ W3, const float* __restrict__ bhh, const float* __restrict__ gx0,
    u16* hA0buf, u16* hA1buf, float* h, float* h2f0, u16* h2b0,
    float* part, int* cnt, int* root) {
  int tid = threadIdx.x, wave = tid >> 6, lane = tid & 63;
  int r15 = lane & 15, kk4 = (lane >> 4) * 8;
  int m0 = wave * 16;
  int G = gridDim.x;
  const int NSTEP = DEC ? Tt : Ss;
  __shared__ int sfin;

  for (int st = 0; st < NSTEP; st++) {
    u16* hAin  = (st & 1) ? hA1buf : hA0buf;
    u16* hAout = (st & 1) ? hA0buf : hA1buf;
    const float* gxp = DEC ? gx0 : gx0 + (size_t)st * Bb * G3;
    float* h2f = DEC ? h2f0 + (size_t)st * Bb * Hh : nullptr;
    u16*   h2b = DEC ? h2b0 + (size_t)st * Bb * Hh : nullptr;

    for (int tile = blockIdx.x; tile < 512; tile += G) {
      int kq = tile & 7, jt = tile >> 3;
      int j0 = jt * 16, kbase = kq * 384;

      f32x4 acc[3];
#pragma unroll
      for (int g = 0; g < 3; g++) acc[g] = (f32x4){0.f, 0.f, 0.f, 0.f};

      const u32* Ab = (const u32*)(hAin + (size_t)(m0 + r15) * G3 + kbase + kk4);
      const u16* Bb0 = W3 + (size_t)(j0 + r15) * G3 + kbase + kk4;
#pragma unroll 4
      for (int ki = 0; ki < 12; ki++) {
        union { u32 w[4]; short8 v; } au;
        au.w[0] = ag_load_u32(Ab + ki * 16 + 0);
        au.w[1] = ag_load_u32(Ab + ki * 16 + 1);
        au.w[2] = ag_load_u32(Ab + ki * 16 + 2);
        au.w[3] = ag_load_u32(Ab + ki * 16 + 3);
        short8 b0 = *(const short8*)(Bb0 + ki * 32);
        short8 b1 = *(const short8*)(Bb0 + (size_t)Hh * G3 + ki * 32);
        short8 b2 = *(const short8*)(Bb0 + (size_t)2 * Hh * G3 + ki * 32);
        acc[0] = mfma16(au.v, b0, acc[0]);
        acc[1] = mfma16(au.v, b1, acc[1]);
        acc[2] = mfma16(au.v, b2, acc[2]);
      }

      // partial tile PART[jt][kq][batch 64][gatecol 48] -> L3 (sc stores)
      float* pp = part + (((size_t)jt * 8 + kq) * 64) * 48;
#pragma unroll
      for (int g = 0; g < 3; g++)
#pragma unroll
        for (int i = 0; i < 4; i++)
          ag_store(&pp[(m0 + (lane >> 4) * 4 + i) * 48 + g * 16 + r15], acc[g][i]);

      asm volatile("s_waitcnt vmcnt(0)" ::: "memory");   // partials at L3
      __syncthreads();
      if (tid == 0) {
        int old = __hip_atomic_fetch_add(&cnt[jt], 1, __ATOMIC_RELAXED, __HIP_MEMORY_SCOPE_AGENT);
        sfin = (old == 8 * st + 7);
      }
      __syncthreads();

      if (sfin) {
        // ---- gate epilogue for jt: 64 batch x 16 j, j-pairs for packed u32 stores ----
#pragma unroll
        for (int e = 0; e < 2; e++) {
          int p = tid + e * 256;                 // 512 (b, j-pair)
          int b = p >> 3, jc = (p & 7) * 2;
          int j = j0 + jc;
          float hgr0 = 0.f, hgz0 = 0.f, hgn0 = 0.f;
          float hgr1 = 0.f, hgz1 = 0.f, hgn1 = 0.f;
#pragma unroll
          for (int kq2 = 0; kq2 < 8; kq2++) {    // fixed order -> deterministic
            const float* q = part + (((size_t)jt * 8 + kq2) * 64 + b) * 48;
            hgr0 += ag_load(q + jc);      hgr1 += ag_load(q + jc + 1);
            hgz0 += ag_load(q + 16 + jc); hgz1 += ag_load(q + 16 + jc + 1);
            hgn0 += ag_load(q + 32 + jc); hgn1 += ag_load(q + 32 + jc + 1);
          }
          hgr0 += bhh[j];          hgr1 += bhh[j + 1];
          hgz0 += bhh[Hh + j];     hgz1 += bhh[Hh + j + 1];
          hgn0 += bhh[2 * Hh + j]; hgn1 += bhh[2 * Hh + j + 1];
          float xr0, xz0, xn0, xr1, xz1, xn1;
          if (DEC) {
            xr0 = gxp[j];          xr1 = gxp[j + 1];
            xz0 = gxp[Hh + j];     xz1 = gxp[Hh + j + 1];
            xn0 = gxp[2 * Hh + j]; xn1 = gxp[2 * Hh + j + 1];
          } else {
            const float* gr = gxp + (size_t)b * G3;
            xr0 = gr[j];          xr1 = gr[j + 1];
            xz0 = gr[Hh + j];     xz1 = gr[Hh + j + 1];
            xn0 = gr[2 * Hh + j]; xn1 = gr[2 * Hh + j + 1];
          }
          float rg0 = 1.0f / (1.0f + expf(-(xr0 + hgr0)));
          float rg1 = 1.0f / (1.0f + expf(-(xr1 + hgr1)));
          float zg0 = 1.0f / (1.0f + expf(-(xz0 + hgz0)));
          float zg1 = 1.0f / (1.0f + expf(-(xz1 + hgz1)));
          float ng0 = tanhf(xn0 + rg0 * hgn0);
          float ng1 = tanhf(xn1 + rg1 * hgn1);
          float hold0 = ag_load(&h[(size_t)b * Hh + j]);
          float hold1 = ag_load(&h[(size_t)b * Hh + j + 1]);
          float hn0 = (1.0f - zg0) * ng0 + zg0 * hold0;
          float hn1 = (1.0f - zg1) * ng1 + zg1 * hold1;
          ag_store(&h[(size_t)b * Hh + j], hn0);
          ag_store(&h[(size_t)b * Hh + j + 1], hn1);
          u16 hi0 = f2bf(hn0), hi1 = f2bf(hn1);
          u16 lo0 = f2bf(hn0 - bf2f(hi0)), lo1 = f2bf(hn1 - bf2f(hi1));
          u32 hiw = (u32)hi0 | ((u32)hi1 << 16);
          u32 low = (u32)lo0 | ((u32)lo1 << 16);
          u32* oa32 = (u32*)(hAout + (size_t)b * G3);
          ag_store_u32(&oa32[j >> 1], hiw);
          ag_store_u32(&oa32[(Hh + j) >> 1], low);
          ag_store_u32(&oa32[(2 * Hh + j) >> 1], hiw);
          if (DEC) {
            h2f[(size_t)b * Hh + j] = hn0;       // plain: consumed by later dispatches
            h2f[(size_t)b * Hh + j + 1] = hn1;
            ((u32*)(h2b + (size_t)b * Hh))[j >> 1] = hiw;
          }
        }
        asm volatile("s_waitcnt vmcnt(0)" ::: "memory");  // hA stores at L3
        __syncthreads();
        if (tid == 0)
          __hip_atomic_fetch_add(root, 1, __ATOMIC_RELAXED, __HIP_MEMORY_SCOPE_AGENT);
      }
    }

    // wait for all 64 jt-epilogues of this step
    if (tid == 0) {
      int target = 64 * (st + 1);
      while (__hip_atomic_load(root, __ATOMIC_RELAXED, __HIP_MEMORY_SCOPE_AGENT) < target)
        __builtin_amdgcn_s_sleep(2);
    }
    __syncthreads();
  }
}

// ---------------- fallback per-step kernel (Round-3 path, used only if coop launch fails) ----------------
template <int DEC>
__global__ __launch_bounds__(256, 2) void k_step2(
    const u16* __restrict__ W3, const float* __restrict__ bhh, const float* __restrict__ gxp,
    const u16* __restrict__ hAin, u16* __restrict__ hAout, float* __restrict__ h,
    float* __restrict__ h2f, u16* __restrict__ h2b, float* part, int* cnt) {
  int tid = threadIdx.x, wave = tid >> 6, lane = tid & 63;
  int bid = blockIdx.x;
  int kq = bid & 7, jt = bid >> 3;
  int j0 = jt * 16;
  int kbase = kq * 384;
  int r15 = lane & 15, kk = (lane >> 4) * 8;
  int m0 = wave * 16;

  f32x4 acc[3];
#pragma unroll
  for (int g = 0; g < 3; g++) acc[g] = (f32x4){0.f, 0.f, 0.f, 0.f};

  const u16* Ab = hAin + (size_t)(m0 + r15) * G3 + kbase + kk;
  const u16* Bb0 = W3 + (size_t)(j0 + r15) * G3 + kbase + kk;
#pragma unroll 4
  for (int ki = 0; ki < 12; ki++) {
    int ko = ki * 32;
    short8 a  = *(const short8*)(Ab + ko);
    short8 b0 = *(const short8*)(Bb0 + ko);
    short8 b1 = *(const short8*)(Bb0 + (size_t)Hh * G3 + ko);
    short8 b2 = *(const short8*)(Bb0 + (size_t)2 * Hh * G3 + ko);
    acc[0] = mfma16(a, b0, acc[0]);
    acc[1] = mfma16(a, b1, acc[1]);
    acc[2] = mfma16(a, b2, acc[2]);
  }
  float* pp = part + (((size_t)jt * 8 + kq) * 64) * 48;
#pragma unroll
  for (int g = 0; g < 3; g++)
#pragma unroll
    for (int i = 0; i < 4; i++)
      ag_store(&pp[(m0 + (lane >> 4) * 4 + i) * 48 + g * 16 + r15], acc[g][i]);

  __shared__ int sfin;
  asm volatile("s_waitcnt vmcnt(0)" ::: "memory");
  __syncthreads();
  if (tid == 0) {
    int old = __hip_atomic_fetch_add(&cnt[jt], 1, __ATOMIC_RELAXED, __HIP_MEMORY_SCOPE_AGENT);
    sfin = (old == 7);
  }
  __syncthreads();
  if (!sfin) return;

#pragma unroll
  for (int e = 0; e < 4; e++) {
    int p = tid + e * 256;
    int b = p >> 4, jc = p & 15;
    int j = j0 + jc;
    float hgr = 0.f, hgz = 0.f, hgn = 0.f;
#pragma unroll
    for (int kq2 = 0; kq2 < 8; kq2++) {
      const float* q = part + (((size_t)jt * 8 + kq2) * 64 + b) * 48;
      hgr += ag_load(&q[jc]); hgz += ag_load(&q[16 + jc]); hgn += ag_load(&q[32 + jc]);
    }
    hgr += bhh[j]; hgz += bhh[Hh + j]; hgn += bhh[2 * Hh + j];
    float xr, xz, xn;
    if (DEC) { xr = gxp[j]; xz = gxp[Hh + j]; xn = gxp[2 * Hh + j]; }
    else {
      const float* gr = gxp + (size_t)b * G3;
      xr = gr[j]; xz = gr[Hh + j]; xn = gr[2 * Hh + j];
    }
    float rg = 1.0f / (1.0f + expf(-(xr + hgr)));
    float zg = 1.0f / (1.0f + expf(-(xz + hgz)));
    float ng = tanhf(xn + rg * hgn);
    float hold = h[(size_t)b * Hh + j];
    float hn = (1.0f - zg) * ng + zg * hold;
    h[(size_t)b * Hh + j] = hn;
    u16 hi = f2bf(hn);
    u16 lo = f2bf(hn - bf2f(hi));
    u16* oa = hAout + (size_t)b * G3;
    oa[j] = hi; oa[Hh + j] = lo; oa[2 * Hh + j] = hi;
    if (DEC) {
      h2f[(size_t)b * Hh + j] = hn;
      h2b[(size_t)b * Hh + j] = hi;
    }
  }
  if (tid == 0)
    __hip_atomic_store(&cnt[jt], 0, __ATOMIC_RELAXED, __HIP_MEMORY_SCOPE_AGENT);
}

// ---------------- heads (exact f32) ----------------
__global__ __launch_bounds__(256, 2) void k_head1(const float* __restrict__ h,
    const float* __restrict__ Wenc, const float* __restrict__ benc, float* __restrict__ henc) {
  int b = blockIdx.x;
  __shared__ float hs[Hh];
  for (int k = threadIdx.x; k < Hh; k += 256) hs[k] = ag_load(&h[(size_t)b * Hh + k]);
  __syncthreads();
  int q = threadIdx.x;
  const float* wrw = Wenc + (size_t)q * Hh;
  float s = 0.f;
  for (int k = 0; k < Hh; k++) s += hs[k] * wrw[k];
  henc[b * Zz + q] = s + benc[q];
}

__global__ __launch_bounds__(256, 2) void k_head2(const float* __restrict__ henc,
    const float* __restrict__ Wloc, const float* __restrict__ bloc,
    const float* __restrict__ Wsc, const float* __restrict__ bsc,
    const float* __restrict__ eps, float* __restrict__ outLoc, float* __restrict__ outSc,
    float* __restrict__ zb) {
  int b = blockIdx.x;
  __shared__ float hs[Zz];
  if (threadIdx.x < Zz) hs[threadIdx.x] = henc[b * Zz + threadIdx.x];
  __syncthreads();
  int q = threadIdx.x;
  const float* wl = Wloc + (size_t)q * Zz;
  const float* wsp = Wsc + (size_t)q * Zz;
  float sl = 0.f, ssum = 0.f;
  for (int k = 0; k < Zz; k++) { sl += hs[k] * wl[k]; ssum += hs[k] * wsp[k]; }
  sl += bloc[q]; ssum += bsc[q];
  float sp = fmaxf(ssum, 0.f) + log1pf(expf(-fabsf(ssum)));  // softplus, stable
  float zv = sl + eps[b * Zz + q] * expf(0.5f * sp);
  outLoc[b * Zz + q] = sl;
  outSc[b * Zz + q] = sp;
  zb[b * Zz + q] = zv;
}

__global__ __launch_bounds__(256, 2) void k_head3(const float* __restrict__ zb,
    const float* __restrict__ Wdec, const float* __restrict__ bdec,
    float* __restrict__ h, u16* __restrict__ hA0) {
  int b = blockIdx.x;
  __shared__ float zs[Zz];
  if (threadIdx.x < Zz) zs[threadIdx.x] = zb[b * Zz + threadIdx.x];
  __syncthreads();
  for (int j = threadIdx.x; j < Hh; j += 256) {
    const float* wrw = Wdec + (size_t)j * Zz;
    float s = 0.f;
    for (int k = 0; k < Zz; k++) s += zs[k] * wrw[k];
    s += bdec[j];
    ag_store(&h[(size_t)b * Hh + j], s);       // h/hA live in sc-domain for k_persist
    u16 hi = f2bf(s);
    u16 lo = f2bf(s - bf2f(hi));
    u16* oa = hA0 + (size_t)b * G3;
    // u16 sc stores not available: write via u32-aligned pairs is overkill here
    // (64 blocks only); use plain stores + rely on dispatch-boundary release,
    // then k_persist sc-loads read L3 -> need these in L3: plain stores are
    // flushed at kernel end (release), so visible. Safe.
    oa[j] = hi; oa[Hh + j] = lo; oa[2 * Hh + j] = hi;
  }
}

// ---------------- row reduce: max, sumexp, candidates ----------------
__global__ __launch_bounds__(256, 2) void k_rowred(const float* __restrict__ logits,
    float* __restrict__ rowmax, float* __restrict__ sumexp, int* __restrict__ ccnt,
    int* __restrict__ cand) {
  int r = blockIdx.x;
  const float* row = logits + (size_t)r * Vv;
  __shared__ float red[4];
  __shared__ float srm;
  __shared__ int lcnt;
  __shared__ int lcand[32];
  int tid = threadIdx.x, wave = tid >> 6, lane = tid & 63;
  if (tid == 0) lcnt = 0;
  float m = -3.0e38f;
  for (int c = tid * 4; c < Vv; c += 1024) {
    f32x4 v = *(const f32x4*)(row + c);
    m = fmaxf(fmaxf(fmaxf(m, v.x), v.y), fmaxf(v.z, v.w));
  }
  for (int o = 32; o; o >>= 1) m = fmaxf(m, __shfl_xor(m, o));
  if (lane == 0) red[wave] = m;
  __syncthreads();
  if (tid == 0) srm = fmaxf(fmaxf(red[0], red[1]), fmaxf(red[2], red[3]));
  __syncthreads();
  float rm = srm;
  float s = 0.f;
  for (int c = tid * 4; c < Vv; c += 1024) {
    f32x4 v = *(const f32x4*)(row + c);
    s += expf(v.x - rm) + expf(v.y - rm) + expf(v.z - rm) + expf(v.w - rm);
    if (v.x >= rm - 0.0625f) { int sl = atomicAdd(&lcnt, 1); if (sl < 32) lcand[sl] = c; }
    if (v.y >= rm - 0.0625f) { int sl = atomicAdd(&lcnt, 1); if (sl < 32) lcand[sl] = c + 1; }
    if (v.z >= rm - 0.0625f) { int sl = atomicAdd(&lcnt, 1); if (sl < 32) lcand[sl] = c + 2; }
    if (v.w >= rm - 0.0625f) { int sl = atomicAdd(&lcnt, 1); if (sl < 32) lcand[sl] = c + 3; }
  }
  for (int o = 32; o; o >>= 1) s += __shfl_xor(s, o);
  if (lane == 0) red[wave] = s;
  __syncthreads();
  if (tid == 0) {
    float st = red[0] + red[1] + red[2] + red[3];
    int cc = lcnt < 32 ? lcnt : 32;
    for (int i = 0; i < cc; i++)
      for (int k2 = i + 1; k2 < cc; k2++)
        if (lcand[k2] < lcand[i]) { int t = lcand[i]; lcand[i] = lcand[k2]; lcand[k2] = t; }
    rowmax[r] = rm; sumexp[r] = st; ccnt[r] = cc;
    for (int i = 0; i < cc; i++) cand[r * 32 + i] = lcand[i];
  }
}

// ---------------- refine candidates exactly in f32, correct LSE, per-row best ----------------
__global__ __launch_bounds__(256, 1) void k_refine(const float* __restrict__ logits,
    const float* __restrict__ h2f, const float* __restrict__ Wvoc, const float* __restrict__ bvoc,
    const float* __restrict__ rowmax, const float* __restrict__ sumexp,
    const int* __restrict__ ccnt, const int* __restrict__ cand,
    float* __restrict__ lsec, float* __restrict__ bestv, int* __restrict__ besti) {
  int r = blockIdx.x;
  __shared__ float hrow[Hh];
  __shared__ float lex[32];
  __shared__ float del[32];
  int tid = threadIdx.x, wave = tid >> 6, lane = tid & 63;
  for (int k = tid; k < Hh; k += 256) hrow[k] = h2f[(size_t)r * Hh + k];
  int cnt = ccnt[r];
  float rm = rowmax[r];
  __syncthreads();
  for (int ci = wave; ci < cnt; ci += 4) {
    int v = cand[r * 32 + ci];
    const float* wrw = Wvoc + (size_t)v * Hh;
    float s = 0.f;
    for (int k = lane; k < Hh; k += 64) s += hrow[k] * wrw[k];
    for (int o = 32; o; o >>= 1) s += __shfl_xor(s, o);
    if (lane == 0) {
      float le = s + bvoc[v];
      lex[ci] = le;
      float la = logits[(size_t)r * Vv + v];
      del[ci] = expf(le - rm) - expf(la - rm);
    }
  }
  __syncthreads();
  if (tid == 0) {
    float se = sumexp[r];
    for (int i = 0; i < cnt; i++) se += del[i];
    float lse = rm + logf(se);
    lsec[r] = lse;
    float bv = -3.0e38f; int bvi = 0;
    for (int i = 0; i < cnt; i++)
      if (lex[i] > bv) { bv = lex[i]; bvi = cand[r * 32 + i]; }
    bestv[r] = bv - lse;
    besti[r] = (r & 63) * Vv + bvi;
  }
}

// ---------------- per-step global argmax -> seq ----------------
__global__ void k_argmax(const float* __restrict__ bestv, const int* __restrict__ besti,
                         float* __restrict__ outseq) {
  int tid = threadIdx.x;
  if (tid == 0) outseq[0] = 1.0f;
  for (int t = 0; t < Tt; t++) {
    float v = bestv[t * 64 + tid];
    int ii = besti[t * 64 + tid];
    for (int o = 1; o < 64; o <<= 1) {
      float ov = __shfl_xor(v, o);
      int oi = __shfl_xor(ii, o);
      if (ov > v || (ov == v && oi < ii)) { v = ov; ii = oi; }
    }
    if (tid == 0) outseq[1 + t] = (float)ii;
  }
}

// ---------------- in-place log-softmax: logits -= lse[row] ----------------
__global__ __launch_bounds__(256, 2) void k_logp(float* __restrict__ logits,
                                                 const float* __restrict__ lsec) {
  size_t total = (size_t)Tt * Bb * Vv / 4;
  for (size_t p = (size_t)blockIdx.x * 256 + threadIdx.x; p < total;
       p += (size_t)gridDim.x * 256) {
    int r = (int)(p / (Vv / 4));
    f32x4 v = *(f32x4*)(logits + p * 4);
    float l = lsec[r];
    v.x -= l; v.y -= l; v.z -= l; v.w -= l;
    *(f32x4*)(logits + p * 4) = v;
  }
}

// ---------------- host: launch sequence ----------------
extern "C" void kernel_launch(void* const* d_in, const int* in_sizes, int n_in,
                              void* d_out, int out_size, void* d_ws, size_t ws_size,
                              hipStream_t stream) {
  (void)in_sizes; (void)n_in; (void)out_size; (void)ws_size;
  const int*   inp     = (const int*)d_in[0];
  const float* eps     = (const float*)d_in[1];
  const float* emb_enc = (const float*)d_in[2];
  const float* Wih_e   = (const float*)d_in[3];
  const float* Whh_e   = (const float*)d_in[4];
  const float* bih_e   = (const float*)d_in[5];
  const float* bhh_e   = (const float*)d_in[6];
  const float* W_enc   = (const float*)d_in[7];
  const float* b_enc   = (const float*)d_in[8];
  const float* W_loc   = (const float*)d_in[9];
  const float* b_loc   = (const float*)d_in[10];
  const float* W_sc    = (const float*)d_in[11];
  const float* b_sc    = (const float*)d_in[12];
  const float* emb_dec = (const float*)d_in[13];
  const float* W_dec   = (const float*)d_in[14];
  const float* b_dec   = (const float*)d_in[15];
  const float* Wih_d   = (const float*)d_in[16];
  const float* Whh_d   = (const float*)d_in[17];
  const float* bih_d   = (const float*)d_in[18];
  const float* bhh_d   = (const float*)d_in[19];
  const float* W_voc   = (const float*)d_in[20];
  const float* b_voc   = (const float*)d_in[21];

  char* ws = (char*)d_ws;
  u16*   WHHE3 = (u16*)(ws + OFF_WHHE3);
  u16*   WHHD3 = (u16*)(ws + OFF_WHHD3);
  u16*   WIHE3 = (u16*)(ws + OFF_WIHE3);
  u16*   WVOC  = (u16*)(ws + OFF_WVOC);
  u16*   XS    = (u16*)(ws + OFF_XS);
  float* GX    = (float*)(ws + OFF_GX);
  u16*   HA0   = (u16*)(ws + OFF_HA0);
  u16*   HA1   = (u16*)(ws + OFF_HA1);
  float* Hst   = (float*)(ws + OFF_H);
  float* H2F   = (float*)(ws + OFF_H2F);
  u16*   H2B   = (u16*)(ws + OFF_H2B);
  float* GXD   = (float*)(ws + OFF_GXD);
  float* HENC  = (float*)(ws + OFF_HENC);
  float* ZB    = (float*)(ws + OFF_ZB);
  float* RM    = (float*)(ws + OFF_RM);
  float* SE    = (float*)(ws + OFF_SE);
  float* LSE   = (float*)(ws + OFF_LSE);
  float* BV    = (float*)(ws + OFF_BV);
  int*   BI    = (int*)(ws + OFF_BI);
  int*   CC    = (int*)(ws + OFF_CC);
  int*   CAND  = (int*)(ws + OFF_CAND);
  float* PART  = (float*)(ws + OFF_PART);
  int*   CNT   = (int*)(ws + OFF_CNT);
  int*   ROOT  = CNT + 64;

  float* out     = (float*)d_out;
  float* logits  = out;                                   // (T*B, V) f32
  float* outseq  = out + (size_t)Tt * Bb * Vv;
  float* outloc  = outseq + (Tt + 1);
  float* outsc   = outloc + Bb * Zz;

  // --- weight conversions ---
  k_trip<<<1024, 256, 0, stream>>>(Whh_e, WHHE3, G3, Hh);
  k_trip<<<1024, 256, 0, stream>>>(Whh_d, WHHD3, G3, Hh);
  k_trip<<<512, 256, 0, stream>>>(Wih_e, WIHE3, G3, Ee);
  k_tobf<<<2048, 256, 0, stream>>>(W_voc, WVOC, Vv * Hh);
  k_xsplit<<<2048, 256, 0, stream>>>(inp, emb_enc, XS);

  // --- gx = x' * Wih_e3^T + bih_e   (M=16384, N=3072, K=1536) ---
  {
    dim3 g(G3 / 128, (Ss * Bb) / 128);
    gemm_bt<<<g, 256, 0, stream>>>(XS, WIHE3, bih_e, GX, Ss * Bb, G3, 3 * Ee);
  }
  k_gxd<<<12, 256, 0, stream>>>(emb_dec, Wih_d, bih_d, GXD);
  k_zero<<<256, 256, 0, stream>>>((u32*)HA0, (int)((2 * (size_t)Bb * G3 * 2 + (size_t)Bb * Hh * 4) / 4));
  k_zero<<<1, 256, 0, stream>>>((u32*)CNT, 128);

  // --- encoder: persistent cooperative kernel (256 steps in one launch) ---
  hipError_t ce;
  {
    const u16* a0 = WHHE3; const float* a1 = bhh_e; const float* a2 = GX;
    u16* a3 = HA0; u16* a4 = HA1; float* a5 = Hst;
    float* a6 = nullptr; u16* a7 = nullptr;
    float* a8 = PART; int* a9 = CNT; int* a10 = ROOT;
    void* args[] = {&a0,&a1,&a2,&a3,&a4,&a5,&a6,&a7,&a8,&a9,&a10};
    ce = hipLaunchCooperativeKernel(reinterpret_cast<void*>(&k_persist<0>),
                                    dim3(512), dim3(256), args, 0, stream);
  }
  if (ce != hipSuccess) {
    for (int s = 0; s < Ss; s++) {
      const u16* hin = (s & 1) ? HA1 : HA0;
      u16* hout = (s & 1) ? HA0 : HA1;
      k_step2<0><<<512, 256, 0, stream>>>(WHHE3, bhh_e, GX + (size_t)s * Bb * G3,
                                          hin, hout, Hst, nullptr, nullptr, PART, CNT);
    }
  }

  // --- heads ---
  k_head1<<<64, 256, 0, stream>>>(Hst, W_enc, b_enc, HENC);
  k_head2<<<64, 256, 0, stream>>>(HENC, W_loc, b_loc, W_sc, b_sc, eps, outloc, outsc, ZB);
  k_head3<<<64, 256, 0, stream>>>(ZB, W_dec, b_dec, Hst, HA0);
  k_zero<<<1, 256, 0, stream>>>((u32*)CNT, 128);

  // --- decoder: persistent cooperative kernel (64 steps) ---
  {
    const u16* a0 = WHHD3; const float* a1 = bhh_d; const float* a2 = GXD;
    u16* a3 = HA0; u16* a4 = HA1; float* a5 = Hst;
    float* a6 = H2F; u16* a7 = H2B;
    float* a8 = PART; int* a9 = CNT; int* a10 = ROOT;
    void* args[] = {&a0,&a1,&a2,&a3,&a4,&a5,&a6,&a7,&a8,&a9,&a10};
    hipError_t cd = hipLaunchCooperativeKernel(reinterpret_cast<void*>(&k_persist<1>),
                                               dim3(512), dim3(256), args, 0, stream);
    if (cd != hipSuccess) {
      for (int t = 0; t < Tt; t++) {
        const u16* hin = (t & 1) ? HA1 : HA0;
        u16* hout = (t & 1) ? HA0 : HA1;
        k_step2<1><<<512, 256, 0, stream>>>(WHHD3, bhh_d, GXD, hin, hout, Hst,
                                            H2F + (size_t)t * Bb * Hh,
                                            H2B + (size_t)t * Bb * Hh, PART, CNT);
      }
    }
  }

  // --- vocab projection: logits = h2 * Wvoc^T + b_voc  (M=4096, N=32000, K=1024) ---
  {
    dim3 g(Vv / 128, (Tt * Bb) / 128);
    gemm_bt<<<g, 256, 0, stream>>>(H2B, WVOC, b_voc, logits, Tt * Bb, Vv, Hh);
  }

  // --- softmax stats + exact argmax refinement ---
  k_rowred<<<Tt * Bb, 256, 0, stream>>>(logits, RM, SE, CC, CAND);
  k_refine<<<Tt * Bb, 256, 0, stream>>>(logits, H2F, W_voc, b_voc, RM, SE, CC, CAND, LSE, BV, BI);
  k_argmax<<<1, 64, 0, stream>>>(BV, BI, outseq);
  k_logp<<<2048, 256, 0, stream>>>(logits, LSE);
}

// Round 5
// 8472.672 us; speedup vs baseline: 1.6813x; 1.6813x over previous
//
#include <hip/hip_runtime.h>
#include <math.h>
#include <stdint.h>
#include <stddef.h>

typedef unsigned short u16;
typedef unsigned int   u32;
typedef __attribute__((ext_vector_type(8))) short short8;   // bf16x8 MFMA frag
typedef __attribute__((ext_vector_type(4))) float f32x4;

#define DI __device__ __forceinline__

// ---------------- problem constants ----------------
static constexpr int Vv = 32000, Ee = 512, Hh = 1024, Zz = 256;
static constexpr int Bb = 64, Ss = 256, Tt = 64;
static constexpr int G3 = 3 * Hh;            // 3072

// ---------------- workspace layout (bytes) ----------------
static constexpr size_t OFF_WHHE  = 0;                               // bf16 Whh_e [3072][1024]
static constexpr size_t SZ_WHH    = (size_t)G3 * Hh * 2;             // 6,291,456
static constexpr size_t OFF_WHHD  = OFF_WHHE + SZ_WHH;
static constexpr size_t OFF_WIHE3 = OFF_WHHD + SZ_WHH;
static constexpr size_t SZ_WIHE3  = (size_t)G3 * (3 * Ee) * 2;       // 9,437,184
static constexpr size_t OFF_WVOC  = OFF_WIHE3 + SZ_WIHE3;
static constexpr size_t SZ_WVOC   = (size_t)Vv * Hh * 2;             // 65,536,000
static constexpr size_t OFF_XS    = OFF_WVOC + SZ_WVOC;              // dead after gx GEMM
static constexpr size_t SZ_XS     = (size_t)Ss * Bb * (3 * Ee) * 2;  // 50,331,648
static constexpr size_t OFF_GX    = OFF_XS + SZ_XS;                  // (S,B,3H) f32
// overlay inside XS region (live only after gx GEMM consumed XS):
static constexpr size_t OFF_HA0  = OFF_XS;                           // [64][2048] hi|lo bf16
static constexpr size_t SZ_HA    = (size_t)Bb * 2 * Hh * 2;          // 262,144
static constexpr size_t OFF_HA1  = OFF_HA0 + SZ_HA;
static constexpr size_t OFF_H    = OFF_HA1 + SZ_HA;                  // [64][1024] f32
static constexpr size_t OFF_H2F  = OFF_H   + (size_t)Bb * Hh * 4;
static constexpr size_t OFF_H2B  = OFF_H2F + (size_t)Tt * Bb * Hh * 4;
static constexpr size_t OFF_GXD  = OFF_H2B + (size_t)Tt * Bb * Hh * 2;
static constexpr size_t OFF_HENC = OFF_GXD + 12288;
static constexpr size_t OFF_ZB   = OFF_HENC + (size_t)Bb * Zz * 4;
static constexpr size_t OFF_RM   = OFF_ZB + (size_t)Bb * Zz * 4;
static constexpr size_t OFF_SE   = OFF_RM + 16384;
static constexpr size_t OFF_LSE  = OFF_SE + 16384;
static constexpr size_t OFF_BV   = OFF_LSE + 16384;
static constexpr size_t OFF_BI   = OFF_BV + 16384;
static constexpr size_t OFF_CC   = OFF_BI + 16384;
static constexpr size_t OFF_CAND = OFF_CC + 16384;                   // 4096*32 ints

// ---------------- small helpers ----------------
DI u16 f2bf(float f) {                       // f32 -> bf16 RNE
  u32 u = __float_as_uint(f);
  u32 r = (u + 0x7FFFu + ((u >> 16) & 1u)) >> 16;
  return (u16)r;
}
DI float bf2f(u16 h) { return __uint_as_float(((u32)h) << 16); }

DI f32x4 mfma16(short8 a, short8 b, f32x4 c) {
  return __builtin_amdgcn_mfma_f32_16x16x32_bf16(a, b, c, 0, 0, 0);
}
DI void llds16(const u16* g, u16* l) {       // async global->LDS, 16B/lane
  __builtin_amdgcn_global_load_lds(
      (const __attribute__((address_space(1))) u32*)g,
      (__attribute__((address_space(3))) u32*)l, 16, 0, 0);
}

// ---------------- utility kernels ----------------
__global__ void k_zero(u32* p, int n) {
  for (int i = blockIdx.x * 256 + threadIdx.x; i < n; i += gridDim.x * 256) p[i] = 0;
}

// W (rows x kin) f32 -> tripled bf16 [W_hi | W_hi | W_lo] (rows x 3kin)  (gx GEMM only)
__global__ void k_trip(const float* __restrict__ W, u16* __restrict__ W3, int rows, int kin) {
  int n = rows * kin;
  for (int i = blockIdx.x * 256 + threadIdx.x; i < n; i += gridDim.x * 256) {
    int rr = i / kin, k = i - rr * kin;
    float v = W[i];
    u16 hi = f2bf(v);
    u16 lo = f2bf(v - bf2f(hi));
    u16* o = W3 + (size_t)rr * (3 * kin);
    o[k] = hi; o[kin + k] = hi; o[2 * kin + k] = lo;
  }
}

__global__ void k_tobf(const float* __restrict__ W, u16* __restrict__ Wb, int n) {
  for (int i = blockIdx.x * 256 + threadIdx.x; i < n; i += gridDim.x * 256) Wb[i] = f2bf(W[i]);
}

// x' = gathered embeddings split as [x_hi | x_lo | x_hi]  (matches B' = [W_hi|W_hi|W_lo])
__global__ void k_xsplit(const int* __restrict__ inp, const float* __restrict__ emb,
                         u16* __restrict__ xs) {
  int n = Ss * Bb * Ee;
  for (int i = blockIdx.x * 256 + threadIdx.x; i < n; i += gridDim.x * 256) {
    int m = i >> 9, k = i & (Ee - 1);
    int tok = inp[m];
    float v = emb[(size_t)tok * Ee + k];
    u16 hi = f2bf(v);
    u16 lo = f2bf(v - bf2f(hi));
    u16* o = xs + (size_t)m * (3 * Ee);
    o[k] = hi; o[Ee + k] = lo; o[2 * Ee + k] = hi;
  }
}

// gxd[g] = emb_dec[EOS] . Wih_d[g] + bih_d[g]   (exact f32, once)
__global__ void k_gxd(const float* __restrict__ emb_dec, const float* __restrict__ Wih_d,
                      const float* __restrict__ bih_d, float* __restrict__ gxd) {
  int g = blockIdx.x * 256 + threadIdx.x;
  if (g >= G3) return;
  const float* er = emb_dec + 2 * Ee;        // EOS_ID = 2
  const float* wr = Wih_d + (size_t)g * Ee;
  float s = 0.f;
  for (int e = 0; e < Ee; e++) s += er[e] * wr[e];
  gxd[g] = s + bih_d[g];
}

// ---------------- generic GEMM: C[m][n] = sum_k A[m][k]*B[n][k] + bias[n] ----------------
__global__ __launch_bounds__(256, 2) void gemm_bt(
    const u16* __restrict__ A, const u16* __restrict__ Bw, const float* __restrict__ bias,
    float* __restrict__ C, int M, int N, int K) {
  __shared__ __align__(16) u16 As[128 * 32];
  __shared__ __align__(16) u16 Bs[128 * 32];
  int tid = threadIdx.x;
  int wave = tid >> 6, lane = tid & 63;
  int wr = wave >> 1, wc = wave & 1;
  int m0 = blockIdx.y * 128, n0 = blockIdx.x * 128;
  f32x4 acc[4][4];
#pragma unroll
  for (int i = 0; i < 4; i++)
#pragma unroll
    for (int j = 0; j < 4; j++) acc[i][j] = (f32x4){0.f, 0.f, 0.f, 0.f};

  int lrow = lane >> 2, lcol = (lane & 3) * 8;
  int r15 = lane & 15, kk = (lane >> 4) * 8;

  for (int k0 = 0; k0 < K; k0 += 32) {
    __syncthreads();
#pragma unroll
    for (int rch = 0; rch < 2; rch++) {
      int c = rch * 4 + wave;
      int row = c * 16 + lrow;
      llds16(A  + (size_t)(m0 + row) * K + k0 + lcol, &As[c * 512]);
      llds16(Bw + (size_t)(n0 + row) * K + k0 + lcol, &Bs[c * 512]);
    }
    __syncthreads();
    short8 af[4], bfv[4];
#pragma unroll
    for (int mi = 0; mi < 4; mi++)
      af[mi] = *(const short8*)&As[(wr * 64 + mi * 16 + r15) * 32 + kk];
#pragma unroll
    for (int ni = 0; ni < 4; ni++)
      bfv[ni] = *(const short8*)&Bs[(wc * 64 + ni * 16 + r15) * 32 + kk];
#pragma unroll
    for (int mi = 0; mi < 4; mi++)
#pragma unroll
      for (int ni = 0; ni < 4; ni++) acc[mi][ni] = mfma16(af[mi], bfv[ni], acc[mi][ni]);
  }
#pragma unroll
  for (int mi = 0; mi < 4; mi++)
#pragma unroll
    for (int ni = 0; ni < 4; ni++) {
      int col = n0 + wc * 64 + ni * 16 + r15;
      float bs = bias[col];
#pragma unroll
      for (int i = 0; i < 4; i++) {
        int row = m0 + wr * 64 + mi * 16 + (lane >> 4) * 4 + i;
        C[(size_t)row * N + col] = acc[mi][ni][i] + bs;
      }
    }
}

// ---------------- one GRU step, dual-pass bf16, in-register epilogue ----------------
// grid 64 (j-tiles of 16 hidden dims), block 512 = 8 waves:
//   wave = (khalf<<2)|mw : mw -> batch rows mw*16..+15, khalf -> K-half (512 of 1024).
// acc[g] += mfma(h_hi, Wg) ; acc[g] += mfma(h_lo, Wg)   (dual-pass: same B frag twice)
// K-halves reduced via 12KB LDS; gates computed IN REGISTER (lane holds r,z,n of the
// same (b,j)); no global partials, no atomics, no sc ops -> dispatch-boundary coherence.
template <int DEC>
__global__ __launch_bounds__(512, 1) void k_step3(
    const u16* __restrict__ W, const float* __restrict__ bhh, const float* __restrict__ gxp,
    const u16* __restrict__ hAin, u16* __restrict__ hAout, float* __restrict__ h,
    float* __restrict__ h2f, u16* __restrict__ h2b) {
  __shared__ float sC[4][64][12];
  int tid = threadIdx.x, wave = tid >> 6, lane = tid & 63;
  int mw = wave & 3, khalf = wave >> 2;
  int m0 = mw * 16;
  int r15 = lane & 15, kk = (lane >> 4) * 8;
  int j0 = blockIdx.x * 16;
  int kbase = khalf * 512;

  f32x4 acc[3];
#pragma unroll
  for (int g = 0; g < 3; g++) acc[g] = (f32x4){0.f, 0.f, 0.f, 0.f};

  const u16* Ah = hAin + (size_t)(m0 + r15) * 2048 + kbase + kk;          // h_hi
  const u16* Bb = W + (size_t)(j0 + r15) * Hh + kbase + kk;               // gate r rows
#pragma unroll 4
  for (int ks = 0; ks < 16; ks++) {
    int ko = ks * 32;
    short8 ah = *(const short8*)(Ah + ko);
    short8 al = *(const short8*)(Ah + 1024 + ko);                          // h_lo
    short8 b0 = *(const short8*)(Bb + ko);
    short8 b1 = *(const short8*)(Bb + (size_t)Hh * Hh + ko);               // gate z
    short8 b2 = *(const short8*)(Bb + (size_t)2 * Hh * Hh + ko);           // gate n
    acc[0] = mfma16(ah, b0, acc[0]);
    acc[1] = mfma16(ah, b1, acc[1]);
    acc[2] = mfma16(ah, b2, acc[2]);
    acc[0] = mfma16(al, b0, acc[0]);
    acc[1] = mfma16(al, b1, acc[1]);
    acc[2] = mfma16(al, b2, acc[2]);
  }

  if (khalf == 1) {
#pragma unroll
    for (int g = 0; g < 3; g++)
#pragma unroll
      for (int i = 0; i < 4; i++) sC[mw][lane][g * 4 + i] = acc[g][i];
  }
  __syncthreads();
  if (khalf == 1) return;

  // ---- in-register gate epilogue: lane holds (b = m0+(lane>>4)*4+i, j = j0+r15) ----
  int j = j0 + r15;
  float br = bhh[j], bz = bhh[Hh + j], bn = bhh[2 * Hh + j];
  float xrD = 0.f, xzD = 0.f, xnD = 0.f;
  if (DEC) { xrD = gxp[j]; xzD = gxp[Hh + j]; xnD = gxp[2 * Hh + j]; }
#pragma unroll
  for (int i = 0; i < 4; i++) {
    int b = m0 + (lane >> 4) * 4 + i;
    float hgr = acc[0][i] + sC[mw][lane][i]     + br;     // fixed order -> deterministic
    float hgz = acc[1][i] + sC[mw][lane][4 + i] + bz;
    float hgn = acc[2][i] + sC[mw][lane][8 + i] + bn;
    float xr, xz, xn;
    if (DEC) { xr = xrD; xz = xzD; xn = xnD; }
    else {
      const float* gr = gxp + (size_t)b * G3;
      xr = gr[j]; xz = gr[Hh + j]; xn = gr[2 * Hh + j];
    }
    float rg = 1.0f / (1.0f + expf(-(xr + hgr)));
    float zg = 1.0f / (1.0f + expf(-(xz + hgz)));
    float ng = tanhf(xn + rg * hgn);
    float hold = h[(size_t)b * Hh + j];
    float hn = (1.0f - zg) * ng + zg * hold;
    h[(size_t)b * Hh + j] = hn;
    u16 hi = f2bf(hn);
    u16 lo = f2bf(hn - bf2f(hi));
    hAout[(size_t)b * 2048 + j] = hi;
    hAout[(size_t)b * 2048 + 1024 + j] = lo;
    if (DEC) {
      h2f[(size_t)b * Hh + j] = hn;
      h2b[(size_t)b * Hh + j] = hi;
    }
  }
}

// ---------------- heads (exact f32) ----------------
__global__ __launch_bounds__(256, 2) void k_head1(const float* __restrict__ h,
    const float* __restrict__ Wenc, const float* __restrict__ benc, float* __restrict__ henc) {
  int b = blockIdx.x;
  __shared__ float hs[Hh];
  for (int k = threadIdx.x; k < Hh; k += 256) hs[k] = h[(size_t)b * Hh + k];
  __syncthreads();
  int q = threadIdx.x;
  const float* wrw = Wenc + (size_t)q * Hh;
  float s = 0.f;
  for (int k = 0; k < Hh; k++) s += hs[k] * wrw[k];
  henc[b * Zz + q] = s + benc[q];
}

__global__ __launch_bounds__(256, 2) void k_head2(const float* __restrict__ henc,
    const float* __restrict__ Wloc, const float* __restrict__ bloc,
    const float* __restrict__ Wsc, const float* __restrict__ bsc,
    const float* __restrict__ eps, float* __restrict__ outLoc, float* __restrict__ outSc,
    float* __restrict__ zb) {
  int b = blockIdx.x;
  __shared__ float hs[Zz];
  if (threadIdx.x < Zz) hs[threadIdx.x] = henc[b * Zz + threadIdx.x];
  __syncthreads();
  int q = threadIdx.x;
  const float* wl = Wloc + (size_t)q * Zz;
  const float* wsp = Wsc + (size_t)q * Zz;
  float sl = 0.f, ssum = 0.f;
  for (int k = 0; k < Zz; k++) { sl += hs[k] * wl[k]; ssum += hs[k] * wsp[k]; }
  sl += bloc[q]; ssum += bsc[q];
  float sp = fmaxf(ssum, 0.f) + log1pf(expf(-fabsf(ssum)));  // softplus, stable
  float zv = sl + eps[b * Zz + q] * expf(0.5f * sp);
  outLoc[b * Zz + q] = sl;
  outSc[b * Zz + q] = sp;
  zb[b * Zz + q] = zv;
}

__global__ __launch_bounds__(256, 2) void k_head3(const float* __restrict__ zb,
    const float* __restrict__ Wdec, const float* __restrict__ bdec,
    float* __restrict__ h, u16* __restrict__ hA0) {
  int b = blockIdx.x;
  __shared__ float zs[Zz];
  if (threadIdx.x < Zz) zs[threadIdx.x] = zb[b * Zz + threadIdx.x];
  __syncthreads();
  for (int j = threadIdx.x; j < Hh; j += 256) {
    const float* wrw = Wdec + (size_t)j * Zz;
    float s = 0.f;
    for (int k = 0; k < Zz; k++) s += zs[k] * wrw[k];
    s += bdec[j];
    h[(size_t)b * Hh + j] = s;
    u16 hi = f2bf(s);
    u16 lo = f2bf(s - bf2f(hi));
    hA0[(size_t)b * 2048 + j] = hi;
    hA0[(size_t)b * 2048 + 1024 + j] = lo;
  }
}

// ---------------- row reduce: max, sumexp, candidates ----------------
__global__ __launch_bounds__(256, 2) void k_rowred(const float* __restrict__ logits,
    float* __restrict__ rowmax, float* __restrict__ sumexp, int* __restrict__ ccnt,
    int* __restrict__ cand) {
  int r = blockIdx.x;
  const float* row = logits + (size_t)r * Vv;
  __shared__ float red[4];
  __shared__ float srm;
  __shared__ int lcnt;
  __shared__ int lcand[32];
  int tid = threadIdx.x, wave = tid >> 6, lane = tid & 63;
  if (tid == 0) lcnt = 0;
  float m = -3.0e38f;
  for (int c = tid * 4; c < Vv; c += 1024) {
    f32x4 v = *(const f32x4*)(row + c);
    m = fmaxf(fmaxf(fmaxf(m, v.x), v.y), fmaxf(v.z, v.w));
  }
  for (int o = 32; o; o >>= 1) m = fmaxf(m, __shfl_xor(m, o));
  if (lane == 0) red[wave] = m;
  __syncthreads();
  if (tid == 0) srm = fmaxf(fmaxf(red[0], red[1]), fmaxf(red[2], red[3]));
  __syncthreads();
  float rm = srm;
  float s = 0.f;
  for (int c = tid * 4; c < Vv; c += 1024) {
    f32x4 v = *(const f32x4*)(row + c);
    s += expf(v.x - rm) + expf(v.y - rm) + expf(v.z - rm) + expf(v.w - rm);
    if (v.x >= rm - 0.0625f) { int sl = atomicAdd(&lcnt, 1); if (sl < 32) lcand[sl] = c; }
    if (v.y >= rm - 0.0625f) { int sl = atomicAdd(&lcnt, 1); if (sl < 32) lcand[sl] = c + 1; }
    if (v.z >= rm - 0.0625f) { int sl = atomicAdd(&lcnt, 1); if (sl < 32) lcand[sl] = c + 2; }
    if (v.w >= rm - 0.0625f) { int sl = atomicAdd(&lcnt, 1); if (sl < 32) lcand[sl] = c + 3; }
  }
  for (int o = 32; o; o >>= 1) s += __shfl_xor(s, o);
  if (lane == 0) red[wave] = s;
  __syncthreads();
  if (tid == 0) {
    float st = red[0] + red[1] + red[2] + red[3];
    int cc = lcnt < 32 ? lcnt : 32;
    for (int i = 0; i < cc; i++)
      for (int k2 = i + 1; k2 < cc; k2++)
        if (lcand[k2] < lcand[i]) { int t = lcand[i]; lcand[i] = lcand[k2]; lcand[k2] = t; }
    rowmax[r] = rm; sumexp[r] = st; ccnt[r] = cc;
    for (int i = 0; i < cc; i++) cand[r * 32 + i] = lcand[i];
  }
}

// ---------------- refine candidates exactly in f32, correct LSE, per-row best ----------------
__global__ __launch_bounds__(256, 1) void k_refine(const float* __restrict__ logits,
    const float* __restrict__ h2f, const float* __restrict__ Wvoc, const float* __restrict__ bvoc,
    const float* __restrict__ rowmax, const float* __restrict__ sumexp,
    const int* __restrict__ ccnt, const int* __restrict__ cand,
    float* __restrict__ lsec, float* __restrict__ bestv, int* __restrict__ besti) {
  int r = blockIdx.x;
  __shared__ float hrow[Hh];
  __shared__ float lex[32];
  __shared__ float del[32];
  int tid = threadIdx.x, wave = tid >> 6, lane = tid & 63;
  for (int k = tid; k < Hh; k += 256) hrow[k] = h2f[(size_t)r * Hh + k];
  int cnt = ccnt[r];
  float rm = rowmax[r];
  __syncthreads();
  for (int ci = wave; ci < cnt; ci += 4) {
    int v = cand[r * 32 + ci];
    const float* wrw = Wvoc + (size_t)v * Hh;
    float s = 0.f;
    for (int k = lane; k < Hh; k += 64) s += hrow[k] * wrw[k];
    for (int o = 32; o; o >>= 1) s += __shfl_xor(s, o);
    if (lane == 0) {
      float le = s + bvoc[v];
      lex[ci] = le;
      float la = logits[(size_t)r * Vv + v];
      del[ci] = expf(le - rm) - expf(la - rm);
    }
  }
  __syncthreads();
  if (tid == 0) {
    float se = sumexp[r];
    for (int i = 0; i < cnt; i++) se += del[i];
    float lse = rm + logf(se);
    lsec[r] = lse;
    float bv = -3.0e38f; int bvi = 0;
    for (int i = 0; i < cnt; i++)
      if (lex[i] > bv) { bv = lex[i]; bvi = cand[r * 32 + i]; }
    bestv[r] = bv - lse;
    besti[r] = (r & 63) * Vv + bvi;
  }
}

// ---------------- per-step global argmax -> seq ----------------
__global__ void k_argmax(const float* __restrict__ bestv, const int* __restrict__ besti,
                         float* __restrict__ outseq) {
  int tid = threadIdx.x;
  if (tid == 0) outseq[0] = 1.0f;
  for (int t = 0; t < Tt; t++) {
    float v = bestv[t * 64 + tid];
    int ii = besti[t * 64 + tid];
    for (int o = 1; o < 64; o <<= 1) {
      float ov = __shfl_xor(v, o);
      int oi = __shfl_xor(ii, o);
      if (ov > v || (ov == v && oi < ii)) { v = ov; ii = oi; }
    }
    if (tid == 0) outseq[1 + t] = (float)ii;
  }
}

// ---------------- in-place log-softmax: logits -= lse[row] ----------------
__global__ __launch_bounds__(256, 2) void k_logp(float* __restrict__ logits,
                                                 const float* __restrict__ lsec) {
  size_t total = (size_t)Tt * Bb * Vv / 4;
  for (size_t p = (size_t)blockIdx.x * 256 + threadIdx.x; p < total;
       p += (size_t)gridDim.x * 256) {
    int r = (int)(p / (Vv / 4));
    f32x4 v = *(f32x4*)(logits + p * 4);
    float l = lsec[r];
    v.x -= l; v.y -= l; v.z -= l; v.w -= l;
    *(f32x4*)(logits + p * 4) = v;
  }
}

// ---------------- host: launch sequence ----------------
extern "C" void kernel_launch(void* const* d_in, const int* in_sizes, int n_in,
                              void* d_out, int out_size, void* d_ws, size_t ws_size,
                              hipStream_t stream) {
  (void)in_sizes; (void)n_in; (void)out_size; (void)ws_size;
  const int*   inp     = (const int*)d_in[0];
  const float* eps     = (const float*)d_in[1];
  const float* emb_enc = (const float*)d_in[2];
  const float* Wih_e   = (const float*)d_in[3];
  const float* Whh_e   = (const float*)d_in[4];
  const float* bih_e   = (const float*)d_in[5];
  const float* bhh_e   = (const float*)d_in[6];
  const float* W_enc   = (const float*)d_in[7];
  const float* b_enc   = (const float*)d_in[8];
  const float* W_loc   = (const float*)d_in[9];
  const float* b_loc   = (const float*)d_in[10];
  const float* W_sc    = (const float*)d_in[11];
  const float* b_sc    = (const float*)d_in[12];
  const float* emb_dec = (const float*)d_in[13];
  const float* W_dec   = (const float*)d_in[14];
  const float* b_dec   = (const float*)d_in[15];
  const float* Wih_d   = (const float*)d_in[16];
  const float* Whh_d   = (const float*)d_in[17];
  const float* bih_d   = (const float*)d_in[18];
  const float* bhh_d   = (const float*)d_in[19];
  const float* W_voc   = (const float*)d_in[20];
  const float* b_voc   = (const float*)d_in[21];

  char* ws = (char*)d_ws;
  u16*   WHHE  = (u16*)(ws + OFF_WHHE);
  u16*   WHHD  = (u16*)(ws + OFF_WHHD);
  u16*   WIHE3 = (u16*)(ws + OFF_WIHE3);
  u16*   WVOC  = (u16*)(ws + OFF_WVOC);
  u16*   XS    = (u16*)(ws + OFF_XS);
  float* GX    = (float*)(ws + OFF_GX);
  u16*   HA0   = (u16*)(ws + OFF_HA0);
  u16*   HA1   = (u16*)(ws + OFF_HA1);
  float* Hst   = (float*)(ws + OFF_H);
  float* H2F   = (float*)(ws + OFF_H2F);
  u16*   H2B   = (u16*)(ws + OFF_H2B);
  float* GXD   = (float*)(ws + OFF_GXD);
  float* HENC  = (float*)(ws + OFF_HENC);
  float* ZB    = (float*)(ws + OFF_ZB);
  float* RM    = (float*)(ws + OFF_RM);
  float* SE    = (float*)(ws + OFF_SE);
  float* LSE   = (float*)(ws + OFF_LSE);
  float* BV    = (float*)(ws + OFF_BV);
  int*   BI    = (int*)(ws + OFF_BI);
  int*   CC    = (int*)(ws + OFF_CC);
  int*   CAND  = (int*)(ws + OFF_CAND);

  float* out     = (float*)d_out;
  float* logits  = out;                                   // (T*B, V) f32
  float* outseq  = out + (size_t)Tt * Bb * Vv;
  float* outloc  = outseq + (Tt + 1);
  float* outsc   = outloc + Bb * Zz;

  // --- weight conversions ---
  k_tobf<<<1024, 256, 0, stream>>>(Whh_e, WHHE, G3 * Hh);
  k_tobf<<<1024, 256, 0, stream>>>(Whh_d, WHHD, G3 * Hh);
  k_trip<<<512, 256, 0, stream>>>(Wih_e, WIHE3, G3, Ee);
  k_tobf<<<2048, 256, 0, stream>>>(W_voc, WVOC, Vv * Hh);
  k_xsplit<<<2048, 256, 0, stream>>>(inp, emb_enc, XS);

  // --- gx = x' * Wih_e3^T + bih_e   (M=16384, N=3072, K=1536) ---
  {
    dim3 g(G3 / 128, (Ss * Bb) / 128);
    gemm_bt<<<g, 256, 0, stream>>>(XS, WIHE3, bih_e, GX, Ss * Bb, G3, 3 * Ee);
  }
  k_gxd<<<12, 256, 0, stream>>>(emb_dec, Wih_d, bih_d, GXD);
  // zero HA0 | HA1 | H (contiguous, 3*256KB)
  k_zero<<<256, 256, 0, stream>>>((u32*)HA0, (int)((2 * SZ_HA + (size_t)Bb * Hh * 4) / 4));

  // --- encoder: 256 sequential GRU steps (64 blocks x 512 thr, dual-pass) ---
  for (int s = 0; s < Ss; s++) {
    const u16* hin = (s & 1) ? HA1 : HA0;
    u16* hout = (s & 1) ? HA0 : HA1;
    k_step3<0><<<64, 512, 0, stream>>>(WHHE, bhh_e, GX + (size_t)s * Bb * G3,
                                       hin, hout, Hst, nullptr, nullptr);
  }

  // --- heads ---
  k_head1<<<64, 256, 0, stream>>>(Hst, W_enc, b_enc, HENC);
  k_head2<<<64, 256, 0, stream>>>(HENC, W_loc, b_loc, W_sc, b_sc, eps, outloc, outsc, ZB);
  k_head3<<<64, 256, 0, stream>>>(ZB, W_dec, b_dec, Hst, HA0);

  // --- decoder: 64 sequential GRU steps ---
  for (int t = 0; t < Tt; t++) {
    const u16* hin = (t & 1) ? HA1 : HA0;
    u16* hout = (t & 1) ? HA0 : HA1;
    k_step3<1><<<64, 512, 0, stream>>>(WHHD, bhh_d, GXD, hin, hout, Hst,
                                       H2F + (size_t)t * Bb * Hh, H2B + (size_t)t * Bb * Hh);
  }

  // --- vocab projection: logits = h2 * Wvoc^T + b_voc  (M=4096, N=32000, K=1024) ---
  {
    dim3 g(Vv / 128, (Tt * Bb) / 128);
    gemm_bt<<<g, 256, 0, stream>>>(H2B, WVOC, b_voc, logits, Tt * Bb, Vv, Hh);
  }

  // --- softmax stats + exact argmax refinement ---
  k_rowred<<<Tt * Bb, 256, 0, stream>>>(logits, RM, SE, CC, CAND);
  k_refine<<<Tt * Bb, 256, 0, stream>>>(logits, H2F, W_voc, b_voc, RM, SE, CC, CAND, LSE, BV, BI);
  k_argmax<<<1, 64, 0, stream>>>(BV, BI, outseq);
  k_logp<<<2048, 256, 0, stream>>>(logits, LSE);
}

// Round 6
// 6463.614 us; speedup vs baseline: 2.2039x; 1.3108x over previous
//
#include <hip/hip_runtime.h>
#include <math.h>
#include <stdint.h>
#include <stddef.h>

typedef unsigned short u16;
typedef unsigned int   u32;
typedef __attribute__((ext_vector_type(8))) short short8;   // bf16x8 MFMA frag
typedef __attribute__((ext_vector_type(4))) float f32x4;

#define DI __device__ __forceinline__

// ---------------- problem constants ----------------
static constexpr int Vv = 32000, Ee = 512, Hh = 1024, Zz = 256;
static constexpr int Bb = 64, Ss = 256, Tt = 64;
static constexpr int G3 = 3 * Hh;            // 3072

// ---------------- workspace layout (bytes) ----------------
static constexpr size_t OFF_WHHE  = 0;                               // bf16 Whh_e [3072][1024]
static constexpr size_t SZ_WHH    = (size_t)G3 * Hh * 2;             // 6,291,456
static constexpr size_t OFF_WHHD  = OFF_WHHE + SZ_WHH;
static constexpr size_t OFF_WIHE3 = OFF_WHHD + SZ_WHH;
static constexpr size_t SZ_WIHE3  = (size_t)G3 * (3 * Ee) * 2;       // 9,437,184
static constexpr size_t OFF_WVOC  = OFF_WIHE3 + SZ_WIHE3;
static constexpr size_t SZ_WVOC   = (size_t)Vv * Hh * 2;             // 65,536,000
static constexpr size_t OFF_XS    = OFF_WVOC + SZ_WVOC;              // dead after gx GEMM
static constexpr size_t SZ_XS     = (size_t)Ss * Bb * (3 * Ee) * 2;  // 50,331,648
static constexpr size_t OFF_GX    = OFF_XS + SZ_XS;                  // (S,B,3H) f32
// overlay inside XS region (live only after gx GEMM consumed XS):
static constexpr size_t OFF_HA0  = OFF_XS;                           // [64][2048] hi|lo bf16
static constexpr size_t SZ_HA    = (size_t)Bb * 2 * Hh * 2;          // 262,144
static constexpr size_t OFF_HA1  = OFF_HA0 + SZ_HA;
static constexpr size_t OFF_H    = OFF_HA1 + SZ_HA;                  // [64][1024] f32
static constexpr size_t OFF_H2F  = OFF_H   + (size_t)Bb * Hh * 4;
static constexpr size_t OFF_H2B  = OFF_H2F + (size_t)Tt * Bb * Hh * 4;
static constexpr size_t OFF_GXD  = OFF_H2B + (size_t)Tt * Bb * Hh * 2;
static constexpr size_t OFF_HENC = OFF_GXD + 12288;
static constexpr size_t OFF_ZB   = OFF_HENC + (size_t)Bb * Zz * 4;
static constexpr size_t OFF_RM   = OFF_ZB + (size_t)Bb * Zz * 4;
static constexpr size_t OFF_SE   = OFF_RM + 16384;
static constexpr size_t OFF_LSE  = OFF_SE + 16384;
static constexpr size_t OFF_BV   = OFF_LSE + 16384;
static constexpr size_t OFF_BI   = OFF_BV + 16384;
static constexpr size_t OFF_CC   = OFF_BI + 16384;
static constexpr size_t OFF_CAND = OFF_CC + 16384;                   // 4096*32 ints
static constexpr size_t OFF_BAR  = OFF_CAND + (size_t)4096 * 32 * 4;

// ---------------- small helpers ----------------
DI u16 f2bf(float f) {                       // f32 -> bf16 RNE
  u32 u = __float_as_uint(f);
  u32 r = (u + 0x7FFFu + ((u >> 16) & 1u)) >> 16;
  return (u16)r;
}
DI float bf2f(u16 h) { return __uint_as_float(((u32)h) << 16); }

DI f32x4 mfma16(short8 a, short8 b, f32x4 c) {
  return __builtin_amdgcn_mfma_f32_16x16x32_bf16(a, b, c, 0, 0, 0);
}
DI void llds16(const u16* g, u16* l) {       // async global->LDS, 16B/lane
  __builtin_amdgcn_global_load_lds(
      (const __attribute__((address_space(1))) u32*)g,
      (__attribute__((address_space(3))) u32*)l, 16, 0, 0);
}

// agent-scope (device-coherent) access: sc-bit ops, no cache maintenance.
DI void ag_store_u32(u32* p, u32 v) {
  __hip_atomic_store(p, v, __ATOMIC_RELAXED, __HIP_MEMORY_SCOPE_AGENT);
}
DI u32 ag_load_u32(const u32* p) {
  return __hip_atomic_load((u32*)p, __ATOMIC_RELAXED, __HIP_MEMORY_SCOPE_AGENT);
}

// ---------------- utility kernels ----------------
__global__ void k_zero(u32* p, int n) {
  for (int i = blockIdx.x * 256 + threadIdx.x; i < n; i += gridDim.x * 256) p[i] = 0;
}

// W (rows x kin) f32 -> tripled bf16 [W_hi | W_hi | W_lo] (rows x 3kin)  (gx GEMM only)
__global__ void k_trip(const float* __restrict__ W, u16* __restrict__ W3, int rows, int kin) {
  int n = rows * kin;
  for (int i = blockIdx.x * 256 + threadIdx.x; i < n; i += gridDim.x * 256) {
    int rr = i / kin, k = i - rr * kin;
    float v = W[i];
    u16 hi = f2bf(v);
    u16 lo = f2bf(v - bf2f(hi));
    u16* o = W3 + (size_t)rr * (3 * kin);
    o[k] = hi; o[kin + k] = hi; o[2 * kin + k] = lo;
  }
}

__global__ void k_tobf(const float* __restrict__ W, u16* __restrict__ Wb, int n) {
  for (int i = blockIdx.x * 256 + threadIdx.x; i < n; i += gridDim.x * 256) Wb[i] = f2bf(W[i]);
}

// x' = gathered embeddings split as [x_hi | x_lo | x_hi]
__global__ void k_xsplit(const int* __restrict__ inp, const float* __restrict__ emb,
                         u16* __restrict__ xs) {
  int n = Ss * Bb * Ee;
  for (int i = blockIdx.x * 256 + threadIdx.x; i < n; i += gridDim.x * 256) {
    int m = i >> 9, k = i & (Ee - 1);
    int tok = inp[m];
    float v = emb[(size_t)tok * Ee + k];
    u16 hi = f2bf(v);
    u16 lo = f2bf(v - bf2f(hi));
    u16* o = xs + (size_t)m * (3 * Ee);
    o[k] = hi; o[Ee + k] = lo; o[2 * Ee + k] = hi;
  }
}

// gxd[g] = emb_dec[EOS] . Wih_d[g] + bih_d[g]   (exact f32, once)
__global__ void k_gxd(const float* __restrict__ emb_dec, const float* __restrict__ Wih_d,
                      const float* __restrict__ bih_d, float* __restrict__ gxd) {
  int g = blockIdx.x * 256 + threadIdx.x;
  if (g >= G3) return;
  const float* er = emb_dec + 2 * Ee;        // EOS_ID = 2
  const float* wr = Wih_d + (size_t)g * Ee;
  float s = 0.f;
  for (int e = 0; e < Ee; e++) s += er[e] * wr[e];
  gxd[g] = s + bih_d[g];
}

// ---------------- generic GEMM: C[m][n] = sum_k A[m][k]*B[n][k] + bias[n] ----------------
__global__ __launch_bounds__(256, 2) void gemm_bt(
    const u16* __restrict__ A, const u16* __restrict__ Bw, const float* __restrict__ bias,
    float* __restrict__ C, int M, int N, int K) {
  __shared__ __align__(16) u16 As[128 * 32];
  __shared__ __align__(16) u16 Bs[128 * 32];
  int tid = threadIdx.x;
  int wave = tid >> 6, lane = tid & 63;
  int wr = wave >> 1, wc = wave & 1;
  int m0 = blockIdx.y * 128, n0 = blockIdx.x * 128;
  f32x4 acc[4][4];
#pragma unroll
  for (int i = 0; i < 4; i++)
#pragma unroll
    for (int j = 0; j < 4; j++) acc[i][j] = (f32x4){0.f, 0.f, 0.f, 0.f};

  int lrow = lane >> 2, lcol = (lane & 3) * 8;
  int r15 = lane & 15, kk = (lane >> 4) * 8;

  for (int k0 = 0; k0 < K; k0 += 32) {
    __syncthreads();
#pragma unroll
    for (int rch = 0; rch < 2; rch++) {
      int c = rch * 4 + wave;
      int row = c * 16 + lrow;
      llds16(A  + (size_t)(m0 + row) * K + k0 + lcol, &As[c * 512]);
      llds16(Bw + (size_t)(n0 + row) * K + k0 + lcol, &Bs[c * 512]);
    }
    __syncthreads();
    short8 af[4], bfv[4];
#pragma unroll
    for (int mi = 0; mi < 4; mi++)
      af[mi] = *(const short8*)&As[(wr * 64 + mi * 16 + r15) * 32 + kk];
#pragma unroll
    for (int ni = 0; ni < 4; ni++)
      bfv[ni] = *(const short8*)&Bs[(wc * 64 + ni * 16 + r15) * 32 + kk];
#pragma unroll
    for (int mi = 0; mi < 4; mi++)
#pragma unroll
      for (int ni = 0; ni < 4; ni++) acc[mi][ni] = mfma16(af[mi], bfv[ni], acc[mi][ni]);
  }
#pragma unroll
  for (int mi = 0; mi < 4; mi++)
#pragma unroll
    for (int ni = 0; ni < 4; ni++) {
      int col = n0 + wc * 64 + ni * 16 + r15;
      float bs = bias[col];
#pragma unroll
      for (int i = 0; i < 4; i++) {
        int row = m0 + wr * 64 + mi * 16 + (lane >> 4) * 4 + i;
        C[(size_t)row * N + col] = acc[mi][ni][i] + bs;
      }
    }
}

// ---------------- persistent GRU phase ----------------
// grid 256 = 64 jt x 4 bq; block 256 = 4 waves splitting K=1024 into 4x256.
// Block owns output tile (16 b x 16 j): full-K sums via LDS reduce of 4 wave partials,
// gate epilogue in wave0's registers, h state lives in LDS (block-private, persistent).
// Cross-step exchange: hA hi/lo via agent-scope u32 L3 ops ONLY. W/gx plain (read-only,
// L2-resident). One monotonic-counter grid barrier per step (256 arrivals, tid0 polls).
template <int DEC>
__global__ __launch_bounds__(256, 2) void k_pers(
    const u16* __restrict__ W, const float* __restrict__ bhh, const float* __restrict__ gx0,
    u16* hA0buf, u16* hA1buf, float* Hst, float* h2f0, u16* h2b0, int* bar) {
  int tid = threadIdx.x, wave = tid >> 6, lane = tid & 63;
  int r15 = lane & 15, kk = (lane >> 4) * 8;
  int bq = blockIdx.x & 3, jt = blockIdx.x >> 2;
  int b0 = bq * 16, j0 = jt * 16;
  int kbase = wave * 256;
  const int NSTEP = DEC ? Tt : Ss;

  __shared__ float sC[3][64][12];              // wave 1..3 partials
  __shared__ float hT[256];                    // h tile [b_local][j_local] f32
  __shared__ __align__(16) u16 stg[2][16][16]; // hi/lo bf16 staging

  if (DEC) hT[tid] = Hst[(size_t)(b0 + (tid >> 4)) * Hh + j0 + (tid & 15)];
  else     hT[tid] = 0.f;

  int j = j0 + r15;
  float br = 0.f, bz = 0.f, bn = 0.f, xrD = 0.f, xzD = 0.f, xnD = 0.f;
  if (wave == 0) {
    br = bhh[j]; bz = bhh[Hh + j]; bn = bhh[2 * Hh + j];
    if (DEC) { xrD = gx0[j]; xzD = gx0[Hh + j]; xnD = gx0[2 * Hh + j]; }
  }
  __syncthreads();

  const u16* Wrow = W + (size_t)(j0 + r15) * Hh + kbase + kk;

  for (int st = 0; st < NSTEP; st++) {
    const u16* hAin = (st & 1) ? hA1buf : hA0buf;
    u16* hAout = (st & 1) ? hA0buf : hA1buf;

    // hoisted gx loads (encoder) -- issue before MFMA phase to hide latency
    float xr4[4], xz4[4], xn4[4];
    if (!DEC && wave == 0) {
#pragma unroll
      for (int i = 0; i < 4; i++) {
        int b = b0 + (lane >> 4) * 4 + i;
        const float* gr = gx0 + ((size_t)st * Bb + b) * G3;
        xr4[i] = gr[j]; xz4[i] = gr[Hh + j]; xn4[i] = gr[2 * Hh + j];
      }
    }

    f32x4 acc[3];
#pragma unroll
    for (int g = 0; g < 3; g++) acc[g] = (f32x4){0.f, 0.f, 0.f, 0.f};
    const u16* Ab = hAin + (size_t)(b0 + r15) * 2048 + kbase + kk;
#pragma unroll 4
    for (int ks = 0; ks < 8; ks++) {
      int ko = ks * 32;
      union { u32 w[4]; short8 v; } ah, al;
      const u32* pa = (const u32*)(Ab + ko);
      const u32* pl = (const u32*)(Ab + 1024 + ko);
#pragma unroll
      for (int q = 0; q < 4; q++) { ah.w[q] = ag_load_u32(pa + q); al.w[q] = ag_load_u32(pl + q); }
      short8 w0 = *(const short8*)(Wrow + ko);
      short8 w1 = *(const short8*)(Wrow + (size_t)Hh * Hh + ko);
      short8 w2 = *(const short8*)(Wrow + (size_t)2 * Hh * Hh + ko);
      acc[0] = mfma16(ah.v, w0, acc[0]);
      acc[1] = mfma16(ah.v, w1, acc[1]);
      acc[2] = mfma16(ah.v, w2, acc[2]);
      acc[0] = mfma16(al.v, w0, acc[0]);
      acc[1] = mfma16(al.v, w1, acc[1]);
      acc[2] = mfma16(al.v, w2, acc[2]);
    }

    if (wave != 0) {
#pragma unroll
      for (int g = 0; g < 3; g++)
#pragma unroll
        for (int i = 0; i < 4; i++) sC[wave - 1][lane][g * 4 + i] = acc[g][i];
    }
    __syncthreads();

    if (wave == 0) {
#pragma unroll
      for (int i = 0; i < 4; i++) {
        int bl = (lane >> 4) * 4 + i;
        float hgr = acc[0][i] + sC[0][lane][i]     + sC[1][lane][i]     + sC[2][lane][i]     + br;
        float hgz = acc[1][i] + sC[0][lane][4 + i] + sC[1][lane][4 + i] + sC[2][lane][4 + i] + bz;
        float hgn = acc[2][i] + sC[0][lane][8 + i] + sC[1][lane][8 + i] + sC[2][lane][8 + i] + bn;
        float xr = DEC ? xrD : xr4[i];
        float xz = DEC ? xzD : xz4[i];
        float xn = DEC ? xnD : xn4[i];
        float rg = 1.0f / (1.0f + expf(-(xr + hgr)));
        float zg = 1.0f / (1.0f + expf(-(xz + hgz)));
        float ng = tanhf(xn + rg * hgn);
        float hold = hT[bl * 16 + r15];
        float hn = (1.0f - zg) * ng + zg * hold;
        hT[bl * 16 + r15] = hn;
        u16 hi = f2bf(hn), lo = f2bf(hn - bf2f(hi));
        stg[0][bl][r15] = hi;
        stg[1][bl][r15] = lo;
      }
    }
    __syncthreads();

    // distributed stores: 256 threads, one sc u32 each (hi|lo tile -> L3)
    {
      int part = tid >> 7, idx = tid & 127, row = idx >> 3, dw = idx & 7;
      u32 val = ((const u32*)&stg[part][row][0])[dw];
      ag_store_u32((u32*)(hAout + (size_t)(b0 + row) * 2048 + part * 1024 + j0) + dw, val);
      if (DEC) {
        float* h2f = h2f0 + (size_t)st * Bb * Hh;
        h2f[(size_t)(b0 + (tid >> 4)) * Hh + j0 + (tid & 15)] = hT[tid];
        if (tid < 128) {
          u16* h2b = h2b0 + (size_t)st * Bb * Hh;
          ((u32*)(h2b + (size_t)(b0 + row) * Hh + j0))[dw] = ((const u32*)&stg[0][row][0])[dw];
        }
      }
    }

    if (st + 1 < NSTEP) {
      asm volatile("s_waitcnt vmcnt(0)" ::: "memory");   // own sc stores at L3
      __syncthreads();
      if (tid == 0) {
        __hip_atomic_fetch_add(bar, 1, __ATOMIC_RELAXED, __HIP_MEMORY_SCOPE_AGENT);
        int target = (int)gridDim.x * (st + 1);
        while (__hip_atomic_load(bar, __ATOMIC_RELAXED, __HIP_MEMORY_SCOPE_AGENT) < target)
          __builtin_amdgcn_s_sleep(1);
      }
      __syncthreads();                                    // orders next step's loads
    }
  }

  if (!DEC)
    Hst[(size_t)(b0 + (tid >> 4)) * Hh + j0 + (tid & 15)] = hT[tid];
}

// ---------------- fallback per-step kernel (R5 path, if coop launch fails) ----------------
template <int DEC>
__global__ __launch_bounds__(512, 1) void k_step3(
    const u16* __restrict__ W, const float* __restrict__ bhh, const float* __restrict__ gxp,
    const u16* __restrict__ hAin, u16* __restrict__ hAout, float* __restrict__ h,
    float* __restrict__ h2f, u16* __restrict__ h2b) {
  __shared__ float sC[4][64][12];
  int tid = threadIdx.x, wave = tid >> 6, lane = tid & 63;
  int mw = wave & 3, khalf = wave >> 2;
  int m0 = mw * 16;
  int r15 = lane & 15, kk = (lane >> 4) * 8;
  int j0 = blockIdx.x * 16;
  int kbase = khalf * 512;

  f32x4 acc[3];
#pragma unroll
  for (int g = 0; g < 3; g++) acc[g] = (f32x4){0.f, 0.f, 0.f, 0.f};

  const u16* Ah = hAin + (size_t)(m0 + r15) * 2048 + kbase + kk;
  const u16* Wr = W + (size_t)(j0 + r15) * Hh + kbase + kk;
#pragma unroll 4
  for (int ks = 0; ks < 16; ks++) {
    int ko = ks * 32;
    short8 ah = *(const short8*)(Ah + ko);
    short8 al = *(const short8*)(Ah + 1024 + ko);
    short8 b0 = *(const short8*)(Wr + ko);
    short8 b1 = *(const short8*)(Wr + (size_t)Hh * Hh + ko);
    short8 b2 = *(const short8*)(Wr + (size_t)2 * Hh * Hh + ko);
    acc[0] = mfma16(ah, b0, acc[0]);
    acc[1] = mfma16(ah, b1, acc[1]);
    acc[2] = mfma16(ah, b2, acc[2]);
    acc[0] = mfma16(al, b0, acc[0]);
    acc[1] = mfma16(al, b1, acc[1]);
    acc[2] = mfma16(al, b2, acc[2]);
  }

  if (khalf == 1) {
#pragma unroll
    for (int g = 0; g < 3; g++)
#pragma unroll
      for (int i = 0; i < 4; i++) sC[mw][lane][g * 4 + i] = acc[g][i];
  }
  __syncthreads();
  if (khalf == 1) return;

  int j = j0 + r15;
  float br = bhh[j], bz = bhh[Hh + j], bn = bhh[2 * Hh + j];
  float xrD = 0.f, xzD = 0.f, xnD = 0.f;
  if (DEC) { xrD = gxp[j]; xzD = gxp[Hh + j]; xnD = gxp[2 * Hh + j]; }
#pragma unroll
  for (int i = 0; i < 4; i++) {
    int b = m0 + (lane >> 4) * 4 + i;
    float hgr = acc[0][i] + sC[mw][lane][i]     + br;
    float hgz = acc[1][i] + sC[mw][lane][4 + i] + bz;
    float hgn = acc[2][i] + sC[mw][lane][8 + i] + bn;
    float xr, xz, xn;
    if (DEC) { xr = xrD; xz = xzD; xn = xnD; }
    else {
      const float* gr = gxp + (size_t)b * G3;
      xr = gr[j]; xz = gr[Hh + j]; xn = gr[2 * Hh + j];
    }
    float rg = 1.0f / (1.0f + expf(-(xr + hgr)));
    float zg = 1.0f / (1.0f + expf(-(xz + hgz)));
    float ng = tanhf(xn + rg * hgn);
    float hold = h[(size_t)b * Hh + j];
    float hn = (1.0f - zg) * ng + zg * hold;
    h[(size_t)b * Hh + j] = hn;
    u16 hi = f2bf(hn);
    u16 lo = f2bf(hn - bf2f(hi));
    hAout[(size_t)b * 2048 + j] = hi;
    hAout[(size_t)b * 2048 + 1024 + j] = lo;
    if (DEC) {
      h2f[(size_t)b * Hh + j] = hn;
      h2b[(size_t)b * Hh + j] = hi;
    }
  }
}

// ---------------- heads (exact f32) ----------------
__global__ __launch_bounds__(256, 2) void k_head1(const float* __restrict__ h,
    const float* __restrict__ Wenc, const float* __restrict__ benc, float* __restrict__ henc) {
  int b = blockIdx.x;
  __shared__ float hs[Hh];
  for (int k = threadIdx.x; k < Hh; k += 256) hs[k] = h[(size_t)b * Hh + k];
  __syncthreads();
  int q = threadIdx.x;
  const float* wrw = Wenc + (size_t)q * Hh;
  float s = 0.f;
  for (int k = 0; k < Hh; k++) s += hs[k] * wrw[k];
  henc[b * Zz + q] = s + benc[q];
}

__global__ __launch_bounds__(256, 2) void k_head2(const float* __restrict__ henc,
    const float* __restrict__ Wloc, const float* __restrict__ bloc,
    const float* __restrict__ Wsc, const float* __restrict__ bsc,
    const float* __restrict__ eps, float* __restrict__ outLoc, float* __restrict__ outSc,
    float* __restrict__ zb) {
  int b = blockIdx.x;
  __shared__ float hs[Zz];
  if (threadIdx.x < Zz) hs[threadIdx.x] = henc[b * Zz + threadIdx.x];
  __syncthreads();
  int q = threadIdx.x;
  const float* wl = Wloc + (size_t)q * Zz;
  const float* wsp = Wsc + (size_t)q * Zz;
  float sl = 0.f, ssum = 0.f;
  for (int k = 0; k < Zz; k++) { sl += hs[k] * wl[k]; ssum += hs[k] * wsp[k]; }
  sl += bloc[q]; ssum += bsc[q];
  float sp = fmaxf(ssum, 0.f) + log1pf(expf(-fabsf(ssum)));  // softplus, stable
  float zv = sl + eps[b * Zz + q] * expf(0.5f * sp);
  outLoc[b * Zz + q] = sl;
  outSc[b * Zz + q] = sp;
  zb[b * Zz + q] = zv;
}

__global__ __launch_bounds__(256, 2) void k_head3(const float* __restrict__ zb,
    const float* __restrict__ Wdec, const float* __restrict__ bdec,
    float* __restrict__ h, u16* __restrict__ hA0) {
  int b = blockIdx.x;
  __shared__ float zs[Zz];
  if (threadIdx.x < Zz) zs[threadIdx.x] = zb[b * Zz + threadIdx.x];
  __syncthreads();
  for (int j = threadIdx.x; j < Hh; j += 256) {
    const float* wrw = Wdec + (size_t)j * Zz;
    float s = 0.f;
    for (int k = 0; k < Zz; k++) s += zs[k] * wrw[k];
    s += bdec[j];
    h[(size_t)b * Hh + j] = s;
    u16 hi = f2bf(s);
    u16 lo = f2bf(s - bf2f(hi));
    hA0[(size_t)b * 2048 + j] = hi;
    hA0[(size_t)b * 2048 + 1024 + j] = lo;
  }
}

// ---------------- row reduce: max, sumexp, candidates ----------------
__global__ __launch_bounds__(256, 2) void k_rowred(const float* __restrict__ logits,
    float* __restrict__ rowmax, float* __restrict__ sumexp, int* __restrict__ ccnt,
    int* __restrict__ cand) {
  int r = blockIdx.x;
  const float* row = logits + (size_t)r * Vv;
  __shared__ float red[4];
  __shared__ float srm;
  __shared__ int lcnt;
  __shared__ int lcand[32];
  int tid = threadIdx.x, wave = tid >> 6, lane = tid & 63;
  if (tid == 0) lcnt = 0;
  float m = -3.0e38f;
  for (int c = tid * 4; c < Vv; c += 1024) {
    f32x4 v = *(const f32x4*)(row + c);
    m = fmaxf(fmaxf(fmaxf(m, v.x), v.y), fmaxf(v.z, v.w));
  }
  for (int o = 32; o; o >>= 1) m = fmaxf(m, __shfl_xor(m, o));
  if (lane == 0) red[wave] = m;
  __syncthreads();
  if (tid == 0) srm = fmaxf(fmaxf(red[0], red[1]), fmaxf(red[2], red[3]));
  __syncthreads();
  float rm = srm;
  float s = 0.f;
  for (int c = tid * 4; c < Vv; c += 1024) {
    f32x4 v = *(const f32x4*)(row + c);
    s += expf(v.x - rm) + expf(v.y - rm) + expf(v.z - rm) + expf(v.w - rm);
    if (v.x >= rm - 0.0625f) { int sl = atomicAdd(&lcnt, 1); if (sl < 32) lcand[sl] = c; }
    if (v.y >= rm - 0.0625f) { int sl = atomicAdd(&lcnt, 1); if (sl < 32) lcand[sl] = c + 1; }
    if (v.z >= rm - 0.0625f) { int sl = atomicAdd(&lcnt, 1); if (sl < 32) lcand[sl] = c + 2; }
    if (v.w >= rm - 0.0625f) { int sl = atomicAdd(&lcnt, 1); if (sl < 32) lcand[sl] = c + 3; }
  }
  for (int o = 32; o; o >>= 1) s += __shfl_xor(s, o);
  if (lane == 0) red[wave] = s;
  __syncthreads();
  if (tid == 0) {
    float st = red[0] + red[1] + red[2] + red[3];
    int cc = lcnt < 32 ? lcnt : 32;
    for (int i = 0; i < cc; i++)
      for (int k2 = i + 1; k2 < cc; k2++)
        if (lcand[k2] < lcand[i]) { int t = lcand[i]; lcand[i] = lcand[k2]; lcand[k2] = t; }
    rowmax[r] = rm; sumexp[r] = st; ccnt[r] = cc;
    for (int i = 0; i < cc; i++) cand[r * 32 + i] = lcand[i];
  }
}

// ---------------- refine candidates exactly in f32, correct LSE, per-row best ----------------
__global__ __launch_bounds__(256, 1) void k_refine(const float* __restrict__ logits,
    const float* __restrict__ h2f, const float* __restrict__ Wvoc, const float* __restrict__ bvoc,
    const float* __restrict__ rowmax, const float* __restrict__ sumexp,
    const int* __restrict__ ccnt, const int* __restrict__ cand,
    float* __restrict__ lsec, float* __restrict__ bestv, int* __restrict__ besti) {
  int r = blockIdx.x;
  __shared__ float hrow[Hh];
  __shared__ float lex[32];
  __shared__ float del[32];
  int tid = threadIdx.x, wave = tid >> 6, lane = tid & 63;
  for (int k = tid; k < Hh; k += 256) hrow[k] = h2f[(size_t)r * Hh + k];
  int cnt = ccnt[r];
  float rm = rowmax[r];
  __syncthreads();
  for (int ci = wave; ci < cnt; ci += 4) {
    int v = cand[r * 32 + ci];
    const float* wrw = Wvoc + (size_t)v * Hh;
    float s = 0.f;
    for (int k = lane; k < Hh; k += 64) s += hrow[k] * wrw[k];
    for (int o = 32; o; o >>= 1) s += __shfl_xor(s, o);
    if (lane == 0) {
      float le = s + bvoc[v];
      lex[ci] = le;
      float la = logits[(size_t)r * Vv + v];
      del[ci] = expf(le - rm) - expf(la - rm);
    }
  }
  __syncthreads();
  if (tid == 0) {
    float se = sumexp[r];
    for (int i = 0; i < cnt; i++) se += del[i];
    float lse = rm + logf(se);
    lsec[r] = lse;
    float bv = -3.0e38f; int bvi = 0;
    for (int i = 0; i < cnt; i++)
      if (lex[i] > bv) { bv = lex[i]; bvi = cand[r * 32 + i]; }
    bestv[r] = bv - lse;
    besti[r] = (r & 63) * Vv + bvi;
  }
}

// ---------------- per-step global argmax -> seq ----------------
__global__ void k_argmax(const float* __restrict__ bestv, const int* __restrict__ besti,
                         float* __restrict__ outseq) {
  int tid = threadIdx.x;
  if (tid == 0) outseq[0] = 1.0f;
  for (int t = 0; t < Tt; t++) {
    float v = bestv[t * 64 + tid];
    int ii = besti[t * 64 + tid];
    for (int o = 1; o < 64; o <<= 1) {
      float ov = __shfl_xor(v, o);
      int oi = __shfl_xor(ii, o);
      if (ov > v || (ov == v && oi < ii)) { v = ov; ii = oi; }
    }
    if (tid == 0) outseq[1 + t] = (float)ii;
  }
}

// ---------------- in-place log-softmax: logits -= lse[row] ----------------
__global__ __launch_bounds__(256, 2) void k_logp(float* __restrict__ logits,
                                                 const float* __restrict__ lsec) {
  size_t total = (size_t)Tt * Bb * Vv / 4;
  for (size_t p = (size_t)blockIdx.x * 256 + threadIdx.x; p < total;
       p += (size_t)gridDim.x * 256) {
    int r = (int)(p / (Vv / 4));
    f32x4 v = *(f32x4*)(logits + p * 4);
    float l = lsec[r];
    v.x -= l; v.y -= l; v.z -= l; v.w -= l;
    *(f32x4*)(logits + p * 4) = v;
  }
}

// ---------------- host: launch sequence ----------------
extern "C" void kernel_launch(void* const* d_in, const int* in_sizes, int n_in,
                              void* d_out, int out_size, void* d_ws, size_t ws_size,
                              hipStream_t stream) {
  (void)in_sizes; (void)n_in; (void)out_size; (void)ws_size;
  const int*   inp     = (const int*)d_in[0];
  const float* eps     = (const float*)d_in[1];
  const float* emb_enc = (const float*)d_in[2];
  const float* Wih_e   = (const float*)d_in[3];
  const float* Whh_e   = (const float*)d_in[4];
  const float* bih_e   = (const float*)d_in[5];
  const float* bhh_e   = (const float*)d_in[6];
  const float* W_enc   = (const float*)d_in[7];
  const float* b_enc   = (const float*)d_in[8];
  const float* W_loc   = (const float*)d_in[9];
  const float* b_loc   = (const float*)d_in[10];
  const float* W_sc    = (const float*)d_in[11];
  const float* b_sc    = (const float*)d_in[12];
  const float* emb_dec = (const float*)d_in[13];
  const float* W_dec   = (const float*)d_in[14];
  const float* b_dec   = (const float*)d_in[15];
  const float* Wih_d   = (const float*)d_in[16];
  const float* Whh_d   = (const float*)d_in[17];
  const float* bih_d   = (const float*)d_in[18];
  const float* bhh_d   = (const float*)d_in[19];
  const float* W_voc   = (const float*)d_in[20];
  const float* b_voc   = (const float*)d_in[21];

  char* ws = (char*)d_ws;
  u16*   WHHE  = (u16*)(ws + OFF_WHHE);
  u16*   WHHD  = (u16*)(ws + OFF_WHHD);
  u16*   WIHE3 = (u16*)(ws + OFF_WIHE3);
  u16*   WVOC  = (u16*)(ws + OFF_WVOC);
  u16*   XS    = (u16*)(ws + OFF_XS);
  float* GX    = (float*)(ws + OFF_GX);
  u16*   HA0   = (u16*)(ws + OFF_HA0);
  u16*   HA1   = (u16*)(ws + OFF_HA1);
  float* Hst   = (float*)(ws + OFF_H);
  float* H2F   = (float*)(ws + OFF_H2F);
  u16*   H2B   = (u16*)(ws + OFF_H2B);
  float* GXD   = (float*)(ws + OFF_GXD);
  float* HENC  = (float*)(ws + OFF_HENC);
  float* ZB    = (float*)(ws + OFF_ZB);
  float* RM    = (float*)(ws + OFF_RM);
  float* SE    = (float*)(ws + OFF_SE);
  float* LSE   = (float*)(ws + OFF_LSE);
  float* BV    = (float*)(ws + OFF_BV);
  int*   BI    = (int*)(ws + OFF_BI);
  int*   CC    = (int*)(ws + OFF_CC);
  int*   CAND  = (int*)(ws + OFF_CAND);
  int*   BAR   = (int*)(ws + OFF_BAR);

  float* out     = (float*)d_out;
  float* logits  = out;                                   // (T*B, V) f32
  float* outseq  = out + (size_t)Tt * Bb * Vv;
  float* outloc  = outseq + (Tt + 1);
  float* outsc   = outloc + Bb * Zz;

  // --- weight conversions ---
  k_tobf<<<1024, 256, 0, stream>>>(Whh_e, WHHE, G3 * Hh);
  k_tobf<<<1024, 256, 0, stream>>>(Whh_d, WHHD, G3 * Hh);
  k_trip<<<512, 256, 0, stream>>>(Wih_e, WIHE3, G3, Ee);
  k_tobf<<<2048, 256, 0, stream>>>(W_voc, WVOC, Vv * Hh);
  k_xsplit<<<2048, 256, 0, stream>>>(inp, emb_enc, XS);

  // --- gx = x' * Wih_e3^T + bih_e   (M=16384, N=3072, K=1536) ---
  {
    dim3 g(G3 / 128, (Ss * Bb) / 128);
    gemm_bt<<<g, 256, 0, stream>>>(XS, WIHE3, bih_e, GX, Ss * Bb, G3, 3 * Ee);
  }
  k_gxd<<<12, 256, 0, stream>>>(emb_dec, Wih_d, bih_d, GXD);
  // zero HA0 | HA1 | Hst (contiguous) and BAR
  k_zero<<<256, 256, 0, stream>>>((u32*)HA0, (int)((2 * SZ_HA + (size_t)Bb * Hh * 4) / 4));
  k_zero<<<1, 64, 0, stream>>>((u32*)BAR, 16);

  // --- encoder: persistent cooperative (256 steps), fallback = per-step loop ---
  hipError_t ce;
  {
    const u16* a0 = WHHE; const float* a1 = bhh_e; const float* a2 = GX;
    u16* a3 = HA0; u16* a4 = HA1; float* a5 = Hst;
    float* a6 = nullptr; u16* a7 = nullptr; int* a8 = BAR;
    void* args[] = {&a0,&a1,&a2,&a3,&a4,&a5,&a6,&a7,&a8};
    ce = hipLaunchCooperativeKernel(reinterpret_cast<void*>(&k_pers<0>),
                                    dim3(256), dim3(256), args, 0, stream);
  }
  if (ce != hipSuccess) {
    for (int s = 0; s < Ss; s++) {
      const u16* hin = (s & 1) ? HA1 : HA0;
      u16* hout = (s & 1) ? HA0 : HA1;
      k_step3<0><<<64, 512, 0, stream>>>(WHHE, bhh_e, GX + (size_t)s * Bb * G3,
                                         hin, hout, Hst, nullptr, nullptr);
    }
  }

  // --- heads ---
  k_head1<<<64, 256, 0, stream>>>(Hst, W_enc, b_enc, HENC);
  k_head2<<<64, 256, 0, stream>>>(HENC, W_loc, b_loc, W_sc, b_sc, eps, outloc, outsc, ZB);
  k_head3<<<64, 256, 0, stream>>>(ZB, W_dec, b_dec, Hst, HA0);
  k_zero<<<1, 64, 0, stream>>>((u32*)BAR, 16);

  // --- decoder: persistent cooperative (64 steps), fallback = per-step loop ---
  {
    const u16* a0 = WHHD; const float* a1 = bhh_d; const float* a2 = GXD;
    u16* a3 = HA0; u16* a4 = HA1; float* a5 = Hst;
    float* a6 = H2F; u16* a7 = H2B; int* a8 = BAR;
    void* args[] = {&a0,&a1,&a2,&a3,&a4,&a5,&a6,&a7,&a8};
    hipError_t cd = hipLaunchCooperativeKernel(reinterpret_cast<void*>(&k_pers<1>),
                                               dim3(256), dim3(256), args, 0, stream);
    if (cd != hipSuccess) {
      for (int t = 0; t < Tt; t++) {
        const u16* hin = (t & 1) ? HA1 : HA0;
        u16* hout = (t & 1) ? HA0 : HA1;
        k_step3<1><<<64, 512, 0, stream>>>(WHHD, bhh_d, GXD, hin, hout, Hst,
                                           H2F + (size_t)t * Bb * Hh,
                                           H2B + (size_t)t * Bb * Hh);
      }
    }
  }

  // --- vocab projection: logits = h2 * Wvoc^T + b_voc  (M=4096, N=32000, K=1024) ---
  {
    dim3 g(Vv / 128, (Tt * Bb) / 128);
    gemm_bt<<<g, 256, 0, stream>>>(H2B, WVOC, b_voc, logits, Tt * Bb, Vv, Hh);
  }

  // --- softmax stats + exact argmax refinement ---
  k_rowred<<<Tt * Bb, 256, 0, stream>>>(logits, RM, SE, CC, CAND);
  k_refine<<<Tt * Bb, 256, 0, stream>>>(logits, H2F, W_voc, b_voc, RM, SE, CC, CAND, LSE, BV, BI);
  k_argmax<<<1, 64, 0, stream>>>(BV, BI, outseq);
  k_logp<<<2048, 256, 0, stream>>>(logits, LSE);
}

// Round 7
// 3747.005 us; speedup vs baseline: 3.8017x; 1.7250x over previous
//
#include <hip/hip_runtime.h>
#include <math.h>
#include <stdint.h>
#include <stddef.h>

typedef unsigned short u16;
typedef unsigned int   u32;
typedef __attribute__((ext_vector_type(8))) short short8;   // bf16x8 MFMA frag
typedef __attribute__((ext_vector_type(4))) float f32x4;

#define DI __device__ __forceinline__

// ---------------- problem constants ----------------
static constexpr int Vv = 32000, Ee = 512, Hh = 1024, Zz = 256;
static constexpr int Bb = 64, Ss = 256, Tt = 64;
static constexpr int G3 = 3 * Hh;            // 3072

// ---------------- workspace layout (bytes) ----------------
// peak usage 357.0 MB — below the 364.4 MB proven in rounds 1-3.
static constexpr size_t OFF_WHHE  = 0;                               // bf16 [3072][1024]
static constexpr size_t SZ_WHH    = (size_t)G3 * Hh * 2;             // 6,291,456
static constexpr size_t OFF_WHHD  = OFF_WHHE + SZ_WHH;               // 6,291,456
static constexpr size_t OFF_WIHE3 = OFF_WHHD + SZ_WHH;               // 12,582,912 (buf region B after gx GEMM)
static constexpr size_t SZ_WIHE3  = (size_t)G3 * (3 * Ee) * 2;       // 9,437,184
static constexpr size_t OFF_WVOC  = OFF_WIHE3 + SZ_WIHE3;            // 22,020,096
static constexpr size_t SZ_WVOC   = (size_t)Vv * Hh * 2;             // 65,536,000
static constexpr size_t OFF_XS    = OFF_WVOC + SZ_WVOC;              // 87,556,096 (buf region A after gx GEMM)
static constexpr size_t SZ_XS     = (size_t)Ss * Bb * (3 * Ee) * 2;  // 50,331,648
static constexpr size_t OFF_GX    = OFF_XS + SZ_XS;                  // 137,887,744
static constexpr size_t SZ_GX     = (size_t)Ss * Bb * G3 * 4;        // 201,326,592
static constexpr size_t OFF_H2B   = OFF_GX;                          // overlay: GX slices 0..10 dead long before decoder
static constexpr size_t OFF_H2F   = OFF_GX + SZ_GX;                  // 339,214,336 (buf region C during encoder)
static constexpr size_t SZ_H2F    = (size_t)Tt * Bb * Hh * 4;        // 16,777,216
static constexpr size_t OFF_H     = OFF_H2F + SZ_H2F;                // 355,991,552
static constexpr size_t OFF_GXD   = OFF_H + (size_t)Bb * Hh * 4;
static constexpr size_t OFF_HENC  = OFF_GXD + 12288;
static constexpr size_t OFF_ZB    = OFF_HENC + (size_t)Bb * Zz * 4;
static constexpr size_t OFF_RM    = OFF_ZB + (size_t)Bb * Zz * 4;
static constexpr size_t OFF_SE    = OFF_RM + 16384;
static constexpr size_t OFF_LSE   = OFF_SE + 16384;
static constexpr size_t OFF_BV    = OFF_LSE + 16384;
static constexpr size_t OFF_BI    = OFF_BV + 16384;
static constexpr size_t OFF_CC    = OFF_BI + 16384;
static constexpr size_t OFF_CAND  = OFF_CC + 16384;
static constexpr size_t OFF_BAR   = OFF_CAND + (size_t)4096 * 32 * 4;  // end ~357.0 MB

static constexpr size_t SZ_HAB    = (size_t)Bb * 2 * Hh * 2;         // 262,144 per step-buffer

// ---------------- small helpers ----------------
DI u16 f2bf(float f) {                       // f32 -> bf16 RNE
  u32 u = __float_as_uint(f);
  u32 r = (u + 0x7FFFu + ((u >> 16) & 1u)) >> 16;
  return (u16)r;
}
DI float bf2f(u16 h) { return __uint_as_float(((u32)h) << 16); }

DI f32x4 mfma16(short8 a, short8 b, f32x4 c) {
  return __builtin_amdgcn_mfma_f32_16x16x32_bf16(a, b, c, 0, 0, 0);
}
DI void llds16(const u16* g, u16* l) {       // async global->LDS, 16B/lane
  __builtin_amdgcn_global_load_lds(
      (const __attribute__((address_space(1))) u32*)g,
      (__attribute__((address_space(3))) u32*)l, 16, 0, 0);
}

// agent-scope store: write-through past L2 to the L3 coherence point (no L2 allocation).
DI void ag_store_u32(u32* p, u32 v) {
  __hip_atomic_store(p, v, __ATOMIC_RELAXED, __HIP_MEMORY_SCOPE_AGENT);
}

// per-step hA buffer: regions A (XS, 192) | B (WIHE3, 36) | C (H2F, 29). Each buffer
// is written ONCE (sc stores, step st-1) then read ONCE (plain b128 loads, step st):
// no L2 can ever hold a stale copy (first plain touch is after the producing barrier).
DI u16* hbuf_dev(char* rA, char* rB, char* rC, int i) {
  if (i < 192) return (u16*)(rA + (size_t)i * SZ_HAB);
  if (i < 228) return (u16*)(rB + (size_t)(i - 192) * SZ_HAB);
  return (u16*)(rC + (size_t)(i - 228) * SZ_HAB);
}

// ---------------- utility kernels ----------------
__global__ void k_zero(u32* p, int n) {
  for (int i = blockIdx.x * 256 + threadIdx.x; i < n; i += gridDim.x * 256) p[i] = 0;
}

// W (rows x kin) f32 -> tripled bf16 [W_hi | W_hi | W_lo] (rows x 3kin)  (gx GEMM only)
__global__ void k_trip(const float* __restrict__ W, u16* __restrict__ W3, int rows, int kin) {
  int n = rows * kin;
  for (int i = blockIdx.x * 256 + threadIdx.x; i < n; i += gridDim.x * 256) {
    int rr = i / kin, k = i - rr * kin;
    float v = W[i];
    u16 hi = f2bf(v);
    u16 lo = f2bf(v - bf2f(hi));
    u16* o = W3 + (size_t)rr * (3 * kin);
    o[k] = hi; o[kin + k] = hi; o[2 * kin + k] = lo;
  }
}

__global__ void k_tobf(const float* __restrict__ W, u16* __restrict__ Wb, int n) {
  for (int i = blockIdx.x * 256 + threadIdx.x; i < n; i += gridDim.x * 256) Wb[i] = f2bf(W[i]);
}

// x' = gathered embeddings split as [x_hi | x_lo | x_hi]
__global__ void k_xsplit(const int* __restrict__ inp, const float* __restrict__ emb,
                         u16* __restrict__ xs) {
  int n = Ss * Bb * Ee;
  for (int i = blockIdx.x * 256 + threadIdx.x; i < n; i += gridDim.x * 256) {
    int m = i >> 9, k = i & (Ee - 1);
    int tok = inp[m];
    float v = emb[(size_t)tok * Ee + k];
    u16 hi = f2bf(v);
    u16 lo = f2bf(v - bf2f(hi));
    u16* o = xs + (size_t)m * (3 * Ee);
    o[k] = hi; o[Ee + k] = lo; o[2 * Ee + k] = hi;
  }
}

// gxd[g] = emb_dec[EOS] . Wih_d[g] + bih_d[g]   (exact f32, once)
__global__ void k_gxd(const float* __restrict__ emb_dec, const float* __restrict__ Wih_d,
                      const float* __restrict__ bih_d, float* __restrict__ gxd) {
  int g = blockIdx.x * 256 + threadIdx.x;
  if (g >= G3) return;
  const float* er = emb_dec + 2 * Ee;        // EOS_ID = 2
  const float* wr = Wih_d + (size_t)g * Ee;
  float s = 0.f;
  for (int e = 0; e < Ee; e++) s += er[e] * wr[e];
  gxd[g] = s + bih_d[g];
}

// ---------------- generic GEMM: C[m][n] = sum_k A[m][k]*B[n][k] + bias[n] ----------------
__global__ __launch_bounds__(256, 2) void gemm_bt(
    const u16* __restrict__ A, const u16* __restrict__ Bw, const float* __restrict__ bias,
    float* __restrict__ C, int M, int N, int K) {
  __shared__ __align__(16) u16 As[128 * 32];
  __shared__ __align__(16) u16 Bs[128 * 32];
  int tid = threadIdx.x;
  int wave = tid >> 6, lane = tid & 63;
  int wr = wave >> 1, wc = wave & 1;
  int m0 = blockIdx.y * 128, n0 = blockIdx.x * 128;
  f32x4 acc[4][4];
#pragma unroll
  for (int i = 0; i < 4; i++)
#pragma unroll
    for (int j = 0; j < 4; j++) acc[i][j] = (f32x4){0.f, 0.f, 0.f, 0.f};

  int lrow = lane >> 2, lcol = (lane & 3) * 8;
  int r15 = lane & 15, kk = (lane >> 4) * 8;

  for (int k0 = 0; k0 < K; k0 += 32) {
    __syncthreads();
#pragma unroll
    for (int rch = 0; rch < 2; rch++) {
      int c = rch * 4 + wave;
      int row = c * 16 + lrow;
      llds16(A  + (size_t)(m0 + row) * K + k0 + lcol, &As[c * 512]);
      llds16(Bw + (size_t)(n0 + row) * K + k0 + lcol, &Bs[c * 512]);
    }
    __syncthreads();
    short8 af[4], bfv[4];
#pragma unroll
    for (int mi = 0; mi < 4; mi++)
      af[mi] = *(const short8*)&As[(wr * 64 + mi * 16 + r15) * 32 + kk];
#pragma unroll
    for (int ni = 0; ni < 4; ni++)
      bfv[ni] = *(const short8*)&Bs[(wc * 64 + ni * 16 + r15) * 32 + kk];
#pragma unroll
    for (int mi = 0; mi < 4; mi++)
#pragma unroll
      for (int ni = 0; ni < 4; ni++) acc[mi][ni] = mfma16(af[mi], bfv[ni], acc[mi][ni]);
  }
#pragma unroll
  for (int mi = 0; mi < 4; mi++)
#pragma unroll
    for (int ni = 0; ni < 4; ni++) {
      int col = n0 + wc * 64 + ni * 16 + r15;
      float bs = bias[col];
#pragma unroll
      for (int i = 0; i < 4; i++) {
        int row = m0 + wr * 64 + mi * 16 + (lane >> 4) * 4 + i;
        C[(size_t)row * N + col] = acc[mi][ni][i] + bs;
      }
    }
}

// ---------------- persistent GRU phase (v2) ----------------
// grid 256 = 64 jt x 4 bq; block 512 = 8 waves splitting K=1024 into 8x128.
// Per step: plain b128 A loads from THIS STEP's fresh buffer (L2-cached, 32x reuse/XCD),
// dual-pass hi/lo MFMA, all-wave LDS partials (stride 13: conflict-free), epilogue
// distributed over 256 threads, sc u32 stores of next buffer, flat counter barrier.
template <int DEC>
__global__ __launch_bounds__(512, 1) void k_pers(
    const u16* __restrict__ W, const float* __restrict__ bhh, const float* __restrict__ gx0,
    char* rA, char* rB, char* rC, float* Hst, float* h2f0, u16* h2b0, int* bar) {
  int tid = threadIdx.x, wave = tid >> 6, lane = tid & 63;
  int r15 = lane & 15, kk = (lane >> 4) * 8;
  int bq = blockIdx.x & 3, jt = blockIdx.x >> 2;
  int b0 = bq * 16, j0 = jt * 16;
  int kbase = wave * 128;
  const int NSTEP = DEC ? Tt : Ss;

  __shared__ float sC[8][64][13];              // stride 13 -> no bank conflicts
  __shared__ float hT[256];                    // h tile, [bl*16+jc]
  __shared__ __align__(8) u16 stg[2][16][16];  // hi/lo staging

  int bl = tid >> 4, jc = tid & 15;            // epilogue mapping (tid<256)
  float br = 0.f, bz = 0.f, bn = 0.f, xrD = 0.f, xzD = 0.f, xnD = 0.f;
  if (tid < 256) {
    hT[tid] = DEC ? Hst[(size_t)(b0 + bl) * Hh + j0 + jc] : 0.f;
    int j = j0 + jc;
    br = bhh[j]; bz = bhh[Hh + j]; bn = bhh[2 * Hh + j];
    if (DEC) { xrD = gx0[j]; xzD = gx0[Hh + j]; xnD = gx0[2 * Hh + j]; }
  }
  __syncthreads();

  const u16* Wrow = W + (size_t)(j0 + r15) * Hh + kbase + kk;
  int lsrc = (bl >> 2) * 16 + jc;              // partials source lane for (bl,jc)
  int isrc = bl & 3;

  for (int st = 0; st < NSTEP; st++) {
    const u16* hin = hbuf_dev(rA, rB, rC, st);

    // gx loads issued early (encoder: streams from HBM under the MFMA phase)
    float xr = xrD, xz = xzD, xn = xnD;
    if (!DEC && tid < 256) {
      const float* gr = gx0 + ((size_t)st * Bb + b0 + bl) * G3;
      int j = j0 + jc;
      xr = gr[j]; xz = gr[Hh + j]; xn = gr[2 * Hh + j];
    }

    f32x4 acc[3];
#pragma unroll
    for (int g = 0; g < 3; g++) acc[g] = (f32x4){0.f, 0.f, 0.f, 0.f};
    const u16* Ab = hin + (size_t)(b0 + r15) * 2048 + kbase + kk;
#pragma unroll
    for (int ks = 0; ks < 4; ks++) {
      int ko = ks * 32;
      short8 ah = *(const short8*)(Ab + ko);          // h_hi  (plain b128, L2-cached)
      short8 al = *(const short8*)(Ab + 1024 + ko);   // h_lo
      short8 w0 = *(const short8*)(Wrow + ko);
      short8 w1 = *(const short8*)(Wrow + (size_t)Hh * Hh + ko);
      short8 w2 = *(const short8*)(Wrow + (size_t)2 * Hh * Hh + ko);
      acc[0] = mfma16(ah, w0, acc[0]);
      acc[1] = mfma16(ah, w1, acc[1]);
      acc[2] = mfma16(ah, w2, acc[2]);
      acc[0] = mfma16(al, w0, acc[0]);
      acc[1] = mfma16(al, w1, acc[1]);
      acc[2] = mfma16(al, w2, acc[2]);
    }
#pragma unroll
    for (int g = 0; g < 3; g++)
#pragma unroll
      for (int i = 0; i < 4; i++) sC[wave][lane][g * 4 + i] = acc[g][i];
    __syncthreads();

    if (tid < 256) {
      float hgr = br, hgz = bz, hgn = bn;
#pragma unroll
      for (int w = 0; w < 8; w++) {              // fixed order -> deterministic
        hgr += sC[w][lsrc][isrc];
        hgz += sC[w][lsrc][4 + isrc];
        hgn += sC[w][lsrc][8 + isrc];
      }
      float rg = 1.0f / (1.0f + expf(-(xr + hgr)));
      float zg = 1.0f / (1.0f + expf(-(xz + hgz)));
      float ng = tanhf(xn + rg * hgn);
      float hn = (1.0f - zg) * ng + zg * hT[tid];
      hT[tid] = hn;
      u16 hi = f2bf(hn), lo = f2bf(hn - bf2f(hi));
      stg[0][bl][jc] = hi;
      stg[1][bl][jc] = lo;
      if (DEC) h2f0[((size_t)st * Bb + b0 + bl) * Hh + j0 + jc] = hn;
    }
    __syncthreads();

    // distributed sc stores of the next-step buffer (skipped on last step: unread)
    if (tid < 256) {
      int part = tid >> 7, idx = tid & 127, row = idx >> 3, dw = idx & 7;
      if (st + 1 < NSTEP) {
        u16* hout = hbuf_dev(rA, rB, rC, st + 1);
        u32 val = ((const u32*)&stg[part][row][0])[dw];
        ag_store_u32((u32*)(hout + (size_t)(b0 + row) * 2048 + part * 1024 + j0) + dw, val);
      }
      if (DEC && tid < 128) {
        u16* h2b = h2b0 + (size_t)st * Bb * Hh;
        ((u32*)(h2b + (size_t)(b0 + row) * Hh + j0))[dw] = ((const u32*)&stg[0][row][0])[dw];
      }
    }

    if (st + 1 < NSTEP) {
      asm volatile("s_waitcnt vmcnt(0)" ::: "memory");   // sc stores at L3
      __syncthreads();
      if (tid == 0) {
        __hip_atomic_fetch_add(bar, 1, __ATOMIC_RELAXED, __HIP_MEMORY_SCOPE_AGENT);
        int target = (int)gridDim.x * (st + 1);
        while (__hip_atomic_load(bar, __ATOMIC_RELAXED, __HIP_MEMORY_SCOPE_AGENT) < target)
          __builtin_amdgcn_s_sleep(1);
      }
      __syncthreads();
    }
  }

  if (!DEC && tid < 256)
    Hst[(size_t)(b0 + bl) * Hh + j0 + jc] = hT[tid];
}

// ---------------- fallback per-step kernel (R5 path, if coop launch fails) ----------------
template <int DEC>
__global__ __launch_bounds__(512, 1) void k_step3(
    const u16* __restrict__ W, const float* __restrict__ bhh, const float* __restrict__ gxp,
    const u16* __restrict__ hAin, u16* __restrict__ hAout, float* __restrict__ h,
    float* __restrict__ h2f, u16* __restrict__ h2b) {
  __shared__ float sC[4][64][13];
  int tid = threadIdx.x, wave = tid >> 6, lane = tid & 63;
  int mw = wave & 3, khalf = wave >> 2;
  int m0 = mw * 16;
  int r15 = lane & 15, kk = (lane >> 4) * 8;
  int j0 = blockIdx.x * 16;
  int kbase = khalf * 512;

  f32x4 acc[3];
#pragma unroll
  for (int g = 0; g < 3; g++) acc[g] = (f32x4){0.f, 0.f, 0.f, 0.f};

  const u16* Ah = hAin + (size_t)(m0 + r15) * 2048 + kbase + kk;
  const u16* Wr = W + (size_t)(j0 + r15) * Hh + kbase + kk;
#pragma unroll 4
  for (int ks = 0; ks < 16; ks++) {
    int ko = ks * 32;
    short8 ah = *(const short8*)(Ah + ko);
    short8 al = *(const short8*)(Ah + 1024 + ko);
    short8 b0 = *(const short8*)(Wr + ko);
    short8 b1 = *(const short8*)(Wr + (size_t)Hh * Hh + ko);
    short8 b2 = *(const short8*)(Wr + (size_t)2 * Hh * Hh + ko);
    acc[0] = mfma16(ah, b0, acc[0]);
    acc[1] = mfma16(ah, b1, acc[1]);
    acc[2] = mfma16(ah, b2, acc[2]);
    acc[0] = mfma16(al, b0, acc[0]);
    acc[1] = mfma16(al, b1, acc[1]);
    acc[2] = mfma16(al, b2, acc[2]);
  }

  if (khalf == 1) {
#pragma unroll
    for (int g = 0; g < 3; g++)
#pragma unroll
      for (int i = 0; i < 4; i++) sC[mw][lane][g * 4 + i] = acc[g][i];
  }
  __syncthreads();
  if (khalf == 1) return;

  int j = j0 + r15;
  float br = bhh[j], bz = bhh[Hh + j], bn = bhh[2 * Hh + j];
  float xrD = 0.f, xzD = 0.f, xnD = 0.f;
  if (DEC) { xrD = gxp[j]; xzD = gxp[Hh + j]; xnD = gxp[2 * Hh + j]; }
#pragma unroll
  for (int i = 0; i < 4; i++) {
    int b = m0 + (lane >> 4) * 4 + i;
    float hgr = acc[0][i] + sC[mw][lane][i]     + br;
    float hgz = acc[1][i] + sC[mw][lane][4 + i] + bz;
    float hgn = acc[2][i] + sC[mw][lane][8 + i] + bn;
    float xr, xz, xn;
    if (DEC) { xr = xrD; xz = xzD; xn = xnD; }
    else {
      const float* gr = gxp + (size_t)b * G3;
      xr = gr[j]; xz = gr[Hh + j]; xn = gr[2 * Hh + j];
    }
    float rg = 1.0f / (1.0f + expf(-(xr + hgr)));
    float zg = 1.0f / (1.0f + expf(-(xz + hgz)));
    float ng = tanhf(xn + rg * hgn);
    float hold = h[(size_t)b * Hh + j];
    float hn = (1.0f - zg) * ng + zg * hold;
    h[(size_t)b * Hh + j] = hn;
    u16 hi = f2bf(hn);
    u16 lo = f2bf(hn - bf2f(hi));
    hAout[(size_t)b * 2048 + j] = hi;
    hAout[(size_t)b * 2048 + 1024 + j] = lo;
    if (DEC) {
      h2f[(size_t)b * Hh + j] = hn;
      h2b[(size_t)b * Hh + j] = hi;
    }
  }
}

// ---------------- heads (exact f32) ----------------
__global__ __launch_bounds__(256, 2) void k_head1(const float* __restrict__ h,
    const float* __restrict__ Wenc, const float* __restrict__ benc, float* __restrict__ henc) {
  int b = blockIdx.x;
  __shared__ float hs[Hh];
  for (int k = threadIdx.x; k < Hh; k += 256) hs[k] = h[(size_t)b * Hh + k];
  __syncthreads();
  int q = threadIdx.x;
  const float* wrw = Wenc + (size_t)q * Hh;
  float s = 0.f;
  for (int k = 0; k < Hh; k++) s += hs[k] * wrw[k];
  henc[b * Zz + q] = s + benc[q];
}

__global__ __launch_bounds__(256, 2) void k_head2(const float* __restrict__ henc,
    const float* __restrict__ Wloc, const float* __restrict__ bloc,
    const float* __restrict__ Wsc, const float* __restrict__ bsc,
    const float* __restrict__ eps, float* __restrict__ outLoc, float* __restrict__ outSc,
    float* __restrict__ zb) {
  int b = blockIdx.x;
  __shared__ float hs[Zz];
  if (threadIdx.x < Zz) hs[threadIdx.x] = henc[b * Zz + threadIdx.x];
  __syncthreads();
  int q = threadIdx.x;
  const float* wl = Wloc + (size_t)q * Zz;
  const float* wsp = Wsc + (size_t)q * Zz;
  float sl = 0.f, ssum = 0.f;
  for (int k = 0; k < Zz; k++) { sl += hs[k] * wl[k]; ssum += hs[k] * wsp[k]; }
  sl += bloc[q]; ssum += bsc[q];
  float sp = fmaxf(ssum, 0.f) + log1pf(expf(-fabsf(ssum)));  // softplus, stable
  float zv = sl + eps[b * Zz + q] * expf(0.5f * sp);
  outLoc[b * Zz + q] = sl;
  outSc[b * Zz + q] = sp;
  zb[b * Zz + q] = zv;
}

__global__ __launch_bounds__(256, 2) void k_head3(const float* __restrict__ zb,
    const float* __restrict__ Wdec, const float* __restrict__ bdec,
    float* __restrict__ h, u16* __restrict__ hA0) {
  int b = blockIdx.x;
  __shared__ float zs[Zz];
  if (threadIdx.x < Zz) zs[threadIdx.x] = zb[b * Zz + threadIdx.x];
  __syncthreads();
  for (int j = threadIdx.x; j < Hh; j += 256) {
    const float* wrw = Wdec + (size_t)j * Zz;
    float s = 0.f;
    for (int k = 0; k < Zz; k++) s += zs[k] * wrw[k];
    s += bdec[j];
    h[(size_t)b * Hh + j] = s;
    u16 hi = f2bf(s);
    u16 lo = f2bf(s - bf2f(hi));
    hA0[(size_t)b * 2048 + j] = hi;
    hA0[(size_t)b * 2048 + 1024 + j] = lo;
  }
}

// ---------------- row reduce: max, sumexp, candidates ----------------
__global__ __launch_bounds__(256, 2) void k_rowred(const float* __restrict__ logits,
    float* __restrict__ rowmax, float* __restrict__ sumexp, int* __restrict__ ccnt,
    int* __restrict__ cand) {
  int r = blockIdx.x;
  const float* row = logits + (size_t)r * Vv;
  __shared__ float red[4];
  __shared__ float srm;
  __shared__ int lcnt;
  __shared__ int lcand[32];
  int tid = threadIdx.x, wave = tid >> 6, lane = tid & 63;
  if (tid == 0) lcnt = 0;
  float m = -3.0e38f;
  for (int c = tid * 4; c < Vv; c += 1024) {
    f32x4 v = *(const f32x4*)(row + c);
    m = fmaxf(fmaxf(fmaxf(m, v.x), v.y), fmaxf(v.z, v.w));
  }
  for (int o = 32; o; o >>= 1) m = fmaxf(m, __shfl_xor(m, o));
  if (lane == 0) red[wave] = m;
  __syncthreads();
  if (tid == 0) srm = fmaxf(fmaxf(red[0], red[1]), fmaxf(red[2], red[3]));
  __syncthreads();
  float rm = srm;
  float s = 0.f;
  for (int c = tid * 4; c < Vv; c += 1024) {
    f32x4 v = *(const f32x4*)(row + c);
    s += expf(v.x - rm) + expf(v.y - rm) + expf(v.z - rm) + expf(v.w - rm);
    if (v.x >= rm - 0.0625f) { int sl = atomicAdd(&lcnt, 1); if (sl < 32) lcand[sl] = c; }
    if (v.y >= rm - 0.0625f) { int sl = atomicAdd(&lcnt, 1); if (sl < 32) lcand[sl] = c + 1; }
    if (v.z >= rm - 0.0625f) { int sl = atomicAdd(&lcnt, 1); if (sl < 32) lcand[sl] = c + 2; }
    if (v.w >= rm - 0.0625f) { int sl = atomicAdd(&lcnt, 1); if (sl < 32) lcand[sl] = c + 3; }
  }
  for (int o = 32; o; o >>= 1) s += __shfl_xor(s, o);
  if (lane == 0) red[wave] = s;
  __syncthreads();
  if (tid == 0) {
    float st = red[0] + red[1] + red[2] + red[3];
    int cc = lcnt < 32 ? lcnt : 32;
    for (int i = 0; i < cc; i++)
      for (int k2 = i + 1; k2 < cc; k2++)
        if (lcand[k2] < lcand[i]) { int t = lcand[i]; lcand[i] = lcand[k2]; lcand[k2] = t; }
    rowmax[r] = rm; sumexp[r] = st; ccnt[r] = cc;
    for (int i = 0; i < cc; i++) cand[r * 32 + i] = lcand[i];
  }
}

// ---------------- refine candidates exactly in f32, correct LSE, per-row best ----------------
__global__ __launch_bounds__(256, 1) void k_refine(const float* __restrict__ logits,
    const float* __restrict__ h2f, const float* __restrict__ Wvoc, const float* __restrict__ bvoc,
    const float* __restrict__ rowmax, const float* __restrict__ sumexp,
    const int* __restrict__ ccnt, const int* __restrict__ cand,
    float* __restrict__ lsec, float* __restrict__ bestv, int* __restrict__ besti) {
  int r = blockIdx.x;
  __shared__ float hrow[Hh];
  __shared__ float lex[32];
  __shared__ float del[32];
  int tid = threadIdx.x, wave = tid >> 6, lane = tid & 63;
  for (int k = tid; k < Hh; k += 256) hrow[k] = h2f[(size_t)r * Hh + k];
  int cnt = ccnt[r];
  float rm = rowmax[r];
  __syncthreads();
  for (int ci = wave; ci < cnt; ci += 4) {
    int v = cand[r * 32 + ci];
    const float* wrw = Wvoc + (size_t)v * Hh;
    float s = 0.f;
    for (int k = lane; k < Hh; k += 64) s += hrow[k] * wrw[k];
    for (int o = 32; o; o >>= 1) s += __shfl_xor(s, o);
    if (lane == 0) {
      float le = s + bvoc[v];
      lex[ci] = le;
      float la = logits[(size_t)r * Vv + v];
      del[ci] = expf(le - rm) - expf(la - rm);
    }
  }
  __syncthreads();
  if (tid == 0) {
    float se = sumexp[r];
    for (int i = 0; i < cnt; i++) se += del[i];
    float lse = rm + logf(se);
    lsec[r] = lse;
    float bv = -3.0e38f; int bvi = 0;
    for (int i = 0; i < cnt; i++)
      if (lex[i] > bv) { bv = lex[i]; bvi = cand[r * 32 + i]; }
    bestv[r] = bv - lse;
    besti[r] = (r & 63) * Vv + bvi;
  }
}

// ---------------- per-step global argmax -> seq ----------------
__global__ void k_argmax(const float* __restrict__ bestv, const int* __restrict__ besti,
                         float* __restrict__ outseq) {
  int tid = threadIdx.x;
  if (tid == 0) outseq[0] = 1.0f;
  for (int t = 0; t < Tt; t++) {
    float v = bestv[t * 64 + tid];
    int ii = besti[t * 64 + tid];
    for (int o = 1; o < 64; o <<= 1) {
      float ov = __shfl_xor(v, o);
      int oi = __shfl_xor(ii, o);
      if (ov > v || (ov == v && oi < ii)) { v = ov; ii = oi; }
    }
    if (tid == 0) outseq[1 + t] = (float)ii;
  }
}

// ---------------- in-place log-softmax: logits -= lse[row] ----------------
__global__ __launch_bounds__(256, 2) void k_logp(float* __restrict__ logits,
                                                 const float* __restrict__ lsec) {
  size_t total = (size_t)Tt * Bb * Vv / 4;
  for (size_t p = (size_t)blockIdx.x * 256 + threadIdx.x; p < total;
       p += (size_t)gridDim.x * 256) {
    int r = (int)(p / (Vv / 4));
    f32x4 v = *(f32x4*)(logits + p * 4);
    float l = lsec[r];
    v.x -= l; v.y -= l; v.z -= l; v.w -= l;
    *(f32x4*)(logits + p * 4) = v;
  }
}

// ---------------- host: launch sequence ----------------
extern "C" void kernel_launch(void* const* d_in, const int* in_sizes, int n_in,
                              void* d_out, int out_size, void* d_ws, size_t ws_size,
                              hipStream_t stream) {
  (void)in_sizes; (void)n_in; (void)out_size; (void)ws_size;
  const int*   inp     = (const int*)d_in[0];
  const float* eps     = (const float*)d_in[1];
  const float* emb_enc = (const float*)d_in[2];
  const float* Wih_e   = (const float*)d_in[3];
  const float* Whh_e   = (const float*)d_in[4];
  const float* bih_e   = (const float*)d_in[5];
  const float* bhh_e   = (const float*)d_in[6];
  const float* W_enc   = (const float*)d_in[7];
  const float* b_enc   = (const float*)d_in[8];
  const float* W_loc   = (const float*)d_in[9];
  const float* b_loc   = (const float*)d_in[10];
  const float* W_sc    = (const float*)d_in[11];
  const float* b_sc    = (const float*)d_in[12];
  const float* emb_dec = (const float*)d_in[13];
  const float* W_dec   = (const float*)d_in[14];
  const float* b_dec   = (const float*)d_in[15];
  const float* Wih_d   = (const float*)d_in[16];
  const float* Whh_d   = (const float*)d_in[17];
  const float* bih_d   = (const float*)d_in[18];
  const float* bhh_d   = (const float*)d_in[19];
  const float* W_voc   = (const float*)d_in[20];
  const float* b_voc   = (const float*)d_in[21];

  char* ws = (char*)d_ws;
  u16*   WHHE  = (u16*)(ws + OFF_WHHE);
  u16*   WHHD  = (u16*)(ws + OFF_WHHD);
  u16*   WIHE3 = (u16*)(ws + OFF_WIHE3);
  u16*   WVOC  = (u16*)(ws + OFF_WVOC);
  u16*   XS    = (u16*)(ws + OFF_XS);
  float* GX    = (float*)(ws + OFF_GX);
  float* Hst   = (float*)(ws + OFF_H);
  float* H2F   = (float*)(ws + OFF_H2F);
  u16*   H2B   = (u16*)(ws + OFF_H2B);
  float* GXD   = (float*)(ws + OFF_GXD);
  float* HENC  = (float*)(ws + OFF_HENC);
  float* ZB    = (float*)(ws + OFF_ZB);
  float* RM    = (float*)(ws + OFF_RM);
  float* SE    = (float*)(ws + OFF_SE);
  float* LSE   = (float*)(ws + OFF_LSE);
  float* BV    = (float*)(ws + OFF_BV);
  int*   BI    = (int*)(ws + OFF_BI);
  int*   CC    = (int*)(ws + OFF_CC);
  int*   CAND  = (int*)(ws + OFF_CAND);
  int*   BAR   = (int*)(ws + OFF_BAR);

  char* rA = ws + OFF_XS;      // step-buffer regions
  char* rB = ws + OFF_WIHE3;
  char* rC = ws + OFF_H2F;
  auto hbuf = [&](int i) -> u16* {
    if (i < 192) return (u16*)(rA + (size_t)i * SZ_HAB);
    if (i < 228) return (u16*)(rB + (size_t)(i - 192) * SZ_HAB);
    return (u16*)(rC + (size_t)(i - 228) * SZ_HAB);
  };

  float* out     = (float*)d_out;
  float* logits  = out;                                   // (T*B, V) f32
  float* outseq  = out + (size_t)Tt * Bb * Vv;
  float* outloc  = outseq + (Tt + 1);
  float* outsc   = outloc + Bb * Zz;

  // --- weight conversions ---
  k_tobf<<<1024, 256, 0, stream>>>(Whh_e, WHHE, G3 * Hh);
  k_tobf<<<1024, 256, 0, stream>>>(Whh_d, WHHD, G3 * Hh);
  k_trip<<<512, 256, 0, stream>>>(Wih_e, WIHE3, G3, Ee);
  k_tobf<<<2048, 256, 0, stream>>>(W_voc, WVOC, Vv * Hh);
  k_xsplit<<<2048, 256, 0, stream>>>(inp, emb_enc, XS);

  // --- gx = x' * Wih_e3^T + bih_e   (M=16384, N=3072, K=1536) ---
  {
    dim3 g(G3 / 128, (Ss * Bb) / 128);
    gemm_bt<<<g, 256, 0, stream>>>(XS, WIHE3, bih_e, GX, Ss * Bb, G3, 3 * Ee);
  }
  k_gxd<<<12, 256, 0, stream>>>(emb_dec, Wih_d, bih_d, GXD);
  k_zero<<<64, 256, 0, stream>>>((u32*)hbuf(0), (int)(SZ_HAB / 4));  // h0 = 0
  k_zero<<<1, 64, 0, stream>>>((u32*)BAR, 16);

  // --- encoder: persistent cooperative (256 steps), fallback = per-step loop ---
  hipError_t ce;
  {
    const u16* a0 = WHHE; const float* a1 = bhh_e; const float* a2 = GX;
    char* a3 = rA; char* a4 = rB; char* a5 = rC; float* a6 = Hst;
    float* a7 = nullptr; u16* a8 = nullptr; int* a9 = BAR;
    void* args[] = {&a0,&a1,&a2,&a3,&a4,&a5,&a6,&a7,&a8,&a9};
    ce = hipLaunchCooperativeKernel(reinterpret_cast<void*>(&k_pers<0>),
                                    dim3(256), dim3(512), args, 0, stream);
  }
  if (ce != hipSuccess) {
    for (int s = 0; s < Ss; s++)
      k_step3<0><<<64, 512, 0, stream>>>(WHHE, bhh_e, GX + (size_t)s * Bb * G3,
                                         hbuf(s), hbuf(s + 1), Hst, nullptr, nullptr);
  }

  // --- heads ---
  k_head1<<<64, 256, 0, stream>>>(Hst, W_enc, b_enc, HENC);
  k_head2<<<64, 256, 0, stream>>>(HENC, W_loc, b_loc, W_sc, b_sc, eps, outloc, outsc, ZB);
  k_head3<<<64, 256, 0, stream>>>(ZB, W_dec, b_dec, Hst, hbuf(0));
  k_zero<<<1, 64, 0, stream>>>((u32*)BAR, 16);

  // --- decoder: persistent cooperative (64 steps), fallback = per-step loop ---
  {
    const u16* a0 = WHHD; const float* a1 = bhh_d; const float* a2 = GXD;
    char* a3 = rA; char* a4 = rB; char* a5 = rC; float* a6 = Hst;
    float* a7 = H2F; u16* a8 = H2B; int* a9 = BAR;
    void* args[] = {&a0,&a1,&a2,&a3,&a4,&a5,&a6,&a7,&a8,&a9};
    hipError_t cd = hipLaunchCooperativeKernel(reinterpret_cast<void*>(&k_pers<1>),
                                               dim3(256), dim3(512), args, 0, stream);
    if (cd != hipSuccess) {
      for (int t = 0; t < Tt; t++)
        k_step3<1><<<64, 512, 0, stream>>>(WHHD, bhh_d, GXD, hbuf(t), hbuf(t + 1), Hst,
                                           H2F + (size_t)t * Bb * Hh,
                                           H2B + (size_t)t * Bb * Hh);
    }
  }

  // --- vocab projection: logits = h2 * Wvoc^T + b_voc  (M=4096, N=32000, K=1024) ---
  {
    dim3 g(Vv / 128, (Tt * Bb) / 128);
    gemm_bt<<<g, 256, 0, stream>>>(H2B, WVOC, b_voc, logits, Tt * Bb, Vv, Hh);
  }

  // --- softmax stats + exact argmax refinement ---
  k_rowred<<<Tt * Bb, 256, 0, stream>>>(logits, RM, SE, CC, CAND);
  k_refine<<<Tt * Bb, 256, 0, stream>>>(logits, H2F, W_voc, b_voc, RM, SE, CC, CAND, LSE, BV, BI);
  k_argmax<<<1, 64, 0, stream>>>(BV, BI, outseq);
  k_logp<<<2048, 256, 0, stream>>>(logits, LSE);
}

// Round 8
// 2879.454 us; speedup vs baseline: 4.9472x; 1.3013x over previous
//
#include <hip/hip_runtime.h>
#include <math.h>
#include <stdint.h>
#include <stddef.h>

typedef unsigned short u16;
typedef unsigned int   u32;
typedef __attribute__((ext_vector_type(8))) short short8;   // bf16x8 MFMA frag
typedef __attribute__((ext_vector_type(4))) float f32x4;

#define DI __device__ __forceinline__

// ---------------- problem constants ----------------
static constexpr int Vv = 32000, Ee = 512, Hh = 1024, Zz = 256;
static constexpr int Bb = 64, Ss = 256, Tt = 64;
static constexpr int G3 = 3 * Hh;            // 3072

// ---------------- workspace layout (bytes) ----------------
static constexpr size_t OFF_WHHE  = 0;                               // bf16 [3072][1024]
static constexpr size_t SZ_WHH    = (size_t)G3 * Hh * 2;             // 6,291,456
static constexpr size_t OFF_WHHD  = OFF_WHHE + SZ_WHH;
static constexpr size_t OFF_WIHE3 = OFF_WHHD + SZ_WHH;               // buf region B after gx GEMM
static constexpr size_t SZ_WIHE3  = (size_t)G3 * (3 * Ee) * 2;       // 9,437,184
static constexpr size_t OFF_WVOC  = OFF_WIHE3 + SZ_WIHE3;
static constexpr size_t SZ_WVOC   = (size_t)Vv * Hh * 2;             // 65,536,000
static constexpr size_t OFF_XS    = OFF_WVOC + SZ_WVOC;              // buf region A after gx GEMM
static constexpr size_t SZ_XS     = (size_t)Ss * Bb * (3 * Ee) * 2;  // 50,331,648
static constexpr size_t OFF_GX    = OFF_XS + SZ_XS;
static constexpr size_t SZ_GX     = (size_t)Ss * Bb * G3 * 4;        // 201,326,592
static constexpr size_t OFF_H2B   = OFF_GX;                          // overlay: GX head dead before decoder
static constexpr size_t OFF_H2F   = OFF_GX + SZ_GX;                  // buf region C during encoder
static constexpr size_t SZ_H2F    = (size_t)Tt * Bb * Hh * 4;        // 16,777,216
static constexpr size_t OFF_H     = OFF_H2F + SZ_H2F;
static constexpr size_t OFF_GXD   = OFF_H + (size_t)Bb * Hh * 4;
static constexpr size_t OFF_HENC  = OFF_GXD + 12288;
static constexpr size_t OFF_ZB    = OFF_HENC + (size_t)Bb * Zz * 4;
static constexpr size_t OFF_RM    = OFF_ZB + (size_t)Bb * Zz * 4;
static constexpr size_t OFF_SE    = OFF_RM + 16384;
static constexpr size_t OFF_LSE   = OFF_SE + 16384;
static constexpr size_t OFF_BV    = OFF_LSE + 16384;
static constexpr size_t OFF_BI    = OFF_BV + 16384;
static constexpr size_t OFF_CC    = OFF_BI + 16384;
static constexpr size_t OFF_CAND  = OFF_CC + 16384;
static constexpr size_t OFF_BAR   = OFF_CAND + (size_t)4096 * 32 * 4;  // 256 u32: l1[8]@64B, l2[4]@64B

static constexpr size_t SZ_HAB    = (size_t)Bb * 2 * Hh * 2;         // 262,144 per step-buffer

// ---------------- small helpers ----------------
DI u16 f2bf(float f) {                       // f32 -> bf16 RNE
  u32 u = __float_as_uint(f);
  u32 r = (u + 0x7FFFu + ((u >> 16) & 1u)) >> 16;
  return (u16)r;
}
DI float bf2f(u16 h) { return __uint_as_float(((u32)h) << 16); }

DI f32x4 mfma16(short8 a, short8 b, f32x4 c) {
  return __builtin_amdgcn_mfma_f32_16x16x32_bf16(a, b, c, 0, 0, 0);
}
DI void llds16(const u16* g, u16* l) {       // async global->LDS, 16B/lane
  __builtin_amdgcn_global_load_lds(
      (const __attribute__((address_space(1))) u32*)g,
      (__attribute__((address_space(3))) u32*)l, 16, 0, 0);
}

// agent-scope store: write-through past L2 to the L3 coherence point.
DI void ag_store_u32(u32* p, u32 v) {
  __hip_atomic_store(p, v, __ATOMIC_RELAXED, __HIP_MEMORY_SCOPE_AGENT);
}

// per-step hA buffer: regions A (XS, 192) | B (WIHE3, 36) | C (H2F, 29). Written once
// (sc stores, step st-1), read once (plain b128, step st) -> no stale L2 copies possible.
DI u16* hbuf_dev(char* rA, char* rB, char* rC, int i) {
  if (i < 192) return (u16*)(rA + (size_t)i * SZ_HAB);
  if (i < 228) return (u16*)(rB + (size_t)(i - 192) * SZ_HAB);
  return (u16*)(rC + (size_t)(i - 228) * SZ_HAB);
}

// ---------------- utility kernels ----------------
__global__ void k_zero(u32* p, int n) {
  for (int i = blockIdx.x * 256 + threadIdx.x; i < n; i += gridDim.x * 256) p[i] = 0;
}

// W (rows x kin) f32 -> tripled bf16 [W_hi | W_hi | W_lo] (rows x 3kin)  (gx GEMM only)
__global__ void k_trip(const float* __restrict__ W, u16* __restrict__ W3, int rows, int kin) {
  int n = rows * kin;
  for (int i = blockIdx.x * 256 + threadIdx.x; i < n; i += gridDim.x * 256) {
    int rr = i / kin, k = i - rr * kin;
    float v = W[i];
    u16 hi = f2bf(v);
    u16 lo = f2bf(v - bf2f(hi));
    u16* o = W3 + (size_t)rr * (3 * kin);
    o[k] = hi; o[kin + k] = hi; o[2 * kin + k] = lo;
  }
}

__global__ void k_tobf(const float* __restrict__ W, u16* __restrict__ Wb, int n) {
  for (int i = blockIdx.x * 256 + threadIdx.x; i < n; i += gridDim.x * 256) Wb[i] = f2bf(W[i]);
}

// x' = gathered embeddings split as [x_hi | x_lo | x_hi]
__global__ void k_xsplit(const int* __restrict__ inp, const float* __restrict__ emb,
                         u16* __restrict__ xs) {
  int n = Ss * Bb * Ee;
  for (int i = blockIdx.x * 256 + threadIdx.x; i < n; i += gridDim.x * 256) {
    int m = i >> 9, k = i & (Ee - 1);
    int tok = inp[m];
    float v = emb[(size_t)tok * Ee + k];
    u16 hi = f2bf(v);
    u16 lo = f2bf(v - bf2f(hi));
    u16* o = xs + (size_t)m * (3 * Ee);
    o[k] = hi; o[Ee + k] = lo; o[2 * Ee + k] = hi;
  }
}

// gxd[g] = emb_dec[EOS] . Wih_d[g] + bih_d[g]   (exact f32, once)
__global__ void k_gxd(const float* __restrict__ emb_dec, const float* __restrict__ Wih_d,
                      const float* __restrict__ bih_d, float* __restrict__ gxd) {
  int g = blockIdx.x * 256 + threadIdx.x;
  if (g >= G3) return;
  const float* er = emb_dec + 2 * Ee;        // EOS_ID = 2
  const float* wr = Wih_d + (size_t)g * Ee;
  float s = 0.f;
  for (int e = 0; e < Ee; e++) s += er[e] * wr[e];
  gxd[g] = s + bih_d[g];
}

// ---------------- generic GEMM: C[m][n] = sum_k A[m][k]*B[n][k] + bias[n] ----------------
__global__ __launch_bounds__(256, 2) void gemm_bt(
    const u16* __restrict__ A, const u16* __restrict__ Bw, const float* __restrict__ bias,
    float* __restrict__ C, int M, int N, int K) {
  __shared__ __align__(16) u16 As[128 * 32];
  __shared__ __align__(16) u16 Bs[128 * 32];
  int tid = threadIdx.x;
  int wave = tid >> 6, lane = tid & 63;
  int wr = wave >> 1, wc = wave & 1;
  int m0 = blockIdx.y * 128, n0 = blockIdx.x * 128;
  f32x4 acc[4][4];
#pragma unroll
  for (int i = 0; i < 4; i++)
#pragma unroll
    for (int j = 0; j < 4; j++) acc[i][j] = (f32x4){0.f, 0.f, 0.f, 0.f};

  int lrow = lane >> 2, lcol = (lane & 3) * 8;
  int r15 = lane & 15, kk = (lane >> 4) * 8;

  for (int k0 = 0; k0 < K; k0 += 32) {
    __syncthreads();
#pragma unroll
    for (int rch = 0; rch < 2; rch++) {
      int c = rch * 4 + wave;
      int row = c * 16 + lrow;
      llds16(A  + (size_t)(m0 + row) * K + k0 + lcol, &As[c * 512]);
      llds16(Bw + (size_t)(n0 + row) * K + k0 + lcol, &Bs[c * 512]);
    }
    __syncthreads();
    short8 af[4], bfv[4];
#pragma unroll
    for (int mi = 0; mi < 4; mi++)
      af[mi] = *(const short8*)&As[(wr * 64 + mi * 16 + r15) * 32 + kk];
#pragma unroll
    for (int ni = 0; ni < 4; ni++)
      bfv[ni] = *(const short8*)&Bs[(wc * 64 + ni * 16 + r15) * 32 + kk];
#pragma unroll
    for (int mi = 0; mi < 4; mi++)
#pragma unroll
      for (int ni = 0; ni < 4; ni++) acc[mi][ni] = mfma16(af[mi], bfv[ni], acc[mi][ni]);
  }
#pragma unroll
  for (int mi = 0; mi < 4; mi++)
#pragma unroll
    for (int ni = 0; ni < 4; ni++) {
      int col = n0 + wc * 64 + ni * 16 + r15;
      float bs = bias[col];
#pragma unroll
      for (int i = 0; i < 4; i++) {
        int row = m0 + wr * 64 + mi * 16 + (lane >> 4) * 4 + i;
        C[(size_t)row * N + col] = acc[mi][ni][i] + bs;
      }
    }
}

// ---------------- persistent GRU phase (v3: domain-split hierarchical barrier) ----------------
// grid 256 = 64 jt x 4 bq; block 512 = 8 waves splitting K=1024 into 8x128.
// Step sync only spans a bq-domain (64 blocks): block (jt,bq) reads rows of its own bq,
// produced exclusively by blocks (*, bq). Two-level counters: l1[bid&7] (32 arrivals,
// 64B-spaced lines) -> 32nd arriver bumps l2[bq] -> poll l2[bq] >= 2*(st+1).
// gx loads for st+1 issued under the poll (HBM latency hidden by the barrier wait).
template <int DEC>
__global__ __launch_bounds__(512, 1) void k_pers(
    const u16* __restrict__ W, const float* __restrict__ bhh, const float* __restrict__ gx0,
    char* rA, char* rB, char* rC, float* Hst, float* h2f0, u16* h2b0, int* bar) {
  int tid = threadIdx.x, wave = tid >> 6, lane = tid & 63;
  int r15 = lane & 15, kk = (lane >> 4) * 8;
  int bq = blockIdx.x & 3, jt = blockIdx.x >> 2;
  int b0 = bq * 16, j0 = jt * 16;
  int kbase = wave * 128;
  const int NSTEP = DEC ? Tt : Ss;

  __shared__ float sC[8][64][13];              // stride 13 -> conflict-free
  __shared__ float hT[256];                    // h tile [bl*16+jc]
  __shared__ __align__(8) u16 stg[2][16][16];  // hi/lo staging

  int bl = tid >> 4, jc = tid & 15;            // epilogue mapping (tid<256)
  float br = 0.f, bz = 0.f, bn = 0.f;
  float xr = 0.f, xz = 0.f, xn = 0.f;
  if (tid < 256) {
    hT[tid] = DEC ? Hst[(size_t)(b0 + bl) * Hh + j0 + jc] : 0.f;
    int j = j0 + jc;
    br = bhh[j]; bz = bhh[Hh + j]; bn = bhh[2 * Hh + j];
    if (DEC) { xr = gx0[j]; xz = gx0[Hh + j]; xn = gx0[2 * Hh + j]; }
    else {                                     // prologue gx load, step 0
      const float* gr = gx0 + (size_t)(b0 + bl) * G3;
      xr = gr[j]; xz = gr[Hh + j]; xn = gr[2 * Hh + j];
    }
  }
  __syncthreads();

  const u16* Wrow = W + (size_t)(j0 + r15) * Hh + kbase + kk;
  int lsrc = (bl >> 2) * 16 + jc;              // partials source for (bl,jc)
  int isrc = bl & 3;

  for (int st = 0; st < NSTEP; st++) {
    const u16* hin = hbuf_dev(rA, rB, rC, st);

    f32x4 acc[3];
#pragma unroll
    for (int g = 0; g < 3; g++) acc[g] = (f32x4){0.f, 0.f, 0.f, 0.f};
    const u16* Ab = hin + (size_t)(b0 + r15) * 2048 + kbase + kk;
#pragma unroll
    for (int ks = 0; ks < 4; ks++) {
      int ko = ks * 32;
      short8 ah = *(const short8*)(Ab + ko);          // h_hi (plain b128, L2-cached)
      short8 al = *(const short8*)(Ab + 1024 + ko);   // h_lo
      short8 w0 = *(const short8*)(Wrow + ko);
      short8 w1 = *(const short8*)(Wrow + (size_t)Hh * Hh + ko);
      short8 w2 = *(const short8*)(Wrow + (size_t)2 * Hh * Hh + ko);
      acc[0] = mfma16(ah, w0, acc[0]);
      acc[1] = mfma16(ah, w1, acc[1]);
      acc[2] = mfma16(ah, w2, acc[2]);
      acc[0] = mfma16(al, w0, acc[0]);
      acc[1] = mfma16(al, w1, acc[1]);
      acc[2] = mfma16(al, w2, acc[2]);
    }
#pragma unroll
    for (int g = 0; g < 3; g++)
#pragma unroll
      for (int i = 0; i < 4; i++) sC[wave][lane][g * 4 + i] = acc[g][i];
    __syncthreads();

    if (tid < 256) {
      float hgr = br, hgz = bz, hgn = bn;
#pragma unroll
      for (int w = 0; w < 8; w++) {              // fixed order -> deterministic
        hgr += sC[w][lsrc][isrc];
        hgz += sC[w][lsrc][4 + isrc];
        hgn += sC[w][lsrc][8 + isrc];
      }
      float rg = 1.0f / (1.0f + expf(-(xr + hgr)));
      float zg = 1.0f / (1.0f + expf(-(xz + hgz)));
      float ng = tanhf(xn + rg * hgn);
      float hn = (1.0f - zg) * ng + zg * hT[tid];
      hT[tid] = hn;
      u16 hi = f2bf(hn), lo = f2bf(hn - bf2f(hi));
      stg[0][bl][jc] = hi;
      stg[1][bl][jc] = lo;
      if (DEC) h2f0[((size_t)st * Bb + b0 + bl) * Hh + j0 + jc] = hn;
    }
    __syncthreads();

    // distributed sc stores of the next-step buffer (skipped on last step)
    if (tid < 256) {
      int part = tid >> 7, idx = tid & 127, row = idx >> 3, dw = idx & 7;
      if (st + 1 < NSTEP) {
        u16* hout = hbuf_dev(rA, rB, rC, st + 1);
        u32 val = ((const u32*)&stg[part][row][0])[dw];
        ag_store_u32((u32*)(hout + (size_t)(b0 + row) * 2048 + part * 1024 + j0) + dw, val);
      }
      if (DEC && tid < 128) {
        u16* h2b = h2b0 + (size_t)st * Bb * Hh;
        ((u32*)(h2b + (size_t)(b0 + row) * Hh + j0))[dw] = ((const u32*)&stg[0][row][0])[dw];
      }
    }

    if (st + 1 < NSTEP) {
      asm volatile("s_waitcnt vmcnt(0)" ::: "memory");   // own sc stores at L3
      __syncthreads();                                    // whole block's stores drained
      // prefetch gx(st+1) under the barrier wait (encoder only)
      if (!DEC && tid < 256) {
        const float* gr = gx0 + ((size_t)(st + 1) * Bb + b0 + bl) * G3;
        int j = j0 + jc;
        xr = gr[j]; xz = gr[Hh + j]; xn = gr[2 * Hh + j];
      }
      if (tid == 0) {
        int g = blockIdx.x & 7;
        int old = __hip_atomic_fetch_add(&bar[g * 16], 1,
                                         __ATOMIC_RELAXED, __HIP_MEMORY_SCOPE_AGENT);
        if (old == 32 * (st + 1) - 1)            // 32nd arrival of this step, this group
          __hip_atomic_fetch_add(&bar[128 + bq * 16], 1,
                                 __ATOMIC_RELAXED, __HIP_MEMORY_SCOPE_AGENT);
        while (__hip_atomic_load(&bar[128 + bq * 16],
                                 __ATOMIC_RELAXED, __HIP_MEMORY_SCOPE_AGENT) < 2 * (st + 1))
          __builtin_amdgcn_s_sleep(1);
      }
      __syncthreads();
    }
  }

  if (!DEC && tid < 256)
    Hst[(size_t)(b0 + bl) * Hh + j0 + jc] = hT[tid];
}

// ---------------- fallback per-step kernel (if coop launch fails) ----------------
template <int DEC>
__global__ __launch_bounds__(512, 1) void k_step3(
    const u16* __restrict__ W, const float* __restrict__ bhh, const float* __restrict__ gxp,
    const u16* __restrict__ hAin, u16* __restrict__ hAout, float* __restrict__ h,
    float* __restrict__ h2f, u16* __restrict__ h2b) {
  __shared__ float sC[4][64][13];
  int tid = threadIdx.x, wave = tid >> 6, lane = tid & 63;
  int mw = wave & 3, khalf = wave >> 2;
  int m0 = mw * 16;
  int r15 = lane & 15, kk = (lane >> 4) * 8;
  int j0 = blockIdx.x * 16;
  int kbase = khalf * 512;

  f32x4 acc[3];
#pragma unroll
  for (int g = 0; g < 3; g++) acc[g] = (f32x4){0.f, 0.f, 0.f, 0.f};

  const u16* Ah = hAin + (size_t)(m0 + r15) * 2048 + kbase + kk;
  const u16* Wr = W + (size_t)(j0 + r15) * Hh + kbase + kk;
#pragma unroll 4
  for (int ks = 0; ks < 16; ks++) {
    int ko = ks * 32;
    short8 ah = *(const short8*)(Ah + ko);
    short8 al = *(const short8*)(Ah + 1024 + ko);
    short8 b0 = *(const short8*)(Wr + ko);
    short8 b1 = *(const short8*)(Wr + (size_t)Hh * Hh + ko);
    short8 b2 = *(const short8*)(Wr + (size_t)2 * Hh * Hh + ko);
    acc[0] = mfma16(ah, b0, acc[0]);
    acc[1] = mfma16(ah, b1, acc[1]);
    acc[2] = mfma16(ah, b2, acc[2]);
    acc[0] = mfma16(al, b0, acc[0]);
    acc[1] = mfma16(al, b1, acc[1]);
    acc[2] = mfma16(al, b2, acc[2]);
  }

  if (khalf == 1) {
#pragma unroll
    for (int g = 0; g < 3; g++)
#pragma unroll
      for (int i = 0; i < 4; i++) sC[mw][lane][g * 4 + i] = acc[g][i];
  }
  __syncthreads();
  if (khalf == 1) return;

  int j = j0 + r15;
  float br = bhh[j], bz = bhh[Hh + j], bn = bhh[2 * Hh + j];
  float xrD = 0.f, xzD = 0.f, xnD = 0.f;
  if (DEC) { xrD = gxp[j]; xzD = gxp[Hh + j]; xnD = gxp[2 * Hh + j]; }
#pragma unroll
  for (int i = 0; i < 4; i++) {
    int b = m0 + (lane >> 4) * 4 + i;
    float hgr = acc[0][i] + sC[mw][lane][i]     + br;
    float hgz = acc[1][i] + sC[mw][lane][4 + i] + bz;
    float hgn = acc[2][i] + sC[mw][lane][8 + i] + bn;
    float xr, xz, xn;
    if (DEC) { xr = xrD; xz = xzD; xn = xnD; }
    else {
      const float* gr = gxp + (size_t)b * G3;
      xr = gr[j]; xz = gr[Hh + j]; xn = gr[2 * Hh + j];
    }
    float rg = 1.0f / (1.0f + expf(-(xr + hgr)));
    float zg = 1.0f / (1.0f + expf(-(xz + hgz)));
    float ng = tanhf(xn + rg * hgn);
    float hold = h[(size_t)b * Hh + j];
    float hn = (1.0f - zg) * ng + zg * hold;
    h[(size_t)b * Hh + j] = hn;
    u16 hi = f2bf(hn);
    u16 lo = f2bf(hn - bf2f(hi));
    hAout[(size_t)b * 2048 + j] = hi;
    hAout[(size_t)b * 2048 + 1024 + j] = lo;
    if (DEC) {
      h2f[(size_t)b * Hh + j] = hn;
      h2b[(size_t)b * Hh + j] = hi;
    }
  }
}

// ---------------- heads (exact f32) ----------------
__global__ __launch_bounds__(256, 2) void k_head1(const float* __restrict__ h,
    const float* __restrict__ Wenc, const float* __restrict__ benc, float* __restrict__ henc) {
  int b = blockIdx.x;
  __shared__ float hs[Hh];
  for (int k = threadIdx.x; k < Hh; k += 256) hs[k] = h[(size_t)b * Hh + k];
  __syncthreads();
  int q = threadIdx.x;
  const float* wrw = Wenc + (size_t)q * Hh;
  float s = 0.f;
  for (int k = 0; k < Hh; k++) s += hs[k] * wrw[k];
  henc[b * Zz + q] = s + benc[q];
}

__global__ __launch_bounds__(256, 2) void k_head2(const float* __restrict__ henc,
    const float* __restrict__ Wloc, const float* __restrict__ bloc,
    const float* __restrict__ Wsc, const float* __restrict__ bsc,
    const float* __restrict__ eps, float* __restrict__ outLoc, float* __restrict__ outSc,
    float* __restrict__ zb) {
  int b = blockIdx.x;
  __shared__ float hs[Zz];
  if (threadIdx.x < Zz) hs[threadIdx.x] = henc[b * Zz + threadIdx.x];
  __syncthreads();
  int q = threadIdx.x;
  const float* wl = Wloc + (size_t)q * Zz;
  const float* wsp = Wsc + (size_t)q * Zz;
  float sl = 0.f, ssum = 0.f;
  for (int k = 0; k < Zz; k++) { sl += hs[k] * wl[k]; ssum += hs[k] * wsp[k]; }
  sl += bloc[q]; ssum += bsc[q];
  float sp = fmaxf(ssum, 0.f) + log1pf(expf(-fabsf(ssum)));  // softplus, stable
  float zv = sl + eps[b * Zz + q] * expf(0.5f * sp);
  outLoc[b * Zz + q] = sl;
  outSc[b * Zz + q] = sp;
  zb[b * Zz + q] = zv;
}

__global__ __launch_bounds__(256, 2) void k_head3(const float* __restrict__ zb,
    const float* __restrict__ Wdec, const float* __restrict__ bdec,
    float* __restrict__ h, u16* __restrict__ hA0) {
  int b = blockIdx.x;
  __shared__ float zs[Zz];
  if (threadIdx.x < Zz) zs[threadIdx.x] = zb[b * Zz + threadIdx.x];
  __syncthreads();
  for (int j = threadIdx.x; j < Hh; j += 256) {
    const float* wrw = Wdec + (size_t)j * Zz;
    float s = 0.f;
    for (int k = 0; k < Zz; k++) s += zs[k] * wrw[k];
    s += bdec[j];
    h[(size_t)b * Hh + j] = s;
    u16 hi = f2bf(s);
    u16 lo = f2bf(s - bf2f(hi));
    hA0[(size_t)b * 2048 + j] = hi;
    hA0[(size_t)b * 2048 + 1024 + j] = lo;
  }
}

// ---------------- row reduce: max, sumexp, candidates ----------------
__global__ __launch_bounds__(256, 2) void k_rowred(const float* __restrict__ logits,
    float* __restrict__ rowmax, float* __restrict__ sumexp, int* __restrict__ ccnt,
    int* __restrict__ cand) {
  int r = blockIdx.x;
  const float* row = logits + (size_t)r * Vv;
  __shared__ float red[4];
  __shared__ float srm;
  __shared__ int lcnt;
  __shared__ int lcand[32];
  int tid = threadIdx.x, wave = tid >> 6, lane = tid & 63;
  if (tid == 0) lcnt = 0;
  float m = -3.0e38f;
  for (int c = tid * 4; c < Vv; c += 1024) {
    f32x4 v = *(const f32x4*)(row + c);
    m = fmaxf(fmaxf(fmaxf(m, v.x), v.y), fmaxf(v.z, v.w));
  }
  for (int o = 32; o; o >>= 1) m = fmaxf(m, __shfl_xor(m, o));
  if (lane == 0) red[wave] = m;
  __syncthreads();
  if (tid == 0) srm = fmaxf(fmaxf(red[0], red[1]), fmaxf(red[2], red[3]));
  __syncthreads();
  float rm = srm;
  float s = 0.f;
  for (int c = tid * 4; c < Vv; c += 1024) {
    f32x4 v = *(const f32x4*)(row + c);
    s += expf(v.x - rm) + expf(v.y - rm) + expf(v.z - rm) + expf(v.w - rm);
    if (v.x >= rm - 0.0625f) { int sl = atomicAdd(&lcnt, 1); if (sl < 32) lcand[sl] = c; }
    if (v.y >= rm - 0.0625f) { int sl = atomicAdd(&lcnt, 1); if (sl < 32) lcand[sl] = c + 1; }
    if (v.z >= rm - 0.0625f) { int sl = atomicAdd(&lcnt, 1); if (sl < 32) lcand[sl] = c + 2; }
    if (v.w >= rm - 0.0625f) { int sl = atomicAdd(&lcnt, 1); if (sl < 32) lcand[sl] = c + 3; }
  }
  for (int o = 32; o; o >>= 1) s += __shfl_xor(s, o);
  if (lane == 0) red[wave] = s;
  __syncthreads();
  if (tid == 0) {
    float st = red[0] + red[1] + red[2] + red[3];
    int cc = lcnt < 32 ? lcnt : 32;
    for (int i = 0; i < cc; i++)
      for (int k2 = i + 1; k2 < cc; k2++)
        if (lcand[k2] < lcand[i]) { int t = lcand[i]; lcand[i] = lcand[k2]; lcand[k2] = t; }
    rowmax[r] = rm; sumexp[r] = st; ccnt[r] = cc;
    for (int i = 0; i < cc; i++) cand[r * 32 + i] = lcand[i];
  }
}

// ---------------- refine candidates exactly in f32, correct LSE, per-row best ----------------
__global__ __launch_bounds__(256, 1) void k_refine(const float* __restrict__ logits,
    const float* __restrict__ h2f, const float* __restrict__ Wvoc, const float* __restrict__ bvoc,
    const float* __restrict__ rowmax, const float* __restrict__ sumexp,
    const int* __restrict__ ccnt, const int* __restrict__ cand,
    float* __restrict__ lsec, float* __restrict__ bestv, int* __restrict__ besti) {
  int r = blockIdx.x;
  __shared__ float hrow[Hh];
  __shared__ float lex[32];
  __shared__ float del[32];
  int tid = threadIdx.x, wave = tid >> 6, lane = tid & 63;
  for (int k = tid; k < Hh; k += 256) hrow[k] = h2f[(size_t)r * Hh + k];
  int cnt = ccnt[r];
  float rm = rowmax[r];
  __syncthreads();
  for (int ci = wave; ci < cnt; ci += 4) {
    int v = cand[r * 32 + ci];
    const float* wrw = Wvoc + (size_t)v * Hh;
    float s = 0.f;
    for (int k = lane; k < Hh; k += 64) s += hrow[k] * wrw[k];
    for (int o = 32; o; o >>= 1) s += __shfl_xor(s, o);
    if (lane == 0) {
      float le = s + bvoc[v];
      lex[ci] = le;
      float la = logits[(size_t)r * Vv + v];
      del[ci] = expf(le - rm) - expf(la - rm);
    }
  }
  __syncthreads();
  if (tid == 0) {
    float se = sumexp[r];
    for (int i = 0; i < cnt; i++) se += del[i];
    float lse = rm + logf(se);
    lsec[r] = lse;
    float bv = -3.0e38f; int bvi = 0;
    for (int i = 0; i < cnt; i++)
      if (lex[i] > bv) { bv = lex[i]; bvi = cand[r * 32 + i]; }
    bestv[r] = bv - lse;
    besti[r] = (r & 63) * Vv + bvi;
  }
}

// ---------------- per-step global argmax -> seq ----------------
__global__ void k_argmax(const float* __restrict__ bestv, const int* __restrict__ besti,
                         float* __restrict__ outseq) {
  int tid = threadIdx.x;
  if (tid == 0) outseq[0] = 1.0f;
  for (int t = 0; t < Tt; t++) {
    float v = bestv[t * 64 + tid];
    int ii = besti[t * 64 + tid];
    for (int o = 1; o < 64; o <<= 1) {
      float ov = __shfl_xor(v, o);
      int oi = __shfl_xor(ii, o);
      if (ov > v || (ov == v && oi < ii)) { v = ov; ii = oi; }
    }
    if (tid == 0) outseq[1 + t] = (float)ii;
  }
}

// ---------------- in-place log-softmax: logits -= lse[row] ----------------
__global__ __launch_bounds__(256, 2) void k_logp(float* __restrict__ logits,
                                                 const float* __restrict__ lsec) {
  size_t total = (size_t)Tt * Bb * Vv / 4;
  for (size_t p = (size_t)blockIdx.x * 256 + threadIdx.x; p < total;
       p += (size_t)gridDim.x * 256) {
    int r = (int)(p / (Vv / 4));
    f32x4 v = *(f32x4*)(logits + p * 4);
    float l = lsec[r];
    v.x -= l; v.y -= l; v.z -= l; v.w -= l;
    *(f32x4*)(logits + p * 4) = v;
  }
}

// ---------------- host: launch sequence ----------------
extern "C" void kernel_launch(void* const* d_in, const int* in_sizes, int n_in,
                              void* d_out, int out_size, void* d_ws, size_t ws_size,
                              hipStream_t stream) {
  (void)in_sizes; (void)n_in; (void)out_size; (void)ws_size;
  const int*   inp     = (const int*)d_in[0];
  const float* eps     = (const float*)d_in[1];
  const float* emb_enc = (const float*)d_in[2];
  const float* Wih_e   = (const float*)d_in[3];
  const float* Whh_e   = (const float*)d_in[4];
  const float* bih_e   = (const float*)d_in[5];
  const float* bhh_e   = (const float*)d_in[6];
  const float* W_enc   = (const float*)d_in[7];
  const float* b_enc   = (const float*)d_in[8];
  const float* W_loc   = (const float*)d_in[9];
  const float* b_loc   = (const float*)d_in[10];
  const float* W_sc    = (const float*)d_in[11];
  const float* b_sc    = (const float*)d_in[12];
  const float* emb_dec = (const float*)d_in[13];
  const float* W_dec   = (const float*)d_in[14];
  const float* b_dec   = (const float*)d_in[15];
  const float* Wih_d   = (const float*)d_in[16];
  const float* Whh_d   = (const float*)d_in[17];
  const float* bih_d   = (const float*)d_in[18];
  const float* bhh_d   = (const float*)d_in[19];
  const float* W_voc   = (const float*)d_in[20];
  const float* b_voc   = (const float*)d_in[21];

  char* ws = (char*)d_ws;
  u16*   WHHE  = (u16*)(ws + OFF_WHHE);
  u16*   WHHD  = (u16*)(ws + OFF_WHHD);
  u16*   WIHE3 = (u16*)(ws + OFF_WIHE3);
  u16*   WVOC  = (u16*)(ws + OFF_WVOC);
  u16*   XS    = (u16*)(ws + OFF_XS);
  float* GX    = (float*)(ws + OFF_GX);
  float* Hst   = (float*)(ws + OFF_H);
  float* H2F   = (float*)(ws + OFF_H2F);
  u16*   H2B   = (u16*)(ws + OFF_H2B);
  float* GXD   = (float*)(ws + OFF_GXD);
  float* HENC  = (float*)(ws + OFF_HENC);
  float* ZB    = (float*)(ws + OFF_ZB);
  float* RM    = (float*)(ws + OFF_RM);
  float* SE    = (float*)(ws + OFF_SE);
  float* LSE   = (float*)(ws + OFF_LSE);
  float* BV    = (float*)(ws + OFF_BV);
  int*   BI    = (int*)(ws + OFF_BI);
  int*   CC    = (int*)(ws + OFF_CC);
  int*   CAND  = (int*)(ws + OFF_CAND);
  int*   BAR   = (int*)(ws + OFF_BAR);

  char* rA = ws + OFF_XS;      // step-buffer regions
  char* rB = ws + OFF_WIHE3;
  char* rC = ws + OFF_H2F;
  auto hbuf = [&](int i) -> u16* {
    if (i < 192) return (u16*)(rA + (size_t)i * SZ_HAB);
    if (i < 228) return (u16*)(rB + (size_t)(i - 192) * SZ_HAB);
    return (u16*)(rC + (size_t)(i - 228) * SZ_HAB);
  };

  float* out     = (float*)d_out;
  float* logits  = out;                                   // (T*B, V) f32
  float* outseq  = out + (size_t)Tt * Bb * Vv;
  float* outloc  = outseq + (Tt + 1);
  float* outsc   = outloc + Bb * Zz;

  // --- weight conversions ---
  k_tobf<<<1024, 256, 0, stream>>>(Whh_e, WHHE, G3 * Hh);
  k_tobf<<<1024, 256, 0, stream>>>(Whh_d, WHHD, G3 * Hh);
  k_trip<<<512, 256, 0, stream>>>(Wih_e, WIHE3, G3, Ee);
  k_tobf<<<2048, 256, 0, stream>>>(W_voc, WVOC, Vv * Hh);
  k_xsplit<<<2048, 256, 0, stream>>>(inp, emb_enc, XS);

  // --- gx = x' * Wih_e3^T + bih_e   (M=16384, N=3072, K=1536) ---
  {
    dim3 g(G3 / 128, (Ss * Bb) / 128);
    gemm_bt<<<g, 256, 0, stream>>>(XS, WIHE3, bih_e, GX, Ss * Bb, G3, 3 * Ee);
  }
  k_gxd<<<12, 256, 0, stream>>>(emb_dec, Wih_d, bih_d, GXD);
  k_zero<<<64, 256, 0, stream>>>((u32*)hbuf(0), (int)(SZ_HAB / 4));  // h0 = 0
  k_zero<<<1, 256, 0, stream>>>((u32*)BAR, 256);

  // --- encoder: persistent cooperative (256 steps), fallback = per-step loop ---
  hipError_t ce;
  {
    const u16* a0 = WHHE; const float* a1 = bhh_e; const float* a2 = GX;
    char* a3 = rA; char* a4 = rB; char* a5 = rC; float* a6 = Hst;
    float* a7 = nullptr; u16* a8 = nullptr; int* a9 = BAR;
    void* args[] = {&a0,&a1,&a2,&a3,&a4,&a5,&a6,&a7,&a8,&a9};
    ce = hipLaunchCooperativeKernel(reinterpret_cast<void*>(&k_pers<0>),
                                    dim3(256), dim3(512), args, 0, stream);
  }
  if (ce != hipSuccess) {
    for (int s = 0; s < Ss; s++)
      k_step3<0><<<64, 512, 0, stream>>>(WHHE, bhh_e, GX + (size_t)s * Bb * G3,
                                         hbuf(s), hbuf(s + 1), Hst, nullptr, nullptr);
  }

  // --- heads ---
  k_head1<<<64, 256, 0, stream>>>(Hst, W_enc, b_enc, HENC);
  k_head2<<<64, 256, 0, stream>>>(HENC, W_loc, b_loc, W_sc, b_sc, eps, outloc, outsc, ZB);
  k_head3<<<64, 256, 0, stream>>>(ZB, W_dec, b_dec, Hst, hbuf(0));
  k_zero<<<1, 256, 0, stream>>>((u32*)BAR, 256);

  // --- decoder: persistent cooperative (64 steps), fallback = per-step loop ---
  {
    const u16* a0 = WHHD; const float* a1 = bhh_d; const float* a2 = GXD;
    char* a3 = rA; char* a4 = rB; char* a5 = rC; float* a6 = Hst;
    float* a7 = H2F; u16* a8 = H2B; int* a9 = BAR;
    void* args[] = {&a0,&a1,&a2,&a3,&a4,&a5,&a6,&a7,&a8,&a9};
    hipError_t cd = hipLaunchCooperativeKernel(reinterpret_cast<void*>(&k_pers<1>),
                                               dim3(256), dim3(512), args, 0, stream);
    if (cd != hipSuccess) {
      for (int t = 0; t < Tt; t++)
        k_step3<1><<<64, 512, 0, stream>>>(WHHD, bhh_d, GXD, hbuf(t), hbuf(t + 1), Hst,
                                           H2F + (size_t)t * Bb * Hh,
                                           H2B + (size_t)t * Bb * Hh);
    }
  }

  // --- vocab projection: logits = h2 * Wvoc^T + b_voc  (M=4096, N=32000, K=1024) ---
  {
    dim3 g(Vv / 128, (Tt * Bb) / 128);
    gemm_bt<<<g, 256, 0, stream>>>(H2B, WVOC, b_voc, logits, Tt * Bb, Vv, Hh);
  }

  // --- softmax stats + exact argmax refinement ---
  k_rowred<<<Tt * Bb, 256, 0, stream>>>(logits, RM, SE, CC, CAND);
  k_refine<<<Tt * Bb, 256, 0, stream>>>(logits, H2F, W_voc, b_voc, RM, SE, CC, CAND, LSE, BV, BI);
  k_argmax<<<1, 64, 0, stream>>>(BV, BI, outseq);
  k_logp<<<2048, 256, 0, stream>>>(logits, LSE);
}

// Round 9
// 2824.958 us; speedup vs baseline: 5.0426x; 1.0193x over previous
//
#include <hip/hip_runtime.h>
#include <math.h>
#include <stdint.h>
#include <stddef.h>

typedef unsigned short u16;
typedef unsigned int   u32;
typedef __attribute__((ext_vector_type(8))) short short8;   // bf16x8 MFMA frag
typedef __attribute__((ext_vector_type(4))) float f32x4;

#define DI __device__ __forceinline__

// ---------------- problem constants ----------------
static constexpr int Vv = 32000, Ee = 512, Hh = 1024, Zz = 256;
static constexpr int Bb = 64, Ss = 256, Tt = 64;
static constexpr int G3 = 3 * Hh;            // 3072

// ---------------- workspace layout (bytes) ----------------
static constexpr size_t OFF_WHHE  = 0;                               // bf16 [3072][1024]
static constexpr size_t SZ_WHH    = (size_t)G3 * Hh * 2;             // 6,291,456
static constexpr size_t OFF_WHHD  = OFF_WHHE + SZ_WHH;
static constexpr size_t OFF_WIHE3 = OFF_WHHD + SZ_WHH;               // buf region B after gx GEMM
static constexpr size_t SZ_WIHE3  = (size_t)G3 * (3 * Ee) * 2;       // 9,437,184
static constexpr size_t OFF_WVOC  = OFF_WIHE3 + SZ_WIHE3;
static constexpr size_t SZ_WVOC   = (size_t)Vv * Hh * 2;             // 65,536,000
static constexpr size_t OFF_XS    = OFF_WVOC + SZ_WVOC;              // buf region A after gx GEMM
static constexpr size_t SZ_XS     = (size_t)Ss * Bb * (3 * Ee) * 2;  // 50,331,648
static constexpr size_t OFF_GX    = OFF_XS + SZ_XS;
static constexpr size_t SZ_GX     = (size_t)Ss * Bb * G3 * 4;        // 201,326,592
static constexpr size_t OFF_H2B   = OFF_GX;                          // overlay: GX head dead before decoder
static constexpr size_t OFF_H2F   = OFF_GX + SZ_GX;                  // buf region C during encoder
static constexpr size_t SZ_H2F    = (size_t)Tt * Bb * Hh * 4;        // 16,777,216
static constexpr size_t OFF_H     = OFF_H2F + SZ_H2F;
static constexpr size_t OFF_GXD   = OFF_H + (size_t)Bb * Hh * 4;
static constexpr size_t OFF_HENC  = OFF_GXD + 12288;
static constexpr size_t OFF_ZB    = OFF_HENC + (size_t)Bb * Zz * 4;
static constexpr size_t OFF_RM    = OFF_ZB + (size_t)Bb * Zz * 4;
static constexpr size_t OFF_SE    = OFF_RM + 16384;
static constexpr size_t OFF_LSE   = OFF_SE + 16384;
static constexpr size_t OFF_BV    = OFF_LSE + 16384;
static constexpr size_t OFF_BI    = OFF_BV + 16384;
static constexpr size_t OFF_CC    = OFF_BI + 16384;
static constexpr size_t OFF_CAND  = OFF_CC + 16384;
static constexpr size_t OFF_BAR   = OFF_CAND + (size_t)4096 * 32 * 4;
// BAR: FLG[256] at u32 idx bid*16 (64B lines), GO[4] at idx 4096+bq*16. 4224 u32 total.

static constexpr size_t SZ_HAB    = (size_t)Bb * 2 * Hh * 2;         // 262,144 per step-buffer

// ---------------- small helpers ----------------
DI u16 f2bf(float f) {                       // f32 -> bf16 RNE
  u32 u = __float_as_uint(f);
  u32 r = (u + 0x7FFFu + ((u >> 16) & 1u)) >> 16;
  return (u16)r;
}
DI float bf2f(u16 h) { return __uint_as_float(((u32)h) << 16); }

DI f32x4 mfma16(short8 a, short8 b, f32x4 c) {
  return __builtin_amdgcn_mfma_f32_16x16x32_bf16(a, b, c, 0, 0, 0);
}
DI void llds16(const u16* g, u16* l) {       // async global->LDS, 16B/lane
  __builtin_amdgcn_global_load_lds(
      (const __attribute__((address_space(1))) u32*)g,
      (__attribute__((address_space(3))) u32*)l, 16, 0, 0);
}

// agent-scope ops: write-through past L2 to L3 coherence point / L2-bypassing load.
DI void ag_store_u32(u32* p, u32 v) {
  __hip_atomic_store(p, v, __ATOMIC_RELAXED, __HIP_MEMORY_SCOPE_AGENT);
}
DI u32 ag_load_u32(const u32* p) {
  return __hip_atomic_load((u32*)p, __ATOMIC_RELAXED, __HIP_MEMORY_SCOPE_AGENT);
}
DI void ag_store_f32(float* p, float v) {
  __hip_atomic_store(p, v, __ATOMIC_RELAXED, __HIP_MEMORY_SCOPE_AGENT);
}

// per-step hA buffer: regions A (XS, 192) | B (WIHE3, 36) | C (H2F, 29). Written once
// (sc stores, step st-1), read once (plain b128, step st) -> no stale L2 copies possible.
DI u16* hbuf_dev(char* rA, char* rB, char* rC, int i) {
  if (i < 192) return (u16*)(rA + (size_t)i * SZ_HAB);
  if (i < 228) return (u16*)(rB + (size_t)(i - 192) * SZ_HAB);
  return (u16*)(rC + (size_t)(i - 228) * SZ_HAB);
}

// ---------------- utility kernels ----------------
__global__ void k_zero(u32* p, int n) {
  for (int i = blockIdx.x * 256 + threadIdx.x; i < n; i += gridDim.x * 256) p[i] = 0;
}

// W (rows x kin) f32 -> tripled bf16 [W_hi | W_hi | W_lo] (rows x 3kin)  (gx GEMM only)
__global__ void k_trip(const float* __restrict__ W, u16* __restrict__ W3, int rows, int kin) {
  int n = rows * kin;
  for (int i = blockIdx.x * 256 + threadIdx.x; i < n; i += gridDim.x * 256) {
    int rr = i / kin, k = i - rr * kin;
    float v = W[i];
    u16 hi = f2bf(v);
    u16 lo = f2bf(v - bf2f(hi));
    u16* o = W3 + (size_t)rr * (3 * kin);
    o[k] = hi; o[kin + k] = hi; o[2 * kin + k] = lo;
  }
}

__global__ void k_tobf(const float* __restrict__ W, u16* __restrict__ Wb, int n) {
  for (int i = blockIdx.x * 256 + threadIdx.x; i < n; i += gridDim.x * 256) Wb[i] = f2bf(W[i]);
}

// x' = gathered embeddings split as [x_hi | x_lo | x_hi]
__global__ void k_xsplit(const int* __restrict__ inp, const float* __restrict__ emb,
                         u16* __restrict__ xs) {
  int n = Ss * Bb * Ee;
  for (int i = blockIdx.x * 256 + threadIdx.x; i < n; i += gridDim.x * 256) {
    int m = i >> 9, k = i & (Ee - 1);
    int tok = inp[m];
    float v = emb[(size_t)tok * Ee + k];
    u16 hi = f2bf(v);
    u16 lo = f2bf(v - bf2f(hi));
    u16* o = xs + (size_t)m * (3 * Ee);
    o[k] = hi; o[Ee + k] = lo; o[2 * Ee + k] = hi;
  }
}

// gxd[g] = emb_dec[EOS] . Wih_d[g] + bih_d[g]   (exact f32, once)
__global__ void k_gxd(const float* __restrict__ emb_dec, const float* __restrict__ Wih_d,
                      const float* __restrict__ bih_d, float* __restrict__ gxd) {
  int g = blockIdx.x * 256 + threadIdx.x;
  if (g >= G3) return;
  const float* er = emb_dec + 2 * Ee;        // EOS_ID = 2
  const float* wr = Wih_d + (size_t)g * Ee;
  float s = 0.f;
  for (int e = 0; e < Ee; e++) s += er[e] * wr[e];
  gxd[g] = s + bih_d[g];
}

// ---------------- generic GEMM: C[m][n] = sum_k A[m][k]*B[n][k] + bias[n] ----------------
__global__ __launch_bounds__(256, 2) void gemm_bt(
    const u16* __restrict__ A, const u16* __restrict__ Bw, const float* __restrict__ bias,
    float* __restrict__ C, int M, int N, int K) {
  __shared__ __align__(16) u16 As[128 * 32];
  __shared__ __align__(16) u16 Bs[128 * 32];
  int tid = threadIdx.x;
  int wave = tid >> 6, lane = tid & 63;
  int wr = wave >> 1, wc = wave & 1;
  int m0 = blockIdx.y * 128, n0 = blockIdx.x * 128;
  f32x4 acc[4][4];
#pragma unroll
  for (int i = 0; i < 4; i++)
#pragma unroll
    for (int j = 0; j < 4; j++) acc[i][j] = (f32x4){0.f, 0.f, 0.f, 0.f};

  int lrow = lane >> 2, lcol = (lane & 3) * 8;
  int r15 = lane & 15, kk = (lane >> 4) * 8;

  for (int k0 = 0; k0 < K; k0 += 32) {
    __syncthreads();
#pragma unroll
    for (int rch = 0; rch < 2; rch++) {
      int c = rch * 4 + wave;
      int row = c * 16 + lrow;
      llds16(A  + (size_t)(m0 + row) * K + k0 + lcol, &As[c * 512]);
      llds16(Bw + (size_t)(n0 + row) * K + k0 + lcol, &Bs[c * 512]);
    }
    __syncthreads();
    short8 af[4], bfv[4];
#pragma unroll
    for (int mi = 0; mi < 4; mi++)
      af[mi] = *(const short8*)&As[(wr * 64 + mi * 16 + r15) * 32 + kk];
#pragma unroll
    for (int ni = 0; ni < 4; ni++)
      bfv[ni] = *(const short8*)&Bs[(wc * 64 + ni * 16 + r15) * 32 + kk];
#pragma unroll
    for (int mi = 0; mi < 4; mi++)
#pragma unroll
      for (int ni = 0; ni < 4; ni++) acc[mi][ni] = mfma16(af[mi], bfv[ni], acc[mi][ni]);
  }
#pragma unroll
  for (int mi = 0; mi < 4; mi++)
#pragma unroll
    for (int ni = 0; ni < 4; ni++) {
      int col = n0 + wc * 64 + ni * 16 + r15;
      float bs = bias[col];
#pragma unroll
      for (int i = 0; i < 4; i++) {
        int row = m0 + wr * 64 + mi * 16 + (lane >> 4) * 4 + i;
        C[(size_t)row * N + col] = acc[mi][ni][i] + bs;
      }
    }
}

// ---------------- persistent GRU phase (v4: flag/leader-poll domain barrier) ----------------
// grid 256 = 64 jt x 4 bq; block 512 = 8 waves splitting K=1024 into 8x128.
// Barrier spans only a bq-domain (64 blocks): each block sc-stores FLG[bid]=st+1 on its
// own 64B line (parallel, no RMW); leader block (jt==0) wave0 polls all 64 flags with a
// single 64-lane load per iteration; lane0 then sc-stores GO[bq]=st+1; all others poll GO.
// Critical path after producer drain: ~2 L3 round-trips. gx(st+1) prefetched under poll.
template <int DEC>
__global__ __launch_bounds__(512, 1) void k_pers(
    const u16* __restrict__ W, const float* __restrict__ bhh, const float* __restrict__ gx0,
    char* rA, char* rB, char* rC, float* Hst, float* h2f0, u16* h2b0, u32* bar) {
  int tid = threadIdx.x, wave = tid >> 6, lane = tid & 63;
  int r15 = lane & 15, kk = (lane >> 4) * 8;
  int bq = blockIdx.x & 3, jt = blockIdx.x >> 2;
  int b0 = bq * 16, j0 = jt * 16;
  int kbase = wave * 128;
  const int NSTEP = DEC ? Tt : Ss;

  __shared__ float sC[8][64][13];              // stride 13 -> conflict-free
  __shared__ float hT[256];                    // h tile [bl*16+jc]
  __shared__ __align__(8) u16 stg[2][16][16];  // hi/lo staging

  int bl = tid >> 4, jc = tid & 15;            // epilogue mapping (tid<256)
  float br = 0.f, bz = 0.f, bn = 0.f;
  float xr = 0.f, xz = 0.f, xn = 0.f;
  if (tid < 256) {
    hT[tid] = DEC ? Hst[(size_t)(b0 + bl) * Hh + j0 + jc] : 0.f;
    int j = j0 + jc;
    br = bhh[j]; bz = bhh[Hh + j]; bn = bhh[2 * Hh + j];
    if (DEC) { xr = gx0[j]; xz = gx0[Hh + j]; xn = gx0[2 * Hh + j]; }
    else {                                     // prologue gx load, step 0
      const float* gr = gx0 + (size_t)(b0 + bl) * G3;
      xr = gr[j]; xz = gr[Hh + j]; xn = gr[2 * Hh + j];
    }
  }
  __syncthreads();

  const u16* Wrow = W + (size_t)(j0 + r15) * Hh + kbase + kk;
  int lsrc = (bl >> 2) * 16 + jc;              // partials source for (bl,jc)
  int isrc = bl & 3;
  int flgidx = (lane * 4 + bq) * 16;           // leader poll address per lane

  for (int st = 0; st < NSTEP; st++) {
    const u16* hin = hbuf_dev(rA, rB, rC, st);

    f32x4 acc[3];
#pragma unroll
    for (int g = 0; g < 3; g++) acc[g] = (f32x4){0.f, 0.f, 0.f, 0.f};
    const u16* Ab = hin + (size_t)(b0 + r15) * 2048 + kbase + kk;
#pragma unroll
    for (int ks = 0; ks < 4; ks++) {
      int ko = ks * 32;
      short8 ah = *(const short8*)(Ab + ko);          // h_hi (plain b128, L2-cached)
      short8 al = *(const short8*)(Ab + 1024 + ko);   // h_lo
      short8 w0 = *(const short8*)(Wrow + ko);
      short8 w1 = *(const short8*)(Wrow + (size_t)Hh * Hh + ko);
      short8 w2 = *(const short8*)(Wrow + (size_t)2 * Hh * Hh + ko);
      acc[0] = mfma16(ah, w0, acc[0]);
      acc[1] = mfma16(ah, w1, acc[1]);
      acc[2] = mfma16(ah, w2, acc[2]);
      acc[0] = mfma16(al, w0, acc[0]);
      acc[1] = mfma16(al, w1, acc[1]);
      acc[2] = mfma16(al, w2, acc[2]);
    }
#pragma unroll
    for (int g = 0; g < 3; g++)
#pragma unroll
      for (int i = 0; i < 4; i++) sC[wave][lane][g * 4 + i] = acc[g][i];
    __syncthreads();

    if (tid < 256) {
      float hgr = br, hgz = bz, hgn = bn;
#pragma unroll
      for (int w = 0; w < 8; w++) {              // fixed order -> deterministic
        hgr += sC[w][lsrc][isrc];
        hgz += sC[w][lsrc][4 + isrc];
        hgn += sC[w][lsrc][8 + isrc];
      }
      float rg = 1.0f / (1.0f + expf(-(xr + hgr)));
      float zg = 1.0f / (1.0f + expf(-(xz + hgz)));
      float ng = tanhf(xn + rg * hgn);
      float hn = (1.0f - zg) * ng + zg * hT[tid];
      hT[tid] = hn;
      u16 hi = f2bf(hn), lo = f2bf(hn - bf2f(hi));
      stg[0][bl][jc] = hi;
      stg[1][bl][jc] = lo;
      if (DEC) ag_store_f32(&h2f0[((size_t)st * Bb + b0 + bl) * Hh + j0 + jc], hn);
    }
    __syncthreads();

    // distributed sc stores of the next-step buffer (skipped on last step)
    if (tid < 256) {
      int part = tid >> 7, idx = tid & 127, row = idx >> 3, dw = idx & 7;
      if (st + 1 < NSTEP) {
        u16* hout = hbuf_dev(rA, rB, rC, st + 1);
        u32 val = ((const u32*)&stg[part][row][0])[dw];
        ag_store_u32((u32*)(hout + (size_t)(b0 + row) * 2048 + part * 1024 + j0) + dw, val);
      }
      if (DEC && tid < 128) {
        u16* h2b = h2b0 + (size_t)st * Bb * Hh;
        ag_store_u32((u32*)(h2b + (size_t)(b0 + row) * Hh + j0) + dw,
                     ((const u32*)&stg[0][row][0])[dw]);
      }
    }

    if (st + 1 < NSTEP) {
      asm volatile("s_waitcnt vmcnt(0)" ::: "memory");   // own sc stores at L3
      __syncthreads();                                    // whole block drained
      if (tid == 0)
        ag_store_u32(&bar[blockIdx.x * 16], (u32)(st + 1));  // flag: own 64B line
      // prefetch gx(st+1) under the barrier wait (encoder only)
      if (!DEC && tid < 256) {
        const float* gr = gx0 + ((size_t)(st + 1) * Bb + b0 + bl) * G3;
        int j = j0 + jc;
        xr = gr[j]; xz = gr[Hh + j]; xn = gr[2 * Hh + j];
      }
      if (jt == 0) {                           // leader block of this bq-domain
        if (wave == 0) {
          for (;;) {                           // one 64-lane load per iteration
            int v = (int)ag_load_u32(&bar[flgidx]);
            if (__all(v >= st + 1)) break;
            __builtin_amdgcn_s_sleep(1);
          }
          if (lane == 0) ag_store_u32(&bar[4096 + bq * 16], (u32)(st + 1));
        }
      } else if (tid == 0) {
        while ((int)ag_load_u32(&bar[4096 + bq * 16]) < st + 1)
          __builtin_amdgcn_s_sleep(1);
      }
      __syncthreads();
    }
  }

  if (!DEC && tid < 256)
    Hst[(size_t)(b0 + bl) * Hh + j0 + jc] = hT[tid];
}

// ---------------- fallback per-step kernel (if coop launch fails) ----------------
template <int DEC>
__global__ __launch_bounds__(512, 1) void k_step3(
    const u16* __restrict__ W, const float* __restrict__ bhh, const float* __restrict__ gxp,
    const u16* __restrict__ hAin, u16* __restrict__ hAout, float* __restrict__ h,
    float* __restrict__ h2f, u16* __restrict__ h2b) {
  __shared__ float sC[4][64][13];
  int tid = threadIdx.x, wave = tid >> 6, lane = tid & 63;
  int mw = wave & 3, khalf = wave >> 2;
  int m0 = mw * 16;
  int r15 = lane & 15, kk = (lane >> 4) * 8;
  int j0 = blockIdx.x * 16;
  int kbase = khalf * 512;

  f32x4 acc[3];
#pragma unroll
  for (int g = 0; g < 3; g++) acc[g] = (f32x4){0.f, 0.f, 0.f, 0.f};

  const u16* Ah = hAin + (size_t)(m0 + r15) * 2048 + kbase + kk;
  const u16* Wr = W + (size_t)(j0 + r15) * Hh + kbase + kk;
#pragma unroll 4
  for (int ks = 0; ks < 16; ks++) {
    int ko = ks * 32;
    short8 ah = *(const short8*)(Ah + ko);
    short8 al = *(const short8*)(Ah + 1024 + ko);
    short8 b0 = *(const short8*)(Wr + ko);
    short8 b1 = *(const short8*)(Wr + (size_t)Hh * Hh + ko);
    short8 b2 = *(const short8*)(Wr + (size_t)2 * Hh * Hh + ko);
    acc[0] = mfma16(ah, b0, acc[0]);
    acc[1] = mfma16(ah, b1, acc[1]);
    acc[2] = mfma16(ah, b2, acc[2]);
    acc[0] = mfma16(al, b0, acc[0]);
    acc[1] = mfma16(al, b1, acc[1]);
    acc[2] = mfma16(al, b2, acc[2]);
  }

  if (khalf == 1) {
#pragma unroll
    for (int g = 0; g < 3; g++)
#pragma unroll
      for (int i = 0; i < 4; i++) sC[mw][lane][g * 4 + i] = acc[g][i];
  }
  __syncthreads();
  if (khalf == 1) return;

  int j = j0 + r15;
  float br = bhh[j], bz = bhh[Hh + j], bn = bhh[2 * Hh + j];
  float xrD = 0.f, xzD = 0.f, xnD = 0.f;
  if (DEC) { xrD = gxp[j]; xzD = gxp[Hh + j]; xnD = gxp[2 * Hh + j]; }
#pragma unroll
  for (int i = 0; i < 4; i++) {
    int b = m0 + (lane >> 4) * 4 + i;
    float hgr = acc[0][i] + sC[mw][lane][i]     + br;
    float hgz = acc[1][i] + sC[mw][lane][4 + i] + bz;
    float hgn = acc[2][i] + sC[mw][lane][8 + i] + bn;
    float xr, xz, xn;
    if (DEC) { xr = xrD; xz = xzD; xn = xnD; }
    else {
      const float* gr = gxp + (size_t)b * G3;
      xr = gr[j]; xz = gr[Hh + j]; xn = gr[2 * Hh + j];
    }
    float rg = 1.0f / (1.0f + expf(-(xr + hgr)));
    float zg = 1.0f / (1.0f + expf(-(xz + hgz)));
    float ng = tanhf(xn + rg * hgn);
    float hold = h[(size_t)b * Hh + j];
    float hn = (1.0f - zg) * ng + zg * hold;
    h[(size_t)b * Hh + j] = hn;
    u16 hi = f2bf(hn);
    u16 lo = f2bf(hn - bf2f(hi));
    hAout[(size_t)b * 2048 + j] = hi;
    hAout[(size_t)b * 2048 + 1024 + j] = lo;
    if (DEC) {
      h2f[(size_t)b * Hh + j] = hn;
      h2b[(size_t)b * Hh + j] = hi;
    }
  }
}

// ---------------- heads (exact f32) ----------------
__global__ __launch_bounds__(256, 2) void k_head1(const float* __restrict__ h,
    const float* __restrict__ Wenc, const float* __restrict__ benc, float* __restrict__ henc) {
  int b = blockIdx.x;
  __shared__ float hs[Hh];
  for (int k = threadIdx.x; k < Hh; k += 256) hs[k] = h[(size_t)b * Hh + k];
  __syncthreads();
  int q = threadIdx.x;
  const float* wrw = Wenc + (size_t)q * Hh;
  float s = 0.f;
  for (int k = 0; k < Hh; k++) s += hs[k] * wrw[k];
  henc[b * Zz + q] = s + benc[q];
}

__global__ __launch_bounds__(256, 2) void k_head2(const float* __restrict__ henc,
    const float* __restrict__ Wloc, const float* __restrict__ bloc,
    const float* __restrict__ Wsc, const float* __restrict__ bsc,
    const float* __restrict__ eps, float* __restrict__ outLoc, float* __restrict__ outSc,
    float* __restrict__ zb) {
  int b = blockIdx.x;
  __shared__ float hs[Zz];
  if (threadIdx.x < Zz) hs[threadIdx.x] = henc[b * Zz + threadIdx.x];
  __syncthreads();
  int q = threadIdx.x;
  const float* wl = Wloc + (size_t)q * Zz;
  const float* wsp = Wsc + (size_t)q * Zz;
  float sl = 0.f, ssum = 0.f;
  for (int k = 0; k < Zz; k++) { sl += hs[k] * wl[k]; ssum += hs[k] * wsp[k]; }
  sl += bloc[q]; ssum += bsc[q];
  float sp = fmaxf(ssum, 0.f) + log1pf(expf(-fabsf(ssum)));  // softplus, stable
  float zv = sl + eps[b * Zz + q] * expf(0.5f * sp);
  outLoc[b * Zz + q] = sl;
  outSc[b * Zz + q] = sp;
  zb[b * Zz + q] = zv;
}

__global__ __launch_bounds__(256, 2) void k_head3(const float* __restrict__ zb,
    const float* __restrict__ Wdec, const float* __restrict__ bdec,
    float* __restrict__ h, u16* __restrict__ hA0) {
  int b = blockIdx.x;
  __shared__ float zs[Zz];
  if (threadIdx.x < Zz) zs[threadIdx.x] = zb[b * Zz + threadIdx.x];
  __syncthreads();
  for (int j = threadIdx.x; j < Hh; j += 256) {
    const float* wrw = Wdec + (size_t)j * Zz;
    float s = 0.f;
    for (int k = 0; k < Zz; k++) s += zs[k] * wrw[k];
    s += bdec[j];
    h[(size_t)b * Hh + j] = s;
    u16 hi = f2bf(s);
    u16 lo = f2bf(s - bf2f(hi));
    hA0[(size_t)b * 2048 + j] = hi;
    hA0[(size_t)b * 2048 + 1024 + j] = lo;
  }
}

// ---------------- row reduce: max, sumexp, candidates ----------------
__global__ __launch_bounds__(256, 2) void k_rowred(const float* __restrict__ logits,
    float* __restrict__ rowmax, float* __restrict__ sumexp, int* __restrict__ ccnt,
    int* __restrict__ cand) {
  int r = blockIdx.x;
  const float* row = logits + (size_t)r * Vv;
  __shared__ float red[4];
  __shared__ float srm;
  __shared__ int lcnt;
  __shared__ int lcand[32];
  int tid = threadIdx.x, wave = tid >> 6, lane = tid & 63;
  if (tid == 0) lcnt = 0;
  float m = -3.0e38f;
  for (int c = tid * 4; c < Vv; c += 1024) {
    f32x4 v = *(const f32x4*)(row + c);
    m = fmaxf(fmaxf(fmaxf(m, v.x), v.y), fmaxf(v.z, v.w));
  }
  for (int o = 32; o; o >>= 1) m = fmaxf(m, __shfl_xor(m, o));
  if (lane == 0) red[wave] = m;
  __syncthreads();
  if (tid == 0) srm = fmaxf(fmaxf(red[0], red[1]), fmaxf(red[2], red[3]));
  __syncthreads();
  float rm = srm;
  float s = 0.f;
  for (int c = tid * 4; c < Vv; c += 1024) {
    f32x4 v = *(const f32x4*)(row + c);
    s += expf(v.x - rm) + expf(v.y - rm) + expf(v.z - rm) + expf(v.w - rm);
    if (v.x >= rm - 0.0625f) { int sl = atomicAdd(&lcnt, 1); if (sl < 32) lcand[sl] = c; }
    if (v.y >= rm - 0.0625f) { int sl = atomicAdd(&lcnt, 1); if (sl < 32) lcand[sl] = c + 1; }
    if (v.z >= rm - 0.0625f) { int sl = atomicAdd(&lcnt, 1); if (sl < 32) lcand[sl] = c + 2; }
    if (v.w >= rm - 0.0625f) { int sl = atomicAdd(&lcnt, 1); if (sl < 32) lcand[sl] = c + 3; }
  }
  for (int o = 32; o; o >>= 1) s += __shfl_xor(s, o);
  if (lane == 0) red[wave] = s;
  __syncthreads();
  if (tid == 0) {
    float st = red[0] + red[1] + red[2] + red[3];
    int cc = lcnt < 32 ? lcnt : 32;
    for (int i = 0; i < cc; i++)
      for (int k2 = i + 1; k2 < cc; k2++)
        if (lcand[k2] < lcand[i]) { int t = lcand[i]; lcand[i] = lcand[k2]; lcand[k2] = t; }
    rowmax[r] = rm; sumexp[r] = st; ccnt[r] = cc;
    for (int i = 0; i < cc; i++) cand[r * 32 + i] = lcand[i];
  }
}

// ---------------- refine candidates exactly in f32, correct LSE, per-row best ----------------
__global__ __launch_bounds__(256, 1) void k_refine(const float* __restrict__ logits,
    const float* __restrict__ h2f, const float* __restrict__ Wvoc, const float* __restrict__ bvoc,
    const float* __restrict__ rowmax, const float* __restrict__ sumexp,
    const int* __restrict__ ccnt, const int* __restrict__ cand,
    float* __restrict__ lsec, float* __restrict__ bestv, int* __restrict__ besti) {
  int r = blockIdx.x;
  __shared__ float hrow[Hh];
  __shared__ float lex[32];
  __shared__ float del[32];
  int tid = threadIdx.x, wave = tid >> 6, lane = tid & 63;
  for (int k = tid; k < Hh; k += 256) hrow[k] = h2f[(size_t)r * Hh + k];
  int cnt = ccnt[r];
  float rm = rowmax[r];
  __syncthreads();
  for (int ci = wave; ci < cnt; ci += 4) {
    int v = cand[r * 32 + ci];
    const float* wrw = Wvoc + (size_t)v * Hh;
    float s = 0.f;
    for (int k = lane; k < Hh; k += 64) s += hrow[k] * wrw[k];
    for (int o = 32; o; o >>= 1) s += __shfl_xor(s, o);
    if (lane == 0) {
      float le = s + bvoc[v];
      lex[ci] = le;
      float la = logits[(size_t)r * Vv + v];
      del[ci] = expf(le - rm) - expf(la - rm);
    }
  }
  __syncthreads();
  if (tid == 0) {
    float se = sumexp[r];
    for (int i = 0; i < cnt; i++) se += del[i];
    float lse = rm + logf(se);
    lsec[r] = lse;
    float bv = -3.0e38f; int bvi = 0;
    for (int i = 0; i < cnt; i++)
      if (lex[i] > bv) { bv = lex[i]; bvi = cand[r * 32 + i]; }
    bestv[r] = bv - lse;
    besti[r] = (r & 63) * Vv + bvi;
  }
}

// ---------------- per-step global argmax -> seq ----------------
__global__ void k_argmax(const float* __restrict__ bestv, const int* __restrict__ besti,
                         float* __restrict__ outseq) {
  int tid = threadIdx.x;
  if (tid == 0) outseq[0] = 1.0f;
  for (int t = 0; t < Tt; t++) {
    float v = bestv[t * 64 + tid];
    int ii = besti[t * 64 + tid];
    for (int o = 1; o < 64; o <<= 1) {
      float ov = __shfl_xor(v, o);
      int oi = __shfl_xor(ii, o);
      if (ov > v || (ov == v && oi < ii)) { v = ov; ii = oi; }
    }
    if (tid == 0) outseq[1 + t] = (float)ii;
  }
}

// ---------------- in-place log-softmax: logits -= lse[row] ----------------
__global__ __launch_bounds__(256, 2) void k_logp(float* __restrict__ logits,
                                                 const float* __restrict__ lsec) {
  size_t total = (size_t)Tt * Bb * Vv / 4;
  for (size_t p = (size_t)blockIdx.x * 256 + threadIdx.x; p < total;
       p += (size_t)gridDim.x * 256) {
    int r = (int)(p / (Vv / 4));
    f32x4 v = *(f32x4*)(logits + p * 4);
    float l = lsec[r];
    v.x -= l; v.y -= l; v.z -= l; v.w -= l;
    *(f32x4*)(logits + p * 4) = v;
  }
}

// ---------------- host: launch sequence ----------------
extern "C" void kernel_launch(void* const* d_in, const int* in_sizes, int n_in,
                              void* d_out, int out_size, void* d_ws, size_t ws_size,
                              hipStream_t stream) {
  (void)in_sizes; (void)n_in; (void)out_size; (void)ws_size;
  const int*   inp     = (const int*)d_in[0];
  const float* eps     = (const float*)d_in[1];
  const float* emb_enc = (const float*)d_in[2];
  const float* Wih_e   = (const float*)d_in[3];
  const float* Whh_e   = (const float*)d_in[4];
  const float* bih_e   = (const float*)d_in[5];
  const float* bhh_e   = (const float*)d_in[6];
  const float* W_enc   = (const float*)d_in[7];
  const float* b_enc   = (const float*)d_in[8];
  const float* W_loc   = (const float*)d_in[9];
  const float* b_loc   = (const float*)d_in[10];
  const float* W_sc    = (const float*)d_in[11];
  const float* b_sc    = (const float*)d_in[12];
  const float* emb_dec = (const float*)d_in[13];
  const float* W_dec   = (const float*)d_in[14];
  const float* b_dec   = (const float*)d_in[15];
  const float* Wih_d   = (const float*)d_in[16];
  const float* Whh_d   = (const float*)d_in[17];
  const float* bih_d   = (const float*)d_in[18];
  const float* bhh_d   = (const float*)d_in[19];
  const float* W_voc   = (const float*)d_in[20];
  const float* b_voc   = (const float*)d_in[21];

  char* ws = (char*)d_ws;
  u16*   WHHE  = (u16*)(ws + OFF_WHHE);
  u16*   WHHD  = (u16*)(ws + OFF_WHHD);
  u16*   WIHE3 = (u16*)(ws + OFF_WIHE3);
  u16*   WVOC  = (u16*)(ws + OFF_WVOC);
  u16*   XS    = (u16*)(ws + OFF_XS);
  float* GX    = (float*)(ws + OFF_GX);
  float* Hst   = (float*)(ws + OFF_H);
  float* H2F   = (float*)(ws + OFF_H2F);
  u16*   H2B   = (u16*)(ws + OFF_H2B);
  float* GXD   = (float*)(ws + OFF_GXD);
  float* HENC  = (float*)(ws + OFF_HENC);
  float* ZB    = (float*)(ws + OFF_ZB);
  float* RM    = (float*)(ws + OFF_RM);
  float* SE    = (float*)(ws + OFF_SE);
  float* LSE   = (float*)(ws + OFF_LSE);
  float* BV    = (float*)(ws + OFF_BV);
  int*   BI    = (int*)(ws + OFF_BI);
  int*   CC    = (int*)(ws + OFF_CC);
  int*   CAND  = (int*)(ws + OFF_CAND);
  u32*   BAR   = (u32*)(ws + OFF_BAR);

  char* rA = ws + OFF_XS;      // step-buffer regions
  char* rB = ws + OFF_WIHE3;
  char* rC = ws + OFF_H2F;
  auto hbuf = [&](int i) -> u16* {
    if (i < 192) return (u16*)(rA + (size_t)i * SZ_HAB);
    if (i < 228) return (u16*)(rB + (size_t)(i - 192) * SZ_HAB);
    return (u16*)(rC + (size_t)(i - 228) * SZ_HAB);
  };

  float* out     = (float*)d_out;
  float* logits  = out;                                   // (T*B, V) f32
  float* outseq  = out + (size_t)Tt * Bb * Vv;
  float* outloc  = outseq + (Tt + 1);
  float* outsc   = outloc + Bb * Zz;

  // --- weight conversions ---
  k_tobf<<<1024, 256, 0, stream>>>(Whh_e, WHHE, G3 * Hh);
  k_tobf<<<1024, 256, 0, stream>>>(Whh_d, WHHD, G3 * Hh);
  k_trip<<<512, 256, 0, stream>>>(Wih_e, WIHE3, G3, Ee);
  k_tobf<<<2048, 256, 0, stream>>>(W_voc, WVOC, Vv * Hh);
  k_xsplit<<<2048, 256, 0, stream>>>(inp, emb_enc, XS);

  // --- gx = x' * Wih_e3^T + bih_e   (M=16384, N=3072, K=1536) ---
  {
    dim3 g(G3 / 128, (Ss * Bb) / 128);
    gemm_bt<<<g, 256, 0, stream>>>(XS, WIHE3, bih_e, GX, Ss * Bb, G3, 3 * Ee);
  }
  k_gxd<<<12, 256, 0, stream>>>(emb_dec, Wih_d, bih_d, GXD);
  k_zero<<<64, 256, 0, stream>>>((u32*)hbuf(0), (int)(SZ_HAB / 4));  // h0 = 0
  k_zero<<<1, 256, 0, stream>>>(BAR, 4224);

  // --- encoder: persistent cooperative (256 steps), fallback = per-step loop ---
  hipError_t ce;
  {
    const u16* a0 = WHHE; const float* a1 = bhh_e; const float* a2 = GX;
    char* a3 = rA; char* a4 = rB; char* a5 = rC; float* a6 = Hst;
    float* a7 = nullptr; u16* a8 = nullptr; u32* a9 = BAR;
    void* args[] = {&a0,&a1,&a2,&a3,&a4,&a5,&a6,&a7,&a8,&a9};
    ce = hipLaunchCooperativeKernel(reinterpret_cast<void*>(&k_pers<0>),
                                    dim3(256), dim3(512), args, 0, stream);
  }
  if (ce != hipSuccess) {
    for (int s = 0; s < Ss; s++)
      k_step3<0><<<64, 512, 0, stream>>>(WHHE, bhh_e, GX + (size_t)s * Bb * G3,
                                         hbuf(s), hbuf(s + 1), Hst, nullptr, nullptr);
  }

  // --- heads ---
  k_head1<<<64, 256, 0, stream>>>(Hst, W_enc, b_enc, HENC);
  k_head2<<<64, 256, 0, stream>>>(HENC, W_loc, b_loc, W_sc, b_sc, eps, outloc, outsc, ZB);
  k_head3<<<64, 256, 0, stream>>>(ZB, W_dec, b_dec, Hst, hbuf(0));
  k_zero<<<1, 256, 0, stream>>>(BAR, 4224);

  // --- decoder: persistent cooperative (64 steps), fallback = per-step loop ---
  {
    const u16* a0 = WHHD; const float* a1 = bhh_d; const float* a2 = GXD;
    char* a3 = rA; char* a4 = rB; char* a5 = rC; float* a6 = Hst;
    float* a7 = H2F; u16* a8 = H2B; u32* a9 = BAR;
    void* args[] = {&a0,&a1,&a2,&a3,&a4,&a5,&a6,&a7,&a8,&a9};
    hipError_t cd = hipLaunchCooperativeKernel(reinterpret_cast<void*>(&k_pers<1>),
                                               dim3(256), dim3(512), args, 0, stream);
    if (cd != hipSuccess) {
      for (int t = 0; t < Tt; t++)
        k_step3<1><<<64, 512, 0, stream>>>(WHHD, bhh_d, GXD, hbuf(t), hbuf(t + 1), Hst,
                                           H2F + (size_t)t * Bb * Hh,
                                           H2B + (size_t)t * Bb * Hh);
    }
  }

  // --- vocab projection: logits = h2 * Wvoc^T + b_voc  (M=4096, N=32000, K=1024) ---
  {
    dim3 g(Vv / 128, (Tt * Bb) / 128);
    gemm_bt<<<g, 256, 0, stream>>>(H2B, WVOC, b_voc, logits, Tt * Bb, Vv, Hh);
  }

  // --- softmax stats + exact argmax refinement ---
  k_rowred<<<Tt * Bb, 256, 0, stream>>>(logits, RM, SE, CC, CAND);
  k_refine<<<Tt * Bb, 256, 0, stream>>>(logits, H2F, W_voc, b_voc, RM, SE, CC, CAND, LSE, BV, BI);
  k_argmax<<<1, 64, 0, stream>>>(BV, BI, outseq);
  k_logp<<<2048, 256, 0, stream>>>(logits, LSE);
}

// Round 10
// 2637.084 us; speedup vs baseline: 5.4019x; 1.0712x over previous
//
#include <hip/hip_runtime.h>
#include <math.h>
#include <stdint.h>
#include <stddef.h>

typedef unsigned short u16;
typedef unsigned int   u32;
typedef __attribute__((ext_vector_type(8))) short short8;   // bf16x8 MFMA frag
typedef __attribute__((ext_vector_type(4))) float f32x4;

#define DI __device__ __forceinline__

// ---------------- problem constants ----------------
static constexpr int Vv = 32000, Ee = 512, Hh = 1024, Zz = 256;
static constexpr int Bb = 64, Ss = 256, Tt = 64;
static constexpr int G3 = 3 * Hh;            // 3072

// ---------------- workspace layout (bytes) ----------------
static constexpr size_t OFF_WHHE  = 0;                               // bf16 [3072][1024]
static constexpr size_t SZ_WHH    = (size_t)G3 * Hh * 2;             // 6,291,456
static constexpr size_t OFF_WHHD  = OFF_WHHE + SZ_WHH;
static constexpr size_t OFF_WIHE3 = OFF_WHHD + SZ_WHH;               // bf16 Wih (3.1MB) / buf region B
static constexpr size_t SZ_WIHE3  = (size_t)G3 * (3 * Ee) * 2;       // region B span: 9,437,184
static constexpr size_t OFF_WVOC  = OFF_WIHE3 + SZ_WIHE3;
static constexpr size_t SZ_WVOC   = (size_t)Vv * Hh * 2;             // 65,536,000
static constexpr size_t OFF_XS    = OFF_WVOC + SZ_WVOC;              // bf16 x (16.8MB) / buf region A
static constexpr size_t SZ_XS     = (size_t)Ss * Bb * (3 * Ee) * 2;  // region A span: 50,331,648
static constexpr size_t OFF_GX    = OFF_XS + SZ_XS;
static constexpr size_t SZ_GX     = (size_t)Ss * Bb * G3 * 4;        // 201,326,592
static constexpr size_t OFF_H2B   = OFF_GX;                          // overlay: GX head dead before decoder
static constexpr size_t OFF_H2F   = OFF_GX + SZ_GX;                  // buf region C during encoder
static constexpr size_t SZ_H2F    = (size_t)Tt * Bb * Hh * 4;        // 16,777,216
static constexpr size_t OFF_H     = OFF_H2F + SZ_H2F;
static constexpr size_t OFF_GXD   = OFF_H + (size_t)Bb * Hh * 4;
static constexpr size_t OFF_HENC  = OFF_GXD + 12288;
static constexpr size_t OFF_ZB    = OFF_HENC + (size_t)Bb * Zz * 4;
static constexpr size_t OFF_RM    = OFF_ZB + (size_t)Bb * Zz * 4;
static constexpr size_t OFF_SE    = OFF_RM + 16384;
static constexpr size_t OFF_LSE   = OFF_SE + 16384;
static constexpr size_t OFF_BV    = OFF_LSE + 16384;
static constexpr size_t OFF_BI    = OFF_BV + 16384;
static constexpr size_t OFF_CC    = OFF_BI + 16384;
static constexpr size_t OFF_CAND  = OFF_CC + 16384;
static constexpr size_t OFF_BAR   = OFF_CAND + (size_t)4096 * 32 * 4;
// BAR: FLG[256] at u32 idx bid*16 (64B lines). 4096 u32.

static constexpr size_t SZ_HAB    = (size_t)Bb * 2 * Hh * 2;         // 262,144 per step-buffer

// ---------------- small helpers ----------------
DI u16 f2bf(float f) {                       // f32 -> bf16 RNE
  u32 u = __float_as_uint(f);
  u32 r = (u + 0x7FFFu + ((u >> 16) & 1u)) >> 16;
  return (u16)r;
}
DI float bf2f(u16 h) { return __uint_as_float(((u32)h) << 16); }

DI f32x4 mfma16(short8 a, short8 b, f32x4 c) {
  return __builtin_amdgcn_mfma_f32_16x16x32_bf16(a, b, c, 0, 0, 0);
}
DI void llds16(const u16* g, u16* l) {       // async global->LDS, 16B/lane
  __builtin_amdgcn_global_load_lds(
      (const __attribute__((address_space(1))) u32*)g,
      (__attribute__((address_space(3))) u32*)l, 16, 0, 0);
}

// agent-scope ops: write-through past L2 to L3 coherence point / L2-bypassing load.
DI void ag_store_u32(u32* p, u32 v) {
  __hip_atomic_store(p, v, __ATOMIC_RELAXED, __HIP_MEMORY_SCOPE_AGENT);
}
DI u32 ag_load_u32(const u32* p) {
  return __hip_atomic_load((u32*)p, __ATOMIC_RELAXED, __HIP_MEMORY_SCOPE_AGENT);
}
DI void ag_store_f32(float* p, float v) {
  __hip_atomic_store(p, v, __ATOMIC_RELAXED, __HIP_MEMORY_SCOPE_AGENT);
}

// per-step hA buffer: regions A (XS, 192) | B (WIHE3, 36) | C (H2F, 29). Written once
// (sc stores, step st-1), read once (plain b128, step st) -> no stale L2 copies possible.
DI u16* hbuf_dev(char* rA, char* rB, char* rC, int i) {
  if (i < 192) return (u16*)(rA + (size_t)i * SZ_HAB);
  if (i < 228) return (u16*)(rB + (size_t)(i - 192) * SZ_HAB);
  return (u16*)(rC + (size_t)(i - 228) * SZ_HAB);
}

// ---------------- utility kernels ----------------
__global__ void k_zero(u32* p, int n) {
  for (int i = blockIdx.x * 256 + threadIdx.x; i < n; i += gridDim.x * 256) p[i] = 0;
}

__global__ void k_tobf(const float* __restrict__ W, u16* __restrict__ Wb, int n) {
  for (int i = blockIdx.x * 256 + threadIdx.x; i < n; i += gridDim.x * 256) Wb[i] = f2bf(W[i]);
}

// x = emb_enc[token] gathered as plain bf16 (S*B x E). Dropped split terms are
// ~4e-4 per gate: an order below the recurrence's accepted W-quant noise.
__global__ void k_xgather(const int* __restrict__ inp, const float* __restrict__ emb,
                          u16* __restrict__ xs) {
  int n = Ss * Bb * Ee;
  for (int i = blockIdx.x * 256 + threadIdx.x; i < n; i += gridDim.x * 256) {
    int m = i >> 9, k = i & (Ee - 1);
    xs[i] = f2bf(emb[(size_t)inp[m] * Ee + k]);
  }
}

// gxd[g] = emb_dec[EOS] . Wih_d[g] + bih_d[g]   (exact f32, once)
__global__ void k_gxd(const float* __restrict__ emb_dec, const float* __restrict__ Wih_d,
                      const float* __restrict__ bih_d, float* __restrict__ gxd) {
  int g = blockIdx.x * 256 + threadIdx.x;
  if (g >= G3) return;
  const float* er = emb_dec + 2 * Ee;        // EOS_ID = 2
  const float* wr = Wih_d + (size_t)g * Ee;
  float s = 0.f;
  for (int e = 0; e < Ee; e++) s += er[e] * wr[e];
  gxd[g] = s + bih_d[g];
}

// ---------------- generic GEMM: C[m][n] = sum_k A[m][k]*B[n][k] + bias[n] ----------------
__global__ __launch_bounds__(256, 2) void gemm_bt(
    const u16* __restrict__ A, const u16* __restrict__ Bw, const float* __restrict__ bias,
    float* __restrict__ C, int M, int N, int K) {
  __shared__ __align__(16) u16 As[128 * 32];
  __shared__ __align__(16) u16 Bs[128 * 32];
  int tid = threadIdx.x;
  int wave = tid >> 6, lane = tid & 63;
  int wr = wave >> 1, wc = wave & 1;
  int m0 = blockIdx.y * 128, n0 = blockIdx.x * 128;
  f32x4 acc[4][4];
#pragma unroll
  for (int i = 0; i < 4; i++)
#pragma unroll
    for (int j = 0; j < 4; j++) acc[i][j] = (f32x4){0.f, 0.f, 0.f, 0.f};

  int lrow = lane >> 2, lcol = (lane & 3) * 8;
  int r15 = lane & 15, kk = (lane >> 4) * 8;

  for (int k0 = 0; k0 < K; k0 += 32) {
    __syncthreads();
#pragma unroll
    for (int rch = 0; rch < 2; rch++) {
      int c = rch * 4 + wave;
      int row = c * 16 + lrow;
      llds16(A  + (size_t)(m0 + row) * K + k0 + lcol, &As[c * 512]);
      llds16(Bw + (size_t)(n0 + row) * K + k0 + lcol, &Bs[c * 512]);
    }
    __syncthreads();
    short8 af[4], bfv[4];
#pragma unroll
    for (int mi = 0; mi < 4; mi++)
      af[mi] = *(const short8*)&As[(wr * 64 + mi * 16 + r15) * 32 + kk];
#pragma unroll
    for (int ni = 0; ni < 4; ni++)
      bfv[ni] = *(const short8*)&Bs[(wc * 64 + ni * 16 + r15) * 32 + kk];
#pragma unroll
    for (int mi = 0; mi < 4; mi++)
#pragma unroll
      for (int ni = 0; ni < 4; ni++) acc[mi][ni] = mfma16(af[mi], bfv[ni], acc[mi][ni]);
  }
#pragma unroll
  for (int mi = 0; mi < 4; mi++)
#pragma unroll
    for (int ni = 0; ni < 4; ni++) {
      int col = n0 + wc * 64 + ni * 16 + r15;
      float bs = bias[col];
#pragma unroll
      for (int i = 0; i < 4; i++) {
        int row = m0 + wr * 64 + mi * 16 + (lane >> 4) * 4 + i;
        C[(size_t)row * N + col] = acc[mi][ni][i] + bs;
      }
    }
}

// ---------------- persistent GRU phase (v5: direct all-block flag polling) ----------------
// grid 256 = 64 jt x 4 bq; block 512 = 8 waves splitting K=1024 into 8x128.
// Barrier spans only a bq-domain (64 blocks): each block sc-stores FLG[bid]=st+1 on its
// own 64B line; EVERY wave of every block polls all 64 domain flags itself with a single
// 64-lane load per iteration (no leader, no GO hop, no post-poll syncthreads -- the
// pre-poll syncthreads already ordered all LDS reuse). gx(st+1) prefetched under poll.
template <int DEC>
__global__ __launch_bounds__(512, 1) void k_pers(
    const u16* __restrict__ W, const float* __restrict__ bhh, const float* __restrict__ gx0,
    char* rA, char* rB, char* rC, float* Hst, float* h2f0, u16* h2b0, u32* bar) {
  int tid = threadIdx.x, wave = tid >> 6, lane = tid & 63;
  int r15 = lane & 15, kk = (lane >> 4) * 8;
  int bq = blockIdx.x & 3, jt = blockIdx.x >> 2;
  int b0 = bq * 16, j0 = jt * 16;
  int kbase = wave * 128;
  const int NSTEP = DEC ? Tt : Ss;

  __shared__ float sC[8][64][13];              // stride 13 -> conflict-free
  __shared__ float hT[256];                    // h tile [bl*16+jc]
  __shared__ __align__(8) u16 stg[2][16][16];  // hi/lo staging

  int bl = tid >> 4, jc = tid & 15;            // epilogue mapping (tid<256)
  float br = 0.f, bz = 0.f, bn = 0.f;
  float xr = 0.f, xz = 0.f, xn = 0.f;
  if (tid < 256) {
    hT[tid] = DEC ? Hst[(size_t)(b0 + bl) * Hh + j0 + jc] : 0.f;
    int j = j0 + jc;
    br = bhh[j]; bz = bhh[Hh + j]; bn = bhh[2 * Hh + j];
    if (DEC) { xr = gx0[j]; xz = gx0[Hh + j]; xn = gx0[2 * Hh + j]; }
    else {                                     // prologue gx load, step 0
      const float* gr = gx0 + (size_t)(b0 + bl) * G3;
      xr = gr[j]; xz = gr[Hh + j]; xn = gr[2 * Hh + j];
    }
  }
  __syncthreads();

  const u16* Wrow = W + (size_t)(j0 + r15) * Hh + kbase + kk;
  int lsrc = (bl >> 2) * 16 + jc;              // partials source for (bl,jc)
  int isrc = bl & 3;
  int flgidx = (lane * 4 + bq) * 16;           // poll address per lane (lane = jt')

  for (int st = 0; st < NSTEP; st++) {
    const u16* hin = hbuf_dev(rA, rB, rC, st);

    f32x4 acc[3];
#pragma unroll
    for (int g = 0; g < 3; g++) acc[g] = (f32x4){0.f, 0.f, 0.f, 0.f};
    const u16* Ab = hin + (size_t)(b0 + r15) * 2048 + kbase + kk;
#pragma unroll
    for (int ks = 0; ks < 4; ks++) {
      int ko = ks * 32;
      short8 ah = *(const short8*)(Ab + ko);          // h_hi (plain b128, L2-cached)
      short8 al = *(const short8*)(Ab + 1024 + ko);   // h_lo
      short8 w0 = *(const short8*)(Wrow + ko);
      short8 w1 = *(const short8*)(Wrow + (size_t)Hh * Hh + ko);
      short8 w2 = *(const short8*)(Wrow + (size_t)2 * Hh * Hh + ko);
      acc[0] = mfma16(ah, w0, acc[0]);
      acc[1] = mfma16(ah, w1, acc[1]);
      acc[2] = mfma16(ah, w2, acc[2]);
      acc[0] = mfma16(al, w0, acc[0]);
      acc[1] = mfma16(al, w1, acc[1]);
      acc[2] = mfma16(al, w2, acc[2]);
    }
#pragma unroll
    for (int g = 0; g < 3; g++)
#pragma unroll
      for (int i = 0; i < 4; i++) sC[wave][lane][g * 4 + i] = acc[g][i];
    __syncthreads();

    if (tid < 256) {
      float hgr = br, hgz = bz, hgn = bn;
#pragma unroll
      for (int w = 0; w < 8; w++) {              // fixed order -> deterministic
        hgr += sC[w][lsrc][isrc];
        hgz += sC[w][lsrc][4 + isrc];
        hgn += sC[w][lsrc][8 + isrc];
      }
      float rg = 1.0f / (1.0f + expf(-(xr + hgr)));
      float zg = 1.0f / (1.0f + expf(-(xz + hgz)));
      float ng = tanhf(xn + rg * hgn);
      float hn = (1.0f - zg) * ng + zg * hT[tid];
      hT[tid] = hn;
      u16 hi = f2bf(hn), lo = f2bf(hn - bf2f(hi));
      stg[0][bl][jc] = hi;
      stg[1][bl][jc] = lo;
      if (DEC) ag_store_f32(&h2f0[((size_t)st * Bb + b0 + bl) * Hh + j0 + jc], hn);
    }
    __syncthreads();

    // distributed sc stores of the next-step buffer (skipped on last step)
    if (tid < 256) {
      int part = tid >> 7, idx = tid & 127, row = idx >> 3, dw = idx & 7;
      if (st + 1 < NSTEP) {
        u16* hout = hbuf_dev(rA, rB, rC, st + 1);
        u32 val = ((const u32*)&stg[part][row][0])[dw];
        ag_store_u32((u32*)(hout + (size_t)(b0 + row) * 2048 + part * 1024 + j0) + dw, val);
      }
      if (DEC && tid < 128) {
        u16* h2b = h2b0 + (size_t)st * Bb * Hh;
        ag_store_u32((u32*)(h2b + (size_t)(b0 + row) * Hh + j0) + dw,
                     ((const u32*)&stg[0][row][0])[dw]);
      }
    }

    if (st + 1 < NSTEP) {
      asm volatile("s_waitcnt vmcnt(0)" ::: "memory");   // own sc stores at L3
      __syncthreads();                                    // whole block drained
      if (tid == 0)
        ag_store_u32(&bar[blockIdx.x * 16], (u32)(st + 1));  // flag: own 64B line
      // prefetch gx(st+1) under the barrier wait (encoder only)
      if (!DEC && tid < 256) {
        const float* gr = gx0 + ((size_t)(st + 1) * Bb + b0 + bl) * G3;
        int j = j0 + jc;
        xr = gr[j]; xz = gr[Hh + j]; xn = gr[2 * Hh + j];
      }
      for (;;) {                               // every wave: one 64-lane load per iter
        int v = (int)ag_load_u32(&bar[flgidx]);
        if (__all(v >= st + 1)) break;
        __builtin_amdgcn_s_sleep(1);
      }
      // no syncthreads: waves proceed independently (LDS reuse ordered above)
    }
  }

  if (!DEC && tid < 256)
    Hst[(size_t)(b0 + bl) * Hh + j0 + jc] = hT[tid];
}

// ---------------- fallback per-step kernel (if coop launch fails) ----------------
template <int DEC>
__global__ __launch_bounds__(512, 1) void k_step3(
    const u16* __restrict__ W, const float* __restrict__ bhh, const float* __restrict__ gxp,
    const u16* __restrict__ hAin, u16* __restrict__ hAout, float* __restrict__ h,
    float* __restrict__ h2f, u16* __restrict__ h2b) {
  __shared__ float sC[4][64][13];
  int tid = threadIdx.x, wave = tid >> 6, lane = tid & 63;
  int mw = wave & 3, khalf = wave >> 2;
  int m0 = mw * 16;
  int r15 = lane & 15, kk = (lane >> 4) * 8;
  int j0 = blockIdx.x * 16;
  int kbase = khalf * 512;

  f32x4 acc[3];
#pragma unroll
  for (int g = 0; g < 3; g++) acc[g] = (f32x4){0.f, 0.f, 0.f, 0.f};

  const u16* Ah = hAin + (size_t)(m0 + r15) * 2048 + kbase + kk;
  const u16* Wr = W + (size_t)(j0 + r15) * Hh + kbase + kk;
#pragma unroll 4
  for (int ks = 0; ks < 16; ks++) {
    int ko = ks * 32;
    short8 ah = *(const short8*)(Ah + ko);
    short8 al = *(const short8*)(Ah + 1024 + ko);
    short8 b0 = *(const short8*)(Wr + ko);
    short8 b1 = *(const short8*)(Wr + (size_t)Hh * Hh + ko);
    short8 b2 = *(const short8*)(Wr + (size_t)2 * Hh * Hh + ko);
    acc[0] = mfma16(ah, b0, acc[0]);
    acc[1] = mfma16(ah, b1, acc[1]);
    acc[2] = mfma16(ah, b2, acc[2]);
    acc[0] = mfma16(al, b0, acc[0]);
    acc[1] = mfma16(al, b1, acc[1]);
    acc[2] = mfma16(al, b2, acc[2]);
  }

  if (khalf == 1) {
#pragma unroll
    for (int g = 0; g < 3; g++)
#pragma unroll
      for (int i = 0; i < 4; i++) sC[mw][lane][g * 4 + i] = acc[g][i];
  }
  __syncthreads();
  if (khalf == 1) return;

  int j = j0 + r15;
  float br = bhh[j], bz = bhh[Hh + j], bn = bhh[2 * Hh + j];
  float xrD = 0.f, xzD = 0.f, xnD = 0.f;
  if (DEC) { xrD = gxp[j]; xzD = gxp[Hh + j]; xnD = gxp[2 * Hh + j]; }
#pragma unroll
  for (int i = 0; i < 4; i++) {
    int b = m0 + (lane >> 4) * 4 + i;
    float hgr = acc[0][i] + sC[mw][lane][i]     + br;
    float hgz = acc[1][i] + sC[mw][lane][4 + i] + bz;
    float hgn = acc[2][i] + sC[mw][lane][8 + i] + bn;
    float xr, xz, xn;
    if (DEC) { xr = xrD; xz = xzD; xn = xnD; }
    else {
      const float* gr = gxp + (size_t)b * G3;
      xr = gr[j]; xz = gr[Hh + j]; xn = gr[2 * Hh + j];
    }
    float rg = 1.0f / (1.0f + expf(-(xr + hgr)));
    float zg = 1.0f / (1.0f + expf(-(xz + hgz)));
    float ng = tanhf(xn + rg * hgn);
    float hold = h[(size_t)b * Hh + j];
    float hn = (1.0f - zg) * ng + zg * hold;
    h[(size_t)b * Hh + j] = hn;
    u16 hi = f2bf(hn);
    u16 lo = f2bf(hn - bf2f(hi));
    hAout[(size_t)b * 2048 + j] = hi;
    hAout[(size_t)b * 2048 + 1024 + j] = lo;
    if (DEC) {
      h2f[(size_t)b * Hh + j] = hn;
      h2b[(size_t)b * Hh + j] = hi;
    }
  }
}

// ---------------- heads (exact f32) ----------------
__global__ __launch_bounds__(256, 2) void k_head1(const float* __restrict__ h,
    const float* __restrict__ Wenc, const float* __restrict__ benc, float* __restrict__ henc) {
  int b = blockIdx.x;
  __shared__ float hs[Hh];
  for (int k = threadIdx.x; k < Hh; k += 256) hs[k] = h[(size_t)b * Hh + k];
  __syncthreads();
  int q = threadIdx.x;
  const float* wrw = Wenc + (size_t)q * Hh;
  float s = 0.f;
  for (int k = 0; k < Hh; k++) s += hs[k] * wrw[k];
  henc[b * Zz + q] = s + benc[q];
}

__global__ __launch_bounds__(256, 2) void k_head2(const float* __restrict__ henc,
    const float* __restrict__ Wloc, const float* __restrict__ bloc,
    const float* __restrict__ Wsc, const float* __restrict__ bsc,
    const float* __restrict__ eps, float* __restrict__ outLoc, float* __restrict__ outSc,
    float* __restrict__ zb) {
  int b = blockIdx.x;
  __shared__ float hs[Zz];
  if (threadIdx.x < Zz) hs[threadIdx.x] = henc[b * Zz + threadIdx.x];
  __syncthreads();
  int q = threadIdx.x;
  const float* wl = Wloc + (size_t)q * Zz;
  const float* wsp = Wsc + (size_t)q * Zz;
  float sl = 0.f, ssum = 0.f;
  for (int k = 0; k < Zz; k++) { sl += hs[k] * wl[k]; ssum += hs[k] * wsp[k]; }
  sl += bloc[q]; ssum += bsc[q];
  float sp = fmaxf(ssum, 0.f) + log1pf(expf(-fabsf(ssum)));  // softplus, stable
  float zv = sl + eps[b * Zz + q] * expf(0.5f * sp);
  outLoc[b * Zz + q] = sl;
  outSc[b * Zz + q] = sp;
  zb[b * Zz + q] = zv;
}

__global__ __launch_bounds__(256, 2) void k_head3(const float* __restrict__ zb,
    const float* __restrict__ Wdec, const float* __restrict__ bdec,
    float* __restrict__ h, u16* __restrict__ hA0) {
  int b = blockIdx.x;
  __shared__ float zs[Zz];
  if (threadIdx.x < Zz) zs[threadIdx.x] = zb[b * Zz + threadIdx.x];
  __syncthreads();
  for (int j = threadIdx.x; j < Hh; j += 256) {
    const float* wrw = Wdec + (size_t)j * Zz;
    float s = 0.f;
    for (int k = 0; k < Zz; k++) s += zs[k] * wrw[k];
    s += bdec[j];
    h[(size_t)b * Hh + j] = s;
    u16 hi = f2bf(s);
    u16 lo = f2bf(s - bf2f(hi));
    hA0[(size_t)b * 2048 + j] = hi;
    hA0[(size_t)b * 2048 + 1024 + j] = lo;
  }
}

// ---------------- fused softmax: stats + candidate refine + in-place logp, one pass ----------------
// One block per row (T*B = 4096 rows). Row staged in 125KB LDS; single global read +
// single global write. Candidate sort + fixed-order sums preserve determinism; exact-f32
// candidate recompute preserves the argmax guarantee.
__global__ __launch_bounds__(1024, 1) void k_soft(
    float* __restrict__ logits, const float* __restrict__ h2f,
    const float* __restrict__ Wvoc, const float* __restrict__ bvoc,
    float* __restrict__ bestv, int* __restrict__ besti) {
  __shared__ float row[Vv];                    // 125 KB
  __shared__ float hrow[Hh];
  __shared__ float red[16];
  __shared__ float srm, ssum, slse;
  __shared__ int lcnt, scc;
  __shared__ int lcand[32];
  __shared__ float lex[32], del[32];
  int r = blockIdx.x;
  int tid = threadIdx.x, wave = tid >> 6, lane = tid & 63;
  float* grow = logits + (size_t)r * Vv;
  if (tid == 0) lcnt = 0;
  hrow[tid] = h2f[(size_t)r * Hh + tid];
  float m = -3.0e38f;
  for (int c = tid * 4; c < Vv; c += 4096) {
    f32x4 v = *(const f32x4*)(grow + c);
    *(f32x4*)(row + c) = v;
    m = fmaxf(fmaxf(m, v.x), fmaxf(v.y, fmaxf(v.z, v.w)));
  }
  for (int o = 32; o; o >>= 1) m = fmaxf(m, __shfl_xor(m, o));
  if (lane == 0) red[wave] = m;
  __syncthreads();
  if (tid == 0) {
    float t = red[0];
    for (int i = 1; i < 16; i++) t = fmaxf(t, red[i]);
    srm = t;
  }
  __syncthreads();
  float rm = srm;
  float s = 0.f;
  for (int c = tid * 4; c < Vv; c += 4096) {
    f32x4 v = *(const f32x4*)(row + c);
    s += expf(v.x - rm) + expf(v.y - rm) + expf(v.z - rm) + expf(v.w - rm);
    if (v.x >= rm - 0.0625f) { int sl = atomicAdd(&lcnt, 1); if (sl < 32) lcand[sl] = c; }
    if (v.y >= rm - 0.0625f) { int sl = atomicAdd(&lcnt, 1); if (sl < 32) lcand[sl] = c + 1; }
    if (v.z >= rm - 0.0625f) { int sl = atomicAdd(&lcnt, 1); if (sl < 32) lcand[sl] = c + 2; }
    if (v.w >= rm - 0.0625f) { int sl = atomicAdd(&lcnt, 1); if (sl < 32) lcand[sl] = c + 3; }
  }
  for (int o = 32; o; o >>= 1) s += __shfl_xor(s, o);
  if (lane == 0) red[wave] = s;
  __syncthreads();
  if (tid == 0) {
    float t = 0.f;
    for (int i = 0; i < 16; i++) t += red[i];   // fixed order -> deterministic
    ssum = t;
    int cc = lcnt < 32 ? lcnt : 32;
    for (int i = 0; i < cc; i++)                // sort ascending -> determinism
      for (int k2 = i + 1; k2 < cc; k2++)
        if (lcand[k2] < lcand[i]) { int q = lcand[i]; lcand[i] = lcand[k2]; lcand[k2] = q; }
    scc = cc;
  }
  __syncthreads();
  int cnt = scc;
  for (int ci = wave; ci < cnt; ci += 16) {     // exact-f32 candidate recompute
    int v = lcand[ci];
    const float* wrw = Wvoc + (size_t)v * Hh;
    float sd = 0.f;
    for (int k = lane; k < Hh; k += 64) sd += hrow[k] * wrw[k];
    for (int o = 32; o; o >>= 1) sd += __shfl_xor(sd, o);
    if (lane == 0) {
      float le = sd + bvoc[v];
      lex[ci] = le;
      del[ci] = expf(le - rm) - expf(row[v] - rm);
    }
  }
  __syncthreads();
  if (tid == 0) {
    float se = ssum;
    for (int i = 0; i < cnt; i++) se += del[i];
    float lse = rm + logf(se);
    slse = lse;
    float bv = -3.0e38f; int bvi = 0;
    for (int i = 0; i < cnt; i++)
      if (lex[i] > bv) { bv = lex[i]; bvi = lcand[i]; }  // sorted -> ties keep lowest v
    bestv[r] = bv - lse;
    besti[r] = (r & 63) * Vv + bvi;             // flat index b*V + v
  }
  __syncthreads();
  float l = slse;
  for (int c = tid * 4; c < Vv; c += 4096) {
    f32x4 v = *(const f32x4*)(row + c);
    v.x -= l; v.y -= l; v.z -= l; v.w -= l;
    *(f32x4*)(grow + c) = v;
  }
}

// ---------------- per-step global argmax -> seq ----------------
__global__ void k_argmax(const float* __restrict__ bestv, const int* __restrict__ besti,
                         float* __restrict__ outseq) {
  int tid = threadIdx.x;
  if (tid == 0) outseq[0] = 1.0f;
  for (int t = 0; t < Tt; t++) {
    float v = bestv[t * 64 + tid];
    int ii = besti[t * 64 + tid];
    for (int o = 1; o < 64; o <<= 1) {
      float ov = __shfl_xor(v, o);
      int oi = __shfl_xor(ii, o);
      if (ov > v || (ov == v && oi < ii)) { v = ov; ii = oi; }
    }
    if (tid == 0) outseq[1 + t] = (float)ii;
  }
}

// ---------------- host: launch sequence ----------------
extern "C" void kernel_launch(void* const* d_in, const int* in_sizes, int n_in,
                              void* d_out, int out_size, void* d_ws, size_t ws_size,
                              hipStream_t stream) {
  (void)in_sizes; (void)n_in; (void)out_size; (void)ws_size;
  const int*   inp     = (const int*)d_in[0];
  const float* eps     = (const float*)d_in[1];
  const float* emb_enc = (const float*)d_in[2];
  const float* Wih_e   = (const float*)d_in[3];
  const float* Whh_e   = (const float*)d_in[4];
  const float* bih_e   = (const float*)d_in[5];
  const float* bhh_e   = (const float*)d_in[6];
  const float* W_enc   = (const float*)d_in[7];
  const float* b_enc   = (const float*)d_in[8];
  const float* W_loc   = (const float*)d_in[9];
  const float* b_loc   = (const float*)d_in[10];
  const float* W_sc    = (const float*)d_in[11];
  const float* b_sc    = (const float*)d_in[12];
  const float* emb_dec = (const float*)d_in[13];
  const float* W_dec   = (const float*)d_in[14];
  const float* b_dec   = (const float*)d_in[15];
  const float* Wih_d   = (const float*)d_in[16];
  const float* Whh_d   = (const float*)d_in[17];
  const float* bih_d   = (const float*)d_in[18];
  const float* bhh_d   = (const float*)d_in[19];
  const float* W_voc   = (const float*)d_in[20];
  const float* b_voc   = (const float*)d_in[21];

  char* ws = (char*)d_ws;
  u16*   WHHE  = (u16*)(ws + OFF_WHHE);
  u16*   WHHD  = (u16*)(ws + OFF_WHHD);
  u16*   WIHB  = (u16*)(ws + OFF_WIHE3);      // plain bf16 Wih_e [3072][512]
  u16*   WVOC  = (u16*)(ws + OFF_WVOC);
  u16*   XS    = (u16*)(ws + OFF_XS);         // plain bf16 x [16384][512]
  float* GX    = (float*)(ws + OFF_GX);
  float* Hst   = (float*)(ws + OFF_H);
  float* H2F   = (float*)(ws + OFF_H2F);
  u16*   H2B   = (u16*)(ws + OFF_H2B);
  float* GXD   = (float*)(ws + OFF_GXD);
  float* HENC  = (float*)(ws + OFF_HENC);
  float* ZB    = (float*)(ws + OFF_ZB);
  float* BV    = (float*)(ws + OFF_BV);
  int*   BI    = (int*)(ws + OFF_BI);
  u32*   BAR   = (u32*)(ws + OFF_BAR);

  char* rA = ws + OFF_XS;      // step-buffer regions
  char* rB = ws + OFF_WIHE3;
  char* rC = ws + OFF_H2F;
  auto hbuf = [&](int i) -> u16* {
    if (i < 192) return (u16*)(rA + (size_t)i * SZ_HAB);
    if (i < 228) return (u16*)(rB + (size_t)(i - 192) * SZ_HAB);
    return (u16*)(rC + (size_t)(i - 228) * SZ_HAB);
  };

  float* out     = (float*)d_out;
  float* logits  = out;                                   // (T*B, V) f32
  float* outseq  = out + (size_t)Tt * Bb * Vv;
  float* outloc  = outseq + (Tt + 1);
  float* outsc   = outloc + Bb * Zz;

  // --- weight conversions ---
  k_tobf<<<1024, 256, 0, stream>>>(Whh_e, WHHE, G3 * Hh);
  k_tobf<<<1024, 256, 0, stream>>>(Whh_d, WHHD, G3 * Hh);
  k_tobf<<<512, 256, 0, stream>>>(Wih_e, WIHB, G3 * Ee);
  k_tobf<<<2048, 256, 0, stream>>>(W_voc, WVOC, Vv * Hh);
  k_xgather<<<2048, 256, 0, stream>>>(inp, emb_enc, XS);

  // --- gx = x * Wih_e^T + bih_e   (M=16384, N=3072, K=512, plain bf16) ---
  {
    dim3 g(G3 / 128, (Ss * Bb) / 128);
    gemm_bt<<<g, 256, 0, stream>>>(XS, WIHB, bih_e, GX, Ss * Bb, G3, Ee);
  }
  k_gxd<<<12, 256, 0, stream>>>(emb_dec, Wih_d, bih_d, GXD);
  k_zero<<<64, 256, 0, stream>>>((u32*)hbuf(0), (int)(SZ_HAB / 4));  // h0 = 0
  k_zero<<<1, 256, 0, stream>>>(BAR, 4096);

  // --- encoder: persistent cooperative (256 steps), fallback = per-step loop ---
  hipError_t ce;
  {
    const u16* a0 = WHHE; const float* a1 = bhh_e; const float* a2 = GX;
    char* a3 = rA; char* a4 = rB; char* a5 = rC; float* a6 = Hst;
    float* a7 = nullptr; u16* a8 = nullptr; u32* a9 = BAR;
    void* args[] = {&a0,&a1,&a2,&a3,&a4,&a5,&a6,&a7,&a8,&a9};
    ce = hipLaunchCooperativeKernel(reinterpret_cast<void*>(&k_pers<0>),
                                    dim3(256), dim3(512), args, 0, stream);
  }
  if (ce != hipSuccess) {
    for (int s = 0; s < Ss; s++)
      k_step3<0><<<64, 512, 0, stream>>>(WHHE, bhh_e, GX + (size_t)s * Bb * G3,
                                         hbuf(s), hbuf(s + 1), Hst, nullptr, nullptr);
  }

  // --- heads ---
  k_head1<<<64, 256, 0, stream>>>(Hst, W_enc, b_enc, HENC);
  k_head2<<<64, 256, 0, stream>>>(HENC, W_loc, b_loc, W_sc, b_sc, eps, outloc, outsc, ZB);
  k_head3<<<64, 256, 0, stream>>>(ZB, W_dec, b_dec, Hst, hbuf(0));
  k_zero<<<1, 256, 0, stream>>>(BAR, 4096);

  // --- decoder: persistent cooperative (64 steps), fallback = per-step loop ---
  {
    const u16* a0 = WHHD; const float* a1 = bhh_d; const float* a2 = GXD;
    char* a3 = rA; char* a4 = rB; char* a5 = rC; float* a6 = Hst;
    float* a7 = H2F; u16* a8 = H2B; u32* a9 = BAR;
    void* args[] = {&a0,&a1,&a2,&a3,&a4,&a5,&a6,&a7,&a8,&a9};
    hipError_t cd = hipLaunchCooperativeKernel(reinterpret_cast<void*>(&k_pers<1>),
                                               dim3(256), dim3(512), args, 0, stream);
    if (cd != hipSuccess) {
      for (int t = 0; t < Tt; t++)
        k_step3<1><<<64, 512, 0, stream>>>(WHHD, bhh_d, GXD, hbuf(t), hbuf(t + 1), Hst,
                                           H2F + (size_t)t * Bb * Hh,
                                           H2B + (size_t)t * Bb * Hh);
    }
  }

  // --- vocab projection: logits = h2 * Wvoc^T + b_voc  (M=4096, N=32000, K=1024) ---
  {
    dim3 g(Vv / 128, (Tt * Bb) / 128);
    gemm_bt<<<g, 256, 0, stream>>>(H2B, WVOC, b_voc, logits, Tt * Bb, Vv, Hh);
  }

  // --- fused softmax (stats + exact argmax refine + in-place log-softmax) ---
  k_soft<<<Tt * Bb, 1024, 0, stream>>>(logits, H2F, W_voc, b_voc, BV, BI);
  k_argmax<<<1, 64, 0, stream>>>(BV, BI, outseq);
}

// Round 11
// 2575.512 us; speedup vs baseline: 5.5310x; 1.0239x over previous
//
#include <hip/hip_runtime.h>
#include <math.h>
#include <stdint.h>
#include <stddef.h>

typedef unsigned short u16;
typedef unsigned int   u32;
typedef __attribute__((ext_vector_type(8))) short short8;   // bf16x8 MFMA frag
typedef __attribute__((ext_vector_type(4))) float f32x4;

#define DI __device__ __forceinline__

// ---------------- problem constants ----------------
static constexpr int Vv = 32000, Ee = 512, Hh = 1024, Zz = 256;
static constexpr int Bb = 64, Ss = 256, Tt = 64;
static constexpr int G3 = 3 * Hh;            // 3072

// ---------------- workspace layout (bytes) ----------------
static constexpr size_t OFF_WHHE  = 0;                               // bf16 [3072][1024]
static constexpr size_t SZ_WHH    = (size_t)G3 * Hh * 2;             // 6,291,456
static constexpr size_t OFF_WHHD  = OFF_WHHE + SZ_WHH;
static constexpr size_t OFF_WIHE3 = OFF_WHHD + SZ_WHH;               // bf16 Wih (3.1MB) / buf region B
static constexpr size_t SZ_WIHE3  = (size_t)G3 * (3 * Ee) * 2;       // region B span: 9,437,184
static constexpr size_t OFF_WVOC  = OFF_WIHE3 + SZ_WIHE3;
static constexpr size_t SZ_WVOC   = (size_t)Vv * Hh * 2;             // 65,536,000
static constexpr size_t OFF_XS    = OFF_WVOC + SZ_WVOC;              // bf16 x (16.8MB) / buf region A
static constexpr size_t SZ_XS     = (size_t)Ss * Bb * (3 * Ee) * 2;  // region A span: 50,331,648
static constexpr size_t OFF_GX    = OFF_XS + SZ_XS;
static constexpr size_t SZ_GX     = (size_t)Ss * Bb * G3 * 4;        // 201,326,592
static constexpr size_t OFF_H2B   = OFF_GX;                          // overlay: GX head dead before decoder
static constexpr size_t OFF_H2F   = OFF_GX + SZ_GX;                  // buf region C during encoder
static constexpr size_t SZ_H2F    = (size_t)Tt * Bb * Hh * 4;        // 16,777,216
static constexpr size_t OFF_H     = OFF_H2F + SZ_H2F;
static constexpr size_t OFF_GXD   = OFF_H + (size_t)Bb * Hh * 4;
static constexpr size_t OFF_HENC  = OFF_GXD + 12288;
static constexpr size_t OFF_ZB    = OFF_HENC + (size_t)Bb * Zz * 4;
static constexpr size_t OFF_BV    = OFF_ZB + (size_t)Bb * Zz * 4;
static constexpr size_t OFF_BI    = OFF_BV + 16384;
static constexpr size_t OFF_BAR   = OFF_BI + 16384;
// BAR: FLG[256] at u32 idx bid*16 (64B lines). 4096 u32.

static constexpr size_t SZ_HAB    = (size_t)Bb * 2 * Hh * 2;         // 262,144 per step-buffer

// ---------------- small helpers ----------------
DI u16 f2bf(float f) {                       // f32 -> bf16 RNE
  u32 u = __float_as_uint(f);
  u32 r = (u + 0x7FFFu + ((u >> 16) & 1u)) >> 16;
  return (u16)r;
}
DI float bf2f(u16 h) { return __uint_as_float(((u32)h) << 16); }

DI f32x4 mfma16(short8 a, short8 b, f32x4 c) {
  return __builtin_amdgcn_mfma_f32_16x16x32_bf16(a, b, c, 0, 0, 0);
}
DI void llds16(const u16* g, u16* l) {       // async global->LDS, 16B/lane
  __builtin_amdgcn_global_load_lds(
      (const __attribute__((address_space(1))) u32*)g,
      (__attribute__((address_space(3))) u32*)l, 16, 0, 0);
}

// agent-scope ops: write-through past L2 to L3 coherence point / L2-bypassing load.
DI void ag_store_u32(u32* p, u32 v) {
  __hip_atomic_store(p, v, __ATOMIC_RELAXED, __HIP_MEMORY_SCOPE_AGENT);
}
DI u32 ag_load_u32(const u32* p) {
  return __hip_atomic_load((u32*)p, __ATOMIC_RELAXED, __HIP_MEMORY_SCOPE_AGENT);
}
DI void ag_store_f32(float* p, float v) {
  __hip_atomic_store(p, v, __ATOMIC_RELAXED, __HIP_MEMORY_SCOPE_AGENT);
}

// per-step hA buffer: regions A (XS, 192) | B (WIHE3, 36) | C (H2F, 29). Written once
// (sc stores, step st-1), read once (plain b128, step st) -> no stale L2 copies possible.
DI u16* hbuf_dev(char* rA, char* rB, char* rC, int i) {
  if (i < 192) return (u16*)(rA + (size_t)i * SZ_HAB);
  if (i < 228) return (u16*)(rB + (size_t)(i - 192) * SZ_HAB);
  return (u16*)(rC + (size_t)(i - 228) * SZ_HAB);
}

// ---------------- utility kernels ----------------
__global__ void k_zero(u32* p, int n) {
  for (int i = blockIdx.x * 256 + threadIdx.x; i < n; i += gridDim.x * 256) p[i] = 0;
}

__global__ void k_tobf(const float* __restrict__ W, u16* __restrict__ Wb, int n) {
  for (int i = blockIdx.x * 256 + threadIdx.x; i < n; i += gridDim.x * 256) Wb[i] = f2bf(W[i]);
}

// x = emb_enc[token] gathered as plain bf16 (S*B x E)
__global__ void k_xgather(const int* __restrict__ inp, const float* __restrict__ emb,
                          u16* __restrict__ xs) {
  int n = Ss * Bb * Ee;
  for (int i = blockIdx.x * 256 + threadIdx.x; i < n; i += gridDim.x * 256) {
    int m = i >> 9, k = i & (Ee - 1);
    xs[i] = f2bf(emb[(size_t)inp[m] * Ee + k]);
  }
}

// gxd[g] = emb_dec[EOS] . Wih_d[g] + bih_d[g]   (exact f32, once)
__global__ void k_gxd(const float* __restrict__ emb_dec, const float* __restrict__ Wih_d,
                      const float* __restrict__ bih_d, float* __restrict__ gxd) {
  int g = blockIdx.x * 256 + threadIdx.x;
  if (g >= G3) return;
  const float* er = emb_dec + 2 * Ee;        // EOS_ID = 2
  const float* wr = Wih_d + (size_t)g * Ee;
  float s = 0.f;
  for (int e = 0; e < Ee; e++) s += er[e] * wr[e];
  gxd[g] = s + bih_d[g];
}

// ---------------- generic GEMM: C[m][n] = sum_k A[m][k]*B[n][k] + bias[n] ----------------
// 2D grid form (blockIdx.x = n-panel, blockIdx.y = m-panel): used for gx (B fits L2).
__global__ __launch_bounds__(256, 2) void gemm_bt(
    const u16* __restrict__ A, const u16* __restrict__ Bw, const float* __restrict__ bias,
    float* __restrict__ C, int M, int N, int K) {
  __shared__ __align__(16) u16 As[128 * 32];
  __shared__ __align__(16) u16 Bs[128 * 32];
  int tid = threadIdx.x;
  int wave = tid >> 6, lane = tid & 63;
  int wr = wave >> 1, wc = wave & 1;
  int m0 = blockIdx.y * 128, n0 = blockIdx.x * 128;
  f32x4 acc[4][4];
#pragma unroll
  for (int i = 0; i < 4; i++)
#pragma unroll
    for (int j = 0; j < 4; j++) acc[i][j] = (f32x4){0.f, 0.f, 0.f, 0.f};

  int lrow = lane >> 2, lcol = (lane & 3) * 8;
  int r15 = lane & 15, kk = (lane >> 4) * 8;

  for (int k0 = 0; k0 < K; k0 += 32) {
    __syncthreads();
#pragma unroll
    for (int rch = 0; rch < 2; rch++) {
      int c = rch * 4 + wave;
      int row = c * 16 + lrow;
      llds16(A  + (size_t)(m0 + row) * K + k0 + lcol, &As[c * 512]);
      llds16(Bw + (size_t)(n0 + row) * K + k0 + lcol, &Bs[c * 512]);
    }
    __syncthreads();
    short8 af[4], bfv[4];
#pragma unroll
    for (int mi = 0; mi < 4; mi++)
      af[mi] = *(const short8*)&As[(wr * 64 + mi * 16 + r15) * 32 + kk];
#pragma unroll
    for (int ni = 0; ni < 4; ni++)
      bfv[ni] = *(const short8*)&Bs[(wc * 64 + ni * 16 + r15) * 32 + kk];
#pragma unroll
    for (int mi = 0; mi < 4; mi++)
#pragma unroll
      for (int ni = 0; ni < 4; ni++) acc[mi][ni] = mfma16(af[mi], bfv[ni], acc[mi][ni]);
  }
#pragma unroll
  for (int mi = 0; mi < 4; mi++)
#pragma unroll
    for (int ni = 0; ni < 4; ni++) {
      int col = n0 + wc * 64 + ni * 16 + r15;
      float bs = bias[col];
#pragma unroll
      for (int i = 0; i < 4; i++) {
        int row = m0 + wr * 64 + mi * 16 + (lane >> 4) * 4 + i;
        C[(size_t)row * N + col] = acc[mi][ni][i] + bs;
      }
    }
}

// Grouped 1D-grid variant for the vocab GEMM: groups of GN=5 n-panels x all M/128
// m-panels. The group's B slice (5 x 256KB = 1.25MB) stays L2-resident per XCD ->
// B fetched from HBM once instead of once per m-row (was 32x = 2.1GB of L2 refills).
// Same per-block arithmetic -> bitwise-identical C.
__global__ __launch_bounds__(256, 2) void gemm_grp(
    const u16* __restrict__ A, const u16* __restrict__ Bw, const float* __restrict__ bias,
    float* __restrict__ C, int M, int N, int K, int GN) {
  __shared__ __align__(16) u16 As[128 * 32];
  __shared__ __align__(16) u16 Bs[128 * 32];
  int tid = threadIdx.x;
  int wave = tid >> 6, lane = tid & 63;
  int wr = wave >> 1, wc = wave & 1;
  int mp = M >> 7;
  int perg = mp * GN;
  int grp = blockIdx.x / perg;
  int rem = blockIdx.x - grp * perg;
  int m0 = (rem / GN) * 128;
  int n0 = (grp * GN + rem % GN) * 128;
  f32x4 acc[4][4];
#pragma unroll
  for (int i = 0; i < 4; i++)
#pragma unroll
    for (int j = 0; j < 4; j++) acc[i][j] = (f32x4){0.f, 0.f, 0.f, 0.f};

  int lrow = lane >> 2, lcol = (lane & 3) * 8;
  int r15 = lane & 15, kk = (lane >> 4) * 8;

  for (int k0 = 0; k0 < K; k0 += 32) {
    __syncthreads();
#pragma unroll
    for (int rch = 0; rch < 2; rch++) {
      int c = rch * 4 + wave;
      int row = c * 16 + lrow;
      llds16(A  + (size_t)(m0 + row) * K + k0 + lcol, &As[c * 512]);
      llds16(Bw + (size_t)(n0 + row) * K + k0 + lcol, &Bs[c * 512]);
    }
    __syncthreads();
    short8 af[4], bfv[4];
#pragma unroll
    for (int mi = 0; mi < 4; mi++)
      af[mi] = *(const short8*)&As[(wr * 64 + mi * 16 + r15) * 32 + kk];
#pragma unroll
    for (int ni = 0; ni < 4; ni++)
      bfv[ni] = *(const short8*)&Bs[(wc * 64 + ni * 16 + r15) * 32 + kk];
#pragma unroll
    for (int mi = 0; mi < 4; mi++)
#pragma unroll
      for (int ni = 0; ni < 4; ni++) acc[mi][ni] = mfma16(af[mi], bfv[ni], acc[mi][ni]);
  }
#pragma unroll
  for (int mi = 0; mi < 4; mi++)
#pragma unroll
    for (int ni = 0; ni < 4; ni++) {
      int col = n0 + wc * 64 + ni * 16 + r15;
      float bs = bias[col];
#pragma unroll
      for (int i = 0; i < 4; i++) {
        int row = m0 + wr * 64 + mi * 16 + (lane >> 4) * 4 + i;
        C[(size_t)row * N + col] = acc[mi][ni][i] + bs;
      }
    }
}

// ---------------- persistent GRU phase (v6: wave0-only flag polling) ----------------
// grid 256 = 64 jt x 4 bq; block 512 = 8 waves splitting K=1024 into 8x128.
// Barrier spans only a bq-domain (64 blocks): each block sc-stores FLG[bid]=st+1 on its
// own 64B line; ONLY wave0 of each block polls the 64 domain flags (one 64-lane load
// per iteration; 256 polling waves vs R10's 2048 -> 8x less L3 poll traffic), then
// post-poll syncthreads releases the other waves. gx(st+1) prefetched under the poll.
template <int DEC>
__global__ __launch_bounds__(512, 1) void k_pers(
    const u16* __restrict__ W, const float* __restrict__ bhh, const float* __restrict__ gx0,
    char* rA, char* rB, char* rC, float* Hst, float* h2f0, u16* h2b0, u32* bar) {
  int tid = threadIdx.x, wave = tid >> 6, lane = tid & 63;
  int r15 = lane & 15, kk = (lane >> 4) * 8;
  int bq = blockIdx.x & 3, jt = blockIdx.x >> 2;
  int b0 = bq * 16, j0 = jt * 16;
  int kbase = wave * 128;
  const int NSTEP = DEC ? Tt : Ss;

  __shared__ float sC[8][64][13];              // stride 13 -> conflict-free
  __shared__ float hT[256];                    // h tile [bl*16+jc]
  __shared__ __align__(8) u16 stg[2][16][16];  // hi/lo staging

  int bl = tid >> 4, jc = tid & 15;            // epilogue mapping (tid<256)
  float br = 0.f, bz = 0.f, bn = 0.f;
  float xr = 0.f, xz = 0.f, xn = 0.f;
  if (tid < 256) {
    hT[tid] = DEC ? Hst[(size_t)(b0 + bl) * Hh + j0 + jc] : 0.f;
    int j = j0 + jc;
    br = bhh[j]; bz = bhh[Hh + j]; bn = bhh[2 * Hh + j];
    if (DEC) { xr = gx0[j]; xz = gx0[Hh + j]; xn = gx0[2 * Hh + j]; }
    else {                                     // prologue gx load, step 0
      const float* gr = gx0 + (size_t)(b0 + bl) * G3;
      xr = gr[j]; xz = gr[Hh + j]; xn = gr[2 * Hh + j];
    }
  }
  __syncthreads();

  const u16* Wrow = W + (size_t)(j0 + r15) * Hh + kbase + kk;
  int lsrc = (bl >> 2) * 16 + jc;              // partials source for (bl,jc)
  int isrc = bl & 3;
  int flgidx = (lane * 4 + bq) * 16;           // poll address per lane (lane = jt')

  for (int st = 0; st < NSTEP; st++) {
    const u16* hin = hbuf_dev(rA, rB, rC, st);

    f32x4 acc[3];
#pragma unroll
    for (int g = 0; g < 3; g++) acc[g] = (f32x4){0.f, 0.f, 0.f, 0.f};
    const u16* Ab = hin + (size_t)(b0 + r15) * 2048 + kbase + kk;
#pragma unroll
    for (int ks = 0; ks < 4; ks++) {
      int ko = ks * 32;
      short8 ah = *(const short8*)(Ab + ko);          // h_hi (plain b128)
      short8 al = *(const short8*)(Ab + 1024 + ko);   // h_lo
      short8 w0 = *(const short8*)(Wrow + ko);
      short8 w1 = *(const short8*)(Wrow + (size_t)Hh * Hh + ko);
      short8 w2 = *(const short8*)(Wrow + (size_t)2 * Hh * Hh + ko);
      acc[0] = mfma16(ah, w0, acc[0]);
      acc[1] = mfma16(ah, w1, acc[1]);
      acc[2] = mfma16(ah, w2, acc[2]);
      acc[0] = mfma16(al, w0, acc[0]);
      acc[1] = mfma16(al, w1, acc[1]);
      acc[2] = mfma16(al, w2, acc[2]);
    }
#pragma unroll
    for (int g = 0; g < 3; g++)
#pragma unroll
      for (int i = 0; i < 4; i++) sC[wave][lane][g * 4 + i] = acc[g][i];
    __syncthreads();

    if (tid < 256) {
      float hgr = br, hgz = bz, hgn = bn;
#pragma unroll
      for (int w = 0; w < 8; w++) {              // fixed order -> deterministic
        hgr += sC[w][lsrc][isrc];
        hgz += sC[w][lsrc][4 + isrc];
        hgn += sC[w][lsrc][8 + isrc];
      }
      float rg = 1.0f / (1.0f + expf(-(xr + hgr)));
      float zg = 1.0f / (1.0f + expf(-(xz + hgz)));
      float ng = tanhf(xn + rg * hgn);
      float hn = (1.0f - zg) * ng + zg * hT[tid];
      hT[tid] = hn;
      u16 hi = f2bf(hn), lo = f2bf(hn - bf2f(hi));
      stg[0][bl][jc] = hi;
      stg[1][bl][jc] = lo;
      if (DEC) ag_store_f32(&h2f0[((size_t)st * Bb + b0 + bl) * Hh + j0 + jc], hn);
    }
    __syncthreads();

    // distributed sc stores of the next-step buffer (skipped on last step)
    if (tid < 256) {
      int part = tid >> 7, idx = tid & 127, row = idx >> 3, dw = idx & 7;
      if (st + 1 < NSTEP) {
        u16* hout = hbuf_dev(rA, rB, rC, st + 1);
        u32 val = ((const u32*)&stg[part][row][0])[dw];
        ag_store_u32((u32*)(hout + (size_t)(b0 + row) * 2048 + part * 1024 + j0) + dw, val);
      }
      if (DEC && tid < 128) {
        u16* h2b = h2b0 + (size_t)st * Bb * Hh;
        ag_store_u32((u32*)(h2b + (size_t)(b0 + row) * Hh + j0) + dw,
                     ((const u32*)&stg[0][row][0])[dw]);
      }
    }

    if (st + 1 < NSTEP) {
      asm volatile("s_waitcnt vmcnt(0)" ::: "memory");   // own sc stores at L3
      __syncthreads();                                    // whole block drained
      if (tid == 0)
        ag_store_u32(&bar[blockIdx.x * 16], (u32)(st + 1));  // flag: own 64B line
      // prefetch gx(st+1) under the barrier wait (encoder only)
      if (!DEC && tid < 256) {
        const float* gr = gx0 + ((size_t)(st + 1) * Bb + b0 + bl) * G3;
        int j = j0 + jc;
        xr = gr[j]; xz = gr[Hh + j]; xn = gr[2 * Hh + j];
      }
      if (wave == 0) {                         // only wave0 polls (256 pollers total)
        for (;;) {
          int v = (int)ag_load_u32(&bar[flgidx]);
          if (__all(v >= st + 1)) break;
          __builtin_amdgcn_s_sleep(1);
        }
      }
      __syncthreads();                         // release other waves
    }
  }

  if (!DEC && tid < 256)
    Hst[(size_t)(b0 + bl) * Hh + j0 + jc] = hT[tid];
}

// ---------------- fallback per-step kernel (if coop launch fails) ----------------
template <int DEC>
__global__ __launch_bounds__(512, 1) void k_step3(
    const u16* __restrict__ W, const float* __restrict__ bhh, const float* __restrict__ gxp,
    const u16* __restrict__ hAin, u16* __restrict__ hAout, float* __restrict__ h,
    float* __restrict__ h2f, u16* __restrict__ h2b) {
  __shared__ float sC[4][64][13];
  int tid = threadIdx.x, wave = tid >> 6, lane = tid & 63;
  int mw = wave & 3, khalf = wave >> 2;
  int m0 = mw * 16;
  int r15 = lane & 15, kk = (lane >> 4) * 8;
  int j0 = blockIdx.x * 16;
  int kbase = khalf * 512;

  f32x4 acc[3];
#pragma unroll
  for (int g = 0; g < 3; g++) acc[g] = (f32x4){0.f, 0.f, 0.f, 0.f};

  const u16* Ah = hAin + (size_t)(m0 + r15) * 2048 + kbase + kk;
  const u16* Wr = W + (size_t)(j0 + r15) * Hh + kbase + kk;
#pragma unroll 4
  for (int ks = 0; ks < 16; ks++) {
    int ko = ks * 32;
    short8 ah = *(const short8*)(Ah + ko);
    short8 al = *(const short8*)(Ah + 1024 + ko);
    short8 b0 = *(const short8*)(Wr + ko);
    short8 b1 = *(const short8*)(Wr + (size_t)Hh * Hh + ko);
    short8 b2 = *(const short8*)(Wr + (size_t)2 * Hh * Hh + ko);
    acc[0] = mfma16(ah, b0, acc[0]);
    acc[1] = mfma16(ah, b1, acc[1]);
    acc[2] = mfma16(ah, b2, acc[2]);
    acc[0] = mfma16(al, b0, acc[0]);
    acc[1] = mfma16(al, b1, acc[1]);
    acc[2] = mfma16(al, b2, acc[2]);
  }

  if (khalf == 1) {
#pragma unroll
    for (int g = 0; g < 3; g++)
#pragma unroll
      for (int i = 0; i < 4; i++) sC[mw][lane][g * 4 + i] = acc[g][i];
  }
  __syncthreads();
  if (khalf == 1) return;

  int j = j0 + r15;
  float br = bhh[j], bz = bhh[Hh + j], bn = bhh[2 * Hh + j];
  float xrD = 0.f, xzD = 0.f, xnD = 0.f;
  if (DEC) { xrD = gxp[j]; xzD = gxp[Hh + j]; xnD = gxp[2 * Hh + j]; }
#pragma unroll
  for (int i = 0; i < 4; i++) {
    int b = m0 + (lane >> 4) * 4 + i;
    float hgr = acc[0][i] + sC[mw][lane][i]     + br;
    float hgz = acc[1][i] + sC[mw][lane][4 + i] + bz;
    float hgn = acc[2][i] + sC[mw][lane][8 + i] + bn;
    float xr, xz, xn;
    if (DEC) { xr = xrD; xz = xzD; xn = xnD; }
    else {
      const float* gr = gxp + (size_t)b * G3;
      xr = gr[j]; xz = gr[Hh + j]; xn = gr[2 * Hh + j];
    }
    float rg = 1.0f / (1.0f + expf(-(xr + hgr)));
    float zg = 1.0f / (1.0f + expf(-(xz + hgz)));
    float ng = tanhf(xn + rg * hgn);
    float hold = h[(size_t)b * Hh + j];
    float hn = (1.0f - zg) * ng + zg * hold;
    h[(size_t)b * Hh + j] = hn;
    u16 hi = f2bf(hn);
    u16 lo = f2bf(hn - bf2f(hi));
    hAout[(size_t)b * 2048 + j] = hi;
    hAout[(size_t)b * 2048 + 1024 + j] = lo;
    if (DEC) {
      h2f[(size_t)b * Hh + j] = hn;
      h2b[(size_t)b * Hh + j] = hi;
    }
  }
}

// ---------------- heads (exact f32) ----------------
__global__ __launch_bounds__(256, 2) void k_head1(const float* __restrict__ h,
    const float* __restrict__ Wenc, const float* __restrict__ benc, float* __restrict__ henc) {
  int b = blockIdx.x;
  __shared__ float hs[Hh];
  for (int k = threadIdx.x; k < Hh; k += 256) hs[k] = h[(size_t)b * Hh + k];
  __syncthreads();
  int q = threadIdx.x;
  const float* wrw = Wenc + (size_t)q * Hh;
  float s = 0.f;
  for (int k = 0; k < Hh; k++) s += hs[k] * wrw[k];
  henc[b * Zz + q] = s + benc[q];
}

__global__ __launch_bounds__(256, 2) void k_head2(const float* __restrict__ henc,
    const float* __restrict__ Wloc, const float* __restrict__ bloc,
    const float* __restrict__ Wsc, const float* __restrict__ bsc,
    const float* __restrict__ eps, float* __restrict__ outLoc, float* __restrict__ outSc,
    float* __restrict__ zb) {
  int b = blockIdx.x;
  __shared__ float hs[Zz];
  if (threadIdx.x < Zz) hs[threadIdx.x] = henc[b * Zz + threadIdx.x];
  __syncthreads();
  int q = threadIdx.x;
  const float* wl = Wloc + (size_t)q * Zz;
  const float* wsp = Wsc + (size_t)q * Zz;
  float sl = 0.f, ssum = 0.f;
  for (int k = 0; k < Zz; k++) { sl += hs[k] * wl[k]; ssum += hs[k] * wsp[k]; }
  sl += bloc[q]; ssum += bsc[q];
  float sp = fmaxf(ssum, 0.f) + log1pf(expf(-fabsf(ssum)));  // softplus, stable
  float zv = sl + eps[b * Zz + q] * expf(0.5f * sp);
  outLoc[b * Zz + q] = sl;
  outSc[b * Zz + q] = sp;
  zb[b * Zz + q] = zv;
}

__global__ __launch_bounds__(256, 2) void k_head3(const float* __restrict__ zb,
    const float* __restrict__ Wdec, const float* __restrict__ bdec,
    float* __restrict__ h, u16* __restrict__ hA0) {
  int b = blockIdx.x;
  __shared__ float zs[Zz];
  if (threadIdx.x < Zz) zs[threadIdx.x] = zb[b * Zz + threadIdx.x];
  __syncthreads();
  for (int j = threadIdx.x; j < Hh; j += 256) {
    const float* wrw = Wdec + (size_t)j * Zz;
    float s = 0.f;
    for (int k = 0; k < Zz; k++) s += zs[k] * wrw[k];
    s += bdec[j];
    h[(size_t)b * Hh + j] = s;
    u16 hi = f2bf(s);
    u16 lo = f2bf(s - bf2f(hi));
    hA0[(size_t)b * 2048 + j] = hi;
    hA0[(size_t)b * 2048 + 1024 + j] = lo;
  }
}

// ---------------- fused softmax v2: no row-LDS, 2 blocks/CU, re-read via L2/L3 ----------------
// One block per row (T*B = 4096). Pass 1a: max; pass 1b: sumexp + candidates (re-read,
// L2/L3-hot); exact-f32 candidate refine; pass 2: re-read + subtract lse + write.
// Fixed-order reductions + sorted candidates -> deterministic, same results as v1.
__global__ __launch_bounds__(1024, 8) void k_soft(
    float* __restrict__ logits, const float* __restrict__ h2f,
    const float* __restrict__ Wvoc, const float* __restrict__ bvoc,
    float* __restrict__ bestv, int* __restrict__ besti) {
  __shared__ float hrow[Hh];
  __shared__ float red[16];
  __shared__ float srm, ssum, slse;
  __shared__ int lcnt, scc;
  __shared__ int lcand[32];
  __shared__ float lex[32], del[32];
  int r = blockIdx.x;
  int tid = threadIdx.x, wave = tid >> 6, lane = tid & 63;
  float* grow = logits + (size_t)r * Vv;
  if (tid == 0) lcnt = 0;
  hrow[tid] = h2f[(size_t)r * Hh + tid];
  float m = -3.0e38f;
  for (int c = tid * 4; c < Vv; c += 4096) {
    f32x4 v = *(const f32x4*)(grow + c);
    m = fmaxf(fmaxf(m, v.x), fmaxf(v.y, fmaxf(v.z, v.w)));
  }
  for (int o = 32; o; o >>= 1) m = fmaxf(m, __shfl_xor(m, o));
  if (lane == 0) red[wave] = m;
  __syncthreads();
  if (tid == 0) {
    float t = red[0];
    for (int i = 1; i < 16; i++) t = fmaxf(t, red[i]);
    srm = t;
  }
  __syncthreads();
  float rm = srm;
  float s = 0.f;
  for (int c = tid * 4; c < Vv; c += 4096) {
    f32x4 v = *(const f32x4*)(grow + c);            // L2/L3-hot re-read
    s += expf(v.x - rm) + expf(v.y - rm) + expf(v.z - rm) + expf(v.w - rm);
    if (v.x >= rm - 0.0625f) { int sl = atomicAdd(&lcnt, 1); if (sl < 32) lcand[sl] = c; }
    if (v.y >= rm - 0.0625f) { int sl = atomicAdd(&lcnt, 1); if (sl < 32) lcand[sl] = c + 1; }
    if (v.z >= rm - 0.0625f) { int sl = atomicAdd(&lcnt, 1); if (sl < 32) lcand[sl] = c + 2; }
    if (v.w >= rm - 0.0625f) { int sl = atomicAdd(&lcnt, 1); if (sl < 32) lcand[sl] = c + 3; }
  }
  for (int o = 32; o; o >>= 1) s += __shfl_xor(s, o);
  if (lane == 0) red[wave] = s;
  __syncthreads();
  if (tid == 0) {
    float t = 0.f;
    for (int i = 0; i < 16; i++) t += red[i];       // fixed order -> deterministic
    ssum = t;
    int cc = lcnt < 32 ? lcnt : 32;
    for (int i = 0; i < cc; i++)                    // sort ascending -> determinism
      for (int k2 = i + 1; k2 < cc; k2++)
        if (lcand[k2] < lcand[i]) { int q = lcand[i]; lcand[i] = lcand[k2]; lcand[k2] = q; }
    scc = cc;
  }
  __syncthreads();
  int cnt = scc;
  for (int ci = wave; ci < cnt; ci += 16) {         // exact-f32 candidate recompute
    int v = lcand[ci];
    const float* wrw = Wvoc + (size_t)v * Hh;
    float sd = 0.f;
    for (int k = lane; k < Hh; k += 64) sd += hrow[k] * wrw[k];
    for (int o = 32; o; o >>= 1) sd += __shfl_xor(sd, o);
    if (lane == 0) {
      float le = sd + bvoc[v];
      lex[ci] = le;
      del[ci] = expf(le - rm) - expf(grow[v] - rm);
    }
  }
  __syncthreads();
  if (tid == 0) {
    float se = ssum;
    for (int i = 0; i < cnt; i++) se += del[i];
    float lse = rm + logf(se);
    slse = lse;
    float bv = -3.0e38f; int bvi = 0;
    for (int i = 0; i < cnt; i++)
      if (lex[i] > bv) { bv = lex[i]; bvi = lcand[i]; }  // sorted -> ties keep lowest v
    bestv[r] = bv - lse;
    besti[r] = (r & 63) * Vv + bvi;                  // flat index b*V + v
  }
  __syncthreads();
  float l = slse;
  for (int c = tid * 4; c < Vv; c += 4096) {
    f32x4 v = *(const f32x4*)(grow + c);
    v.x -= l; v.y -= l; v.z -= l; v.w -= l;
    *(f32x4*)(grow + c) = v;
  }
}

// ---------------- per-step global argmax -> seq ----------------
__global__ void k_argmax(const float* __restrict__ bestv, const int* __restrict__ besti,
                         float* __restrict__ outseq) {
  int tid = threadIdx.x;
  if (tid == 0) outseq[0] = 1.0f;
  for (int t = 0; t < Tt; t++) {
    float v = bestv[t * 64 + tid];
    int ii = besti[t * 64 + tid];
    for (int o = 1; o < 64; o <<= 1) {
      float ov = __shfl_xor(v, o);
      int oi = __shfl_xor(ii, o);
      if (ov > v || (ov == v && oi < ii)) { v = ov; ii = oi; }
    }
    if (tid == 0) outseq[1 + t] = (float)ii;
  }
}

// ---------------- host: launch sequence ----------------
extern "C" void kernel_launch(void* const* d_in, const int* in_sizes, int n_in,
                              void* d_out, int out_size, void* d_ws, size_t ws_size,
                              hipStream_t stream) {
  (void)in_sizes; (void)n_in; (void)out_size; (void)ws_size;
  const int*   inp     = (const int*)d_in[0];
  const float* eps     = (const float*)d_in[1];
  const float* emb_enc = (const float*)d_in[2];
  const float* Wih_e   = (const float*)d_in[3];
  const float* Whh_e   = (const float*)d_in[4];
  const float* bih_e   = (const float*)d_in[5];
  const float* bhh_e   = (const float*)d_in[6];
  const float* W_enc   = (const float*)d_in[7];
  const float* b_enc   = (const float*)d_in[8];
  const float* W_loc   = (const float*)d_in[9];
  const float* b_loc   = (const float*)d_in[10];
  const float* W_sc    = (const float*)d_in[11];
  const float* b_sc    = (const float*)d_in[12];
  const float* emb_dec = (const float*)d_in[13];
  const float* W_dec   = (const float*)d_in[14];
  const float* b_dec   = (const float*)d_in[15];
  const float* Wih_d   = (const float*)d_in[16];
  const float* Whh_d   = (const float*)d_in[17];
  const float* bih_d   = (const float*)d_in[18];
  const float* bhh_d   = (const float*)d_in[19];
  const float* W_voc   = (const float*)d_in[20];
  const float* b_voc   = (const float*)d_in[21];

  char* ws = (char*)d_ws;
  u16*   WHHE  = (u16*)(ws + OFF_WHHE);
  u16*   WHHD  = (u16*)(ws + OFF_WHHD);
  u16*   WIHB  = (u16*)(ws + OFF_WIHE3);      // plain bf16 Wih_e [3072][512]
  u16*   WVOC  = (u16*)(ws + OFF_WVOC);
  u16*   XS    = (u16*)(ws + OFF_XS);         // plain bf16 x [16384][512]
  float* GX    = (float*)(ws + OFF_GX);
  float* Hst   = (float*)(ws + OFF_H);
  float* H2F   = (float*)(ws + OFF_H2F);
  u16*   H2B   = (u16*)(ws + OFF_H2B);
  float* GXD   = (float*)(ws + OFF_GXD);
  float* HENC  = (float*)(ws + OFF_HENC);
  float* ZB    = (float*)(ws + OFF_ZB);
  float* BV    = (float*)(ws + OFF_BV);
  int*   BI    = (int*)(ws + OFF_BI);
  u32*   BAR   = (u32*)(ws + OFF_BAR);

  char* rA = ws + OFF_XS;      // step-buffer regions
  char* rB = ws + OFF_WIHE3;
  char* rC = ws + OFF_H2F;
  auto hbuf = [&](int i) -> u16* {
    if (i < 192) return (u16*)(rA + (size_t)i * SZ_HAB);
    if (i < 228) return (u16*)(rB + (size_t)(i - 192) * SZ_HAB);
    return (u16*)(rC + (size_t)(i - 228) * SZ_HAB);
  };

  float* out     = (float*)d_out;
  float* logits  = out;                                   // (T*B, V) f32
  float* outseq  = out + (size_t)Tt * Bb * Vv;
  float* outloc  = outseq + (Tt + 1);
  float* outsc   = outloc + Bb * Zz;

  // --- weight conversions ---
  k_tobf<<<1024, 256, 0, stream>>>(Whh_e, WHHE, G3 * Hh);
  k_tobf<<<1024, 256, 0, stream>>>(Whh_d, WHHD, G3 * Hh);
  k_tobf<<<512, 256, 0, stream>>>(Wih_e, WIHB, G3 * Ee);
  k_tobf<<<2048, 256, 0, stream>>>(W_voc, WVOC, Vv * Hh);
  k_xgather<<<2048, 256, 0, stream>>>(inp, emb_enc, XS);

  // --- gx = x * Wih_e^T + bih_e   (M=16384, N=3072, K=512, plain bf16) ---
  {
    dim3 g(G3 / 128, (Ss * Bb) / 128);
    gemm_bt<<<g, 256, 0, stream>>>(XS, WIHB, bih_e, GX, Ss * Bb, G3, Ee);
  }
  k_gxd<<<12, 256, 0, stream>>>(emb_dec, Wih_d, bih_d, GXD);
  k_zero<<<64, 256, 0, stream>>>((u32*)hbuf(0), (int)(SZ_HAB / 4));  // h0 = 0
  k_zero<<<1, 256, 0, stream>>>(BAR, 4096);

  // --- encoder: persistent cooperative (256 steps), fallback = per-step loop ---
  hipError_t ce;
  {
    const u16* a0 = WHHE; const float* a1 = bhh_e; const float* a2 = GX;
    char* a3 = rA; char* a4 = rB; char* a5 = rC; float* a6 = Hst;
    float* a7 = nullptr; u16* a8 = nullptr; u32* a9 = BAR;
    void* args[] = {&a0,&a1,&a2,&a3,&a4,&a5,&a6,&a7,&a8,&a9};
    ce = hipLaunchCooperativeKernel(reinterpret_cast<void*>(&k_pers<0>),
                                    dim3(256), dim3(512), args, 0, stream);
  }
  if (ce != hipSuccess) {
    for (int s = 0; s < Ss; s++)
      k_step3<0><<<64, 512, 0, stream>>>(WHHE, bhh_e, GX + (size_t)s * Bb * G3,
                                         hbuf(s), hbuf(s + 1), Hst, nullptr, nullptr);
  }

  // --- heads ---
  k_head1<<<64, 256, 0, stream>>>(Hst, W_enc, b_enc, HENC);
  k_head2<<<64, 256, 0, stream>>>(HENC, W_loc, b_loc, W_sc, b_sc, eps, outloc, outsc, ZB);
  k_head3<<<64, 256, 0, stream>>>(ZB, W_dec, b_dec, Hst, hbuf(0));
  k_zero<<<1, 256, 0, stream>>>(BAR, 4096);

  // --- decoder: persistent cooperative (64 steps), fallback = per-step loop ---
  {
    const u16* a0 = WHHD; const float* a1 = bhh_d; const float* a2 = GXD;
    char* a3 = rA; char* a4 = rB; char* a5 = rC; float* a6 = Hst;
    float* a7 = H2F; u16* a8 = H2B; u32* a9 = BAR;
    void* args[] = {&a0,&a1,&a2,&a3,&a4,&a5,&a6,&a7,&a8,&a9};
    hipError_t cd = hipLaunchCooperativeKernel(reinterpret_cast<void*>(&k_pers<1>),
                                               dim3(256), dim3(512), args, 0, stream);
    if (cd != hipSuccess) {
      for (int t = 0; t < Tt; t++)
        k_step3<1><<<64, 512, 0, stream>>>(WHHD, bhh_d, GXD, hbuf(t), hbuf(t + 1), Hst,
                                           H2F + (size_t)t * Bb * Hh,
                                           H2B + (size_t)t * Bb * Hh);
    }
  }

  // --- vocab projection: logits = h2 * Wvoc^T + b_voc  (M=4096, N=32000, K=1024) ---
  // grouped 1D grid: 50 groups x (32 m-panels x 5 n-panels) -> B slice L2-resident
  gemm_grp<<<8000, 256, 0, stream>>>(H2B, WVOC, b_voc, logits, Tt * Bb, Vv, Hh, 5);

  // --- fused softmax (stats + exact argmax refine + in-place log-softmax) ---
  k_soft<<<Tt * Bb, 1024, 0, stream>>>(logits, H2F, W_voc, b_voc, BV, BI);
  k_argmax<<<1, 64, 0, stream>>>(BV, BI, outseq);
}